// Round 12
// baseline (474.289 us; speedup 1.0000x reference)
//
#include <hip/hip_runtime.h>
#include <cstdint>
#include <cstddef>

#define DEV __device__ __forceinline__

namespace {

constexpr int BB   = 4;
constexpr int HWP  = 50176;   // 224*224
constexpr int NQ   = 12544;   // 112*112
constexpr int NKk  = 196;     // 14*14
constexpr int VD   = 384;
constexpr float EPS_GN  = 1e-5f;
constexpr float EPS_RMS = 1.1920929e-7f;

typedef __attribute__((ext_vector_type(4))) float f32x4;
typedef __attribute__((ext_vector_type(4))) _Float16 h16x4;

DEV float silu_f(float z) { return z / (1.f + __expf(-z)); }
DEV int rfl(int v) { return __builtin_amdgcn_readfirstlane(v); }

DEV f32x4 mfma16(h16x4 a, h16x4 b, f32x4 c) {
  return __builtin_amdgcn_mfma_f32_16x16x16f16(a, b, c, 0, 0, 0);
}

// ---------- fused weight prep (one launch) ----------
DEV void pack16_one(int id, const float* W, const float* rowscale,
                    _Float16* dst) {
  int j = id & 3, l = (id >> 2) & 63, tile = id >> 8;
  int ct = tile & 7, kt = tile >> 3;
  int ci = kt * 16 + 4 * (l >> 4) + j;
  int co = ct * 16 + (l & 15);
  float v = W[(size_t)co * 128 + ci];
  if (rowscale) v *= rowscale[ci];
  dst[id] = (_Float16)v;
}
// pack 128x384 weight into frag order, K=384 (24 kt)
DEV void pack384_one(int id, const float* W, _Float16* dst) {
  int j = id & 3, l = (id >> 2) & 63, rest = id >> 8;
  int ct = rest & 7, kt = rest >> 3;          // kt 0..23
  int ci = kt * 16 + 4 * (l >> 4) + j;
  int co = ct * 16 + (l & 15);
  dst[id] = (_Float16)W[(size_t)co * 384 + ci];
}

__global__ __launch_bounds__(256) void k_prep(
    const float* __restrict__ qenc_w, const float* __restrict__ kenc_w,
    const float* __restrict__ q_proj_w, const float* __restrict__ rms_q_w,
    const float* __restrict__ block_conv_w,
    const float* __restrict__ kfeat_conv_w, const float* __restrict__ kfeat_proj_w,
    const float* __restrict__ sft_gamma_w, const float* __restrict__ sft_beta_w,
    const float* __restrict__ k_proj_w, const float* __restrict__ rms_k_w,
    const float* __restrict__ ropef, const float* __restrict__ feat,
    _Float16* __restrict__ WqB, _Float16* __restrict__ WkB,
    _Float16* __restrict__ QPB, _Float16* __restrict__ W3B,
    _Float16* __restrict__ KFB, _Float16* __restrict__ KFPB,
    _Float16* __restrict__ GB, _Float16* __restrict__ BBf,
    _Float16* __restrict__ KPB,
    float* __restrict__ cosT, float* __restrict__ sinT,
    _Float16* __restrict__ featB) {
  int idx = blockIdx.x * 256 + threadIdx.x;
  if (idx < 16384) {
    pack16_one(idx, qenc_w, nullptr, WqB);
  } else if (idx < 32768) {
    pack16_one(idx - 16384, kenc_w, nullptr, WkB);
  } else if (idx < 49152) {
    pack16_one(idx - 32768, q_proj_w, rms_q_w, QPB);
  } else if (idx < 196608) {
    int id = idx - 49152;
    int j = id & 3, l = (id >> 2) & 63, tile = (id >> 8) & 63, tap = id >> 14;
    int ct = tile & 7, kt = tile >> 3;
    int ci = kt * 16 + 4 * (l >> 4) + j;
    int co = ct * 16 + (l & 15);
    W3B[id] = (_Float16)block_conv_w[((size_t)co * 128 + ci) * 9 + tap];
  } else if (idx < 245760) {
    pack384_one(idx - 196608, kfeat_conv_w, KFB);
  } else if (idx < 294912) {
    pack384_one(idx - 245760, kfeat_proj_w, KFPB);
  } else if (idx < 311296) {
    pack16_one(idx - 294912, sft_gamma_w, nullptr, GB);
  } else if (idx < 327680) {
    pack16_one(idx - 311296, sft_beta_w, nullptr, BBf);
  } else if (idx < 344064) {
    pack16_one(idx - 327680, k_proj_w, rms_k_w, KPB);
  } else if (idx < 358400) {
    int id = idx - 344064;            // pos*64 + d
    int pos = id >> 6, d = id & 63;
    float a = (pos + 0.5f) * (1.f / 224.f) * ropef[d];
    float s, c;
    __sincosf(a, &s, &c);
    cosT[id] = c;
    sinT[id] = s;
  } else if (idx < 677888) {
    int id = idx - 358400;            // (((b*13+kt)*24+dt)*64+l)*4+j
    int j = id & 3, l = (id >> 2) & 63;
    int rest = id >> 8;
    int dt = rest % 24;
    int kt = (rest / 24) % 13;
    int b = rest / (24 * 13);
    int key = kt * 16 + 4 * (l >> 4) + j;
    int d = dt * 16 + (l & 15);
    float v = (key < 196) ? feat[((size_t)(b * 384) + d) * 196 + key] : 0.f;
    featB[id] = (_Float16)v;
  }
}

// ---------- image GN stats via 3x3 Gram ----------

__global__ __launch_bounds__(256) void k_imgstat1(
    const float* __restrict__ img, float* __restrict__ part) {
  __shared__ float lds[4][9];
  int b = blockIdx.x >> 6, blk = blockIdx.x & 63;
  int t = threadIdx.x;
  float a[9];
#pragma unroll
  for (int j = 0; j < 9; ++j) a[j] = 0.f;
  const float* ib = img + (size_t)b * 3 * HWP;
  for (int pix = blk * 784 + t; pix < blk * 784 + 784; pix += 256) {
    float x0 = ib[pix], x1 = ib[HWP + pix], x2 = ib[2 * HWP + pix];
    a[0] += x0; a[1] += x1; a[2] += x2;
    a[3] += x0 * x0; a[4] += x0 * x1; a[5] += x0 * x2;
    a[6] += x1 * x1; a[7] += x1 * x2; a[8] += x2 * x2;
  }
#pragma unroll
  for (int j = 0; j < 9; ++j)
    for (int m = 1; m < 64; m <<= 1) a[j] += __shfl_xor(a[j], m);
  if ((t & 63) == 0)
    for (int j = 0; j < 9; ++j) lds[t >> 6][j] = a[j];
  __syncthreads();
  if (t < 9)
    part[(size_t)blockIdx.x * 9 + t] =
        lds[0][t] + lds[1][t] + lds[2][t] + lds[3][t];
}

__global__ __launch_bounds__(128) void k_imgstat2(
    const float* __restrict__ part, const float* __restrict__ wimg,
    float* __restrict__ img_murs) {
  __shared__ float MG[9];
  int b = blockIdx.x, t = threadIdx.x;
  if (t < 9) {
    float s = 0.f;
    for (int i = 0; i < 64; ++i) s += part[(size_t)(b * 64 + i) * 9 + t];
    MG[t] = s;
  }
  __syncthreads();
  int c = t;
  float w0 = wimg[c * 3], w1 = wimg[c * 3 + 1], w2 = wimg[c * 3 + 2];
  float s1 = w0 * MG[0] + w1 * MG[1] + w2 * MG[2];
  float s2 = w0 * w0 * MG[3] + w1 * w1 * MG[6] + w2 * w2 * MG[8] +
             2.f * (w0 * w1 * MG[4] + w0 * w2 * MG[5] + w1 * w2 * MG[7]);
  for (int m = 1; m < 16; m <<= 1) {
    s1 += __shfl_xor(s1, m);
    s2 += __shfl_xor(s2, m);
  }
  if ((c & 15) == 0) {
    int g = c >> 4;
    float invN = 1.f / (16.f * HWP);
    float mu = s1 * invN;
    float var = s2 * invN - mu * mu;
    img_murs[b * 16 + g] = mu;
    img_murs[b * 16 + 8 + g] = rsqrtf(var + EPS_GN);
  }
}

// ---------- enc producer + Gram + enc_frag materialization ----------

__global__ __launch_bounds__(256) void k_gram(
    const float* __restrict__ img, const float* __restrict__ cosT,
    const float* __restrict__ sinT,
    const float* __restrict__ wimg, const float* __restrict__ wimgp,
    const float* __restrict__ img_murs,
    _Float16* __restrict__ encF,
    float* __restrict__ Gpart, float* __restrict__ mpart) {
  __shared__ __align__(16) _Float16 fragP[2080 * 4];   // [kt*4+mt][lane(65 pad)][j]
  __shared__ __align__(16) _Float16 fragC[8192];       // [pk][ct][lane][j]
  __shared__ float sWc[384], sWp[384], sMu[8], sRs[8];
  int t = threadIdx.x, l = t & 63, w = t >> 6;
  int b = blockIdx.x / 98, blk = blockIdx.x % 98;
  for (int i = t; i < 384; i += 256) { sWc[i] = wimg[i]; sWp[i] = wimgp[i]; }
  if (t < 8) { sMu[t] = img_murs[b * 16 + t]; sRs[t] = img_murs[b * 16 + 8 + t]; }
  f32x4 acc[2][8];
  f32x4 macc[2];
  f32x4 z = {0.f, 0.f, 0.f, 0.f};
#pragma unroll
  for (int e = 0; e < 2; ++e) {
    macc[e] = z;
#pragma unroll
    for (int nt = 0; nt < 8; ++nt) acc[e][nt] = z;
  }
  h16x4 hone = {(_Float16)1.f, (_Float16)1.f, (_Float16)1.f, (_Float16)1.f};
  int mt = l >> 4;
  int laneCbase = 16 * ((l & 15) >> 2);
  int jC = (l & 15) & 3;
  for (int s = 0; s < 8; ++s) {
    int sub = blk * 8 + s;
    int tile = sub >> 2, st = sub & 3;
    int py = (tile / 14) * 16 + ((st >> 1) << 3) + (l >> 3);
    int px = (tile % 14) * 16 + ((st & 1) << 3) + (l & 7);
    __syncthreads();
    {
      const float* ip = img + (size_t)b * 3 * HWP + py * 224 + px;
      float x0 = ip[0], x1 = ip[HWP], x2 = ip[2 * HWP];
      const float* cy = cosT + py * 64 + w * 16;
      const float* sy = sinT + py * 64 + w * 16;
      const float* cx = cosT + px * 64 + w * 16;
      const float* sx = sinT + px * 64 + w * 16;
#pragma unroll
      for (int jj = 0; jj < 4; ++jj) {
        f32x4 cyv = *(const f32x4*)(cy + jj * 4);
        f32x4 syv = *(const f32x4*)(sy + jj * 4);
        f32x4 cxv = *(const f32x4*)(cx + jj * 4);
        f32x4 sxv = *(const f32x4*)(sx + jj * 4);
        h16x4 lo4, hi4;
#pragma unroll
        for (int u = 0; u < 4; ++u) {
          int d = w * 16 + jj * 4 + u;
          int c2 = d + 64;
          float y1 = sWc[d * 3] * x0 + sWc[d * 3 + 1] * x1 + sWc[d * 3 + 2] * x2;
          float s1 = sWp[d * 3] * x0 + sWp[d * 3 + 1] * x1 + sWp[d * 3 + 2] * x2;
          float y2 = sWc[c2 * 3] * x0 + sWc[c2 * 3 + 1] * x1 + sWc[c2 * 3 + 2] * x2;
          float s2 = sWp[c2 * 3] * x0 + sWp[c2 * 3 + 1] * x1 + sWp[c2 * 3 + 2] * x2;
          int g1 = d >> 4, g2 = g1 + 4;
          float t1 = silu_f((y1 - sMu[g1]) * sRs[g1]) + s1;
          float t2 = silu_f((y2 - sMu[g2]) * sRs[g2]) + s2;
          lo4[u] = (_Float16)(t1 * cyv[u] - t2 * syv[u]);
          hi4[u] = (_Float16)(t2 * cxv[u] + t1 * sxv[u]);
        }
        int lane = (l & 15) + 16 * jj;
        *(h16x4*)&fragP[((w * 4 + mt) * 65 + lane) * 4]       = lo4;
        *(h16x4*)&fragP[(((w + 4) * 4 + mt) * 65 + lane) * 4] = hi4;
#pragma unroll
        for (int u = 0; u < 4; ++u) {
          int laneC = jj * 4 + u + laneCbase;
          fragC[((mt * 8 + w) * 64 + laneC) * 4 + jC]     = lo4[u];
          fragC[((mt * 8 + w + 4) * 64 + laneC) * 4 + jC] = hi4[u];
        }
      }
    }
    __syncthreads();
    _Float16* ef = encF + ((size_t)(b * 784) + sub) * 8192;
    for (int i = t; i < 2048; i += 256) {
      int kt = i >> 8, m2 = (i >> 6) & 3, ln = i & 63;
      *(h16x4*)(ef + (size_t)i * 4) =
          *(const h16x4*)&fragP[((kt * 4 + m2) * 65 + ln) * 4];
    }
#pragma unroll
    for (int pk = 0; pk < 4; ++pk) {
      h16x4 a0 = *(const h16x4*)&fragC[((pk * 8 + 2 * w) * 64 + l) * 4];
      h16x4 a1 = *(const h16x4*)&fragC[((pk * 8 + 2 * w + 1) * 64 + l) * 4];
      macc[0] = mfma16(a0, hone, macc[0]);
      macc[1] = mfma16(a1, hone, macc[1]);
#pragma unroll
      for (int nt = 0; nt < 8; ++nt) {
        h16x4 bv = *(const h16x4*)&fragC[((pk * 8 + nt) * 64 + l) * 4];
        acc[0][nt] = mfma16(a0, bv, acc[0][nt]);
        acc[1][nt] = mfma16(a1, bv, acc[1][nt]);
      }
    }
  }
  float* gp = Gpart + (size_t)(b * 98 + blk) * 16384;
#pragma unroll
  for (int e = 0; e < 2; ++e)
#pragma unroll
    for (int nt = 0; nt < 8; ++nt)
#pragma unroll
      for (int r = 0; r < 4; ++r) {
        int row = (2 * w + e) * 16 + 4 * (l >> 4) + r;
        int col = nt * 16 + (l & 15);
        gp[row * 128 + col] = acc[e][nt][r];
      }
  if ((l & 15) == 0) {
    float* mp = mpart + (size_t)(b * 98 + blk) * 128;
#pragma unroll
    for (int e = 0; e < 2; ++e)
#pragma unroll
      for (int r = 0; r < 4; ++r)
        mp[(2 * w + e) * 16 + 4 * (l >> 4) + r] = macc[e][r];
  }
}

__global__ void k_gred(const float* __restrict__ Gpart,
                       const float* __restrict__ mpart,
                       float* __restrict__ G, float* __restrict__ mvec) {
  int b = blockIdx.x >> 6, chunk = blockIdx.x & 63;
  int idx = chunk * 256 + threadIdx.x;
  float s = 0.f;
  for (int i = 0; i < 98; ++i) s += Gpart[(size_t)(b * 98 + i) * 16384 + idx];
  G[(size_t)b * 16384 + idx] = s;
  if (idx < 128) {
    float sm = 0.f;
    for (int i = 0; i < 98; ++i) sm += mpart[(size_t)(b * 98 + i) * 128 + idx];
    mvec[b * 128 + idx] = sm;
  }
}

__global__ __launch_bounds__(256) void k_gstats(
    const float* __restrict__ G, const float* __restrict__ mvec,
    const float* __restrict__ qw, const float* __restrict__ kw,
    float* __restrict__ qk_murs) {
  __shared__ float red1[4], red2[4];
  int bi = blockIdx.x;               // conv*32 + b*8 + g
  int conv = bi >> 5, b = (bi >> 3) & 3, g = bi & 7;
  const float* W = conv ? kw : qw;
  int t = threadIdx.x;
  int c = g * 16 + (t >> 4);
  int i0 = (t & 15) * 8;
  const float* wc = W + (size_t)c * 128;
  const float* Gb = G + (size_t)b * 16384;
  const float* mb = mvec + b * 128;
  float s1 = 0.f, s2 = 0.f;
  for (int i = i0; i < i0 + 8; ++i) {
    float gi = 0.f;
    for (int j = 0; j < 128; ++j) gi += Gb[i * 128 + j] * wc[j];
    s2 += wc[i] * gi;
    s1 += wc[i] * mb[i];
  }
  for (int m = 1; m < 64; m <<= 1) { s1 += __shfl_xor(s1, m); s2 += __shfl_xor(s2, m); }
  if ((t & 63) == 0) { red1[t >> 6] = s1; red2[t >> 6] = s2; }
  __syncthreads();
  if (t == 0) {
    float S1 = red1[0] + red1[1] + red1[2] + red1[3];
    float S2 = red2[0] + red2[1] + red2[2] + red2[3];
    float invN = 1.f / 802816.f;
    float mu = S1 * invN;
    float var = S2 * invN - mu * mu;
    qk_murs[bi * 2] = mu;
    qk_murs[bi * 2 + 1] = rsqrtf(var + EPS_GN);
  }
}

// ---------- pass A: q/k enc_blocks from encF, swapped operands ----------

__global__ __launch_bounds__(256) void k_passA2(
    const _Float16* __restrict__ encF, const float* __restrict__ qk_murs,
    const _Float16* __restrict__ WqB, const _Float16* __restrict__ WkB,
    float* __restrict__ q_pool, float* __restrict__ kpp,
    float* __restrict__ Qpart) {
  int t = threadIdx.x, l = t & 63;
  int wu = rfl(t >> 6);
  int bi = blockIdx.x;
  int b = bi / 784, sub = bi % 784;
  int tile = sub >> 2, st = sub & 3;
  int by = (tile / 14) * 16, bx = (tile % 14) * 16;
  float qmu[2], qrs[2], kmu[2], krs[2];
#pragma unroll
  for (int cc = 0; cc < 2; ++cc) {
    int g = 2 * wu + cc;
    qmu[cc] = qk_murs[(b * 8 + g) * 2];
    qrs[cc] = qk_murs[(b * 8 + g) * 2 + 1];
    kmu[cc] = qk_murs[(32 + b * 8 + g) * 2];
    krs[cc] = qk_murs[(32 + b * 8 + g) * 2 + 1];
  }
  const h16x4* EF = (const h16x4*)encF + ((size_t)(b * 784) + sub) * 2048;
  f32x4 z = {0.f, 0.f, 0.f, 0.f};
  f32x4 accQ[4][2], accK[4][2];
  h16x4 sf[2][4];
#pragma unroll
  for (int mt = 0; mt < 4; ++mt)
#pragma unroll
    for (int cc = 0; cc < 2; ++cc) { accQ[mt][cc] = z; accK[mt][cc] = z; }
  for (int kt = 0; kt < 8; ++kt) {
    h16x4 a[4];
#pragma unroll
    for (int mt = 0; mt < 4; ++mt) a[mt] = EF[(kt * 4 + mt) * 64 + l];
    if ((kt >> 1) == wu) {
#pragma unroll
      for (int mt = 0; mt < 4; ++mt) sf[kt & 1][mt] = a[mt];
    }
    int fi = (kt * 8 + 2 * wu) * 64 + l;
    h16x4 bq0 = *(const h16x4*)(WqB + (size_t)fi * 4);
    h16x4 bq1 = *(const h16x4*)(WqB + (size_t)(fi + 64) * 4);
    h16x4 bk0 = *(const h16x4*)(WkB + (size_t)fi * 4);
    h16x4 bk1 = *(const h16x4*)(WkB + (size_t)(fi + 64) * 4);
#pragma unroll
    for (int mt = 0; mt < 4; ++mt) {
      accQ[mt][0] = mfma16(bq0, a[mt], accQ[mt][0]);
      accQ[mt][1] = mfma16(bq1, a[mt], accQ[mt][1]);
      accK[mt][0] = mfma16(bk0, a[mt], accK[mt][0]);
      accK[mt][1] = mfma16(bk1, a[mt], accK[mt][1]);
    }
  }
  int q = l & 15;
  bool act = (q & 9) == 0;
  float kacc[2][4];
  float qs1[2] = {0.f, 0.f}, qs2[2] = {0.f, 0.f};
#pragma unroll
  for (int cc = 0; cc < 2; ++cc)
#pragma unroll
    for (int r = 0; r < 4; ++r) kacc[cc][r] = 0.f;
#pragma unroll
  for (int cc = 0; cc < 2; ++cc) {
    int g = 2 * wu + cc;
#pragma unroll
    for (int mt = 0; mt < 4; ++mt) {
      f32x4 pv;
#pragma unroll
      for (int r = 0; r < 4; ++r) {
        float skip = (float)sf[cc][mt][r];
        pv[r] = silu_f((accQ[mt][cc][r] - qmu[cc]) * qrs[cc]) + skip;
        kacc[cc][r] += silu_f((accK[mt][cc][r] - kmu[cc]) * krs[cc]) + skip;
      }
#pragma unroll
      for (int r = 0; r < 4; ++r) {
        float v = pv[r] + __shfl_xor(pv[r], 1);
        v += __shfl_xor(v, 8);
        pv[r] = v * 0.25f;
      }
      if (act) {
        int p = mt * 16 + q;
        int py = by + (st >> 1) * 8 + (p >> 3);
        int px = bx + (st & 1) * 8 + (p & 7);
        size_t base = ((size_t)(b * NQ) + (py >> 1) * 112 + (px >> 1)) * 128 +
                      g * 16 + 4 * (l >> 4);
        *(f32x4*)(q_pool + base) = pv;
        qs1[cc] += pv[0] + pv[1] + pv[2] + pv[3];
        qs2[cc] += pv[0] * pv[0] + pv[1] * pv[1] + pv[2] * pv[2] + pv[3] * pv[3];
      }
    }
  }
#pragma unroll
  for (int cc = 0; cc < 2; ++cc) {
#pragma unroll
    for (int r = 0; r < 4; ++r) {
      float v = kacc[cc][r];
      v += __shfl_xor(v, 1);
      v += __shfl_xor(v, 2);
      v += __shfl_xor(v, 4);
      v += __shfl_xor(v, 8);
      kacc[cc][r] = v;
    }
    if (q == 0) {
      f32x4 kv = {kacc[cc][0], kacc[cc][1], kacc[cc][2], kacc[cc][3]};
      *(f32x4*)(kpp + (size_t)bi * 128 + (2 * wu + cc) * 16 + 4 * (l >> 4)) = kv;
    }
  }
#pragma unroll
  for (int cc = 0; cc < 2; ++cc) {
    float a1 = qs1[cc], a2 = qs2[cc];
    for (int m = 1; m < 64; m <<= 1) {
      a1 += __shfl_xor(a1, m);
      a2 += __shfl_xor(a2, m);
    }
    if (l == 0) {
      Qpart[(size_t)bi * 16 + (2 * wu + cc) * 2] = a1;
      Qpart[(size_t)bi * 16 + (2 * wu + cc) * 2 + 1] = a2;
    }
  }
}

__global__ __launch_bounds__(256) void k_kpred(
    const float* __restrict__ kpp, float* __restrict__ k_pool) {
  int idx = blockIdx.x * 256 + threadIdx.x;
  if (idx >= BB * 128 * NKk) return;
  int b = idx / (128 * NKk);
  int rem = idx % (128 * NKk);
  int c = rem / NKk, tile = rem % NKk;
  const float* base = kpp + ((size_t)(b * 196 + tile) * 4) * 128 + c;
  float s = base[0] + base[128] + base[256] + base[384];
  k_pool[idx] = s * (1.f / 256.f);
}

__global__ __launch_bounds__(256) void k_qstatfin(
    const float* __restrict__ Qpart, float* __restrict__ murs2) {
  __shared__ float l1[4], l2[4];
  int b = blockIdx.x >> 3, g = blockIdx.x & 7, t = threadIdx.x;
  float s1 = 0.f, s2 = 0.f;
  for (int i = t; i < 784; i += 256) {
    s1 += Qpart[((size_t)(b * 784) + i) * 16 + g * 2];
    s2 += Qpart[((size_t)(b * 784) + i) * 16 + g * 2 + 1];
  }
  for (int m = 1; m < 64; m <<= 1) { s1 += __shfl_xor(s1, m); s2 += __shfl_xor(s2, m); }
  if ((t & 63) == 0) { l1[t >> 6] = s1; l2[t >> 6] = s2; }
  __syncthreads();
  if (t == 0) {
    float a = l1[0] + l1[1] + l1[2] + l1[3];
    float bq = l2[0] + l2[1] + l2[2] + l2[3];
    float invN = 1.f / (16.f * (float)NQ);
    float mu = a * invN;
    float var = bq * invN - mu * mu;
    murs2[blockIdx.x * 2] = mu;
    murs2[blockIdx.x * 2 + 1] = rsqrtf(var + EPS_GN);
  }
}

// ---------- GN stats (channel-major src[b][c][P]) ----------

__global__ __launch_bounds__(256) void k_gnstats(
    const float* __restrict__ src, float* __restrict__ murs, int P, float eps) {
  __shared__ float l1[4], l2[4];
  int b = blockIdx.x >> 3, g = blockIdx.x & 7, t = threadIdx.x;
  const float* base = src + ((size_t)(b * 128) + g * 16) * P;
  float s1 = 0.f, s2 = 0.f;
  for (int i = t; i < 16 * P; i += 256) {
    float v = base[i];
    s1 += v; s2 += v * v;
  }
  for (int m = 1; m < 64; m <<= 1) { s1 += __shfl_xor(s1, m); s2 += __shfl_xor(s2, m); }
  if ((t & 63) == 0) { l1[t >> 6] = s1; l2[t >> 6] = s2; }
  __syncthreads();
  if (t == 0) {
    float invN = 1.f / (16.f * (float)P);
    float a = l1[0] + l1[1] + l1[2] + l1[3];
    float bq = l2[0] + l2[1] + l2[2] + l2[3];
    float mu = a * invN;
    float var = bq * invN - mu * mu;
    murs[blockIdx.x * 2] = mu;
    murs[blockIdx.x * 2 + 1] = rsqrtf(var + eps);
  }
}

// ---------- kf branch: fused L2-norm + 384->128 conv+proj (MFMA) ----------

__global__ __launch_bounds__(256) void k_kf(
    const float* __restrict__ feat,
    const _Float16* __restrict__ KFB, const _Float16* __restrict__ KFPB,
    float* __restrict__ y_kf, float* __restrict__ skip_kf) {
  __shared__ __align__(16) _Float16 fnF[24 * 4 * 64 * 4];  // 48KB, A-frags
  __shared__ float ssqL[4][64];
  __shared__ float rsqL[64];
  int t = threadIdx.x, l = t & 63, w = t >> 6;
  int b = blockIdx.x >> 2, tile = blockIdx.x & 3;
  int p0 = tile * 49;
  const float* fb = feat + (size_t)b * VD * NKk;
  {
    float s = 0.f;
    if (l < 49) {
#pragma unroll 4
      for (int k = w; k < VD; k += 4) {
        float v = fb[(size_t)k * NKk + p0 + l];
        s += v * v;
      }
    }
    ssqL[w][l] = s;
  }
  __syncthreads();
  if (t < 64) {
    float s = ssqL[0][t] + ssqL[1][t] + ssqL[2][t] + ssqL[3][t];
    rsqL[t] = rsqrtf(fmaxf(s, 1e-24f));
  }
  __syncthreads();
  for (int i = t; i < VD * 64; i += 256) {
    int k = i >> 6, p = i & 63;
    float v = 0.f;
    if (p < 49) v = fb[(size_t)k * NKk + p0 + p] * rsqL[p];
    int kt = k >> 4, kr = k & 15, u = kr >> 2, j = kr & 3, mt = p >> 4;
    fnF[(((kt * 4 + mt) * 64) + (p & 15) + 16 * u) * 4 + j] = (_Float16)v;
  }
  __syncthreads();
  f32x4 z = {0.f, 0.f, 0.f, 0.f};
  f32x4 accY[4][2], accS[4][2];
#pragma unroll
  for (int mt = 0; mt < 4; ++mt)
#pragma unroll
    for (int cc = 0; cc < 2; ++cc) { accY[mt][cc] = z; accS[mt][cc] = z; }
  for (int kt = 0; kt < 24; ++kt) {
    h16x4 a[4];
#pragma unroll
    for (int mt = 0; mt < 4; ++mt)
      a[mt] = *(const h16x4*)&fnF[((kt * 4 + mt) * 64 + l) * 4];
    int fi = (kt * 8 + 2 * w) * 64 + l;
    h16x4 by0 = *(const h16x4*)(KFB + (size_t)fi * 4);
    h16x4 by1 = *(const h16x4*)(KFB + (size_t)(fi + 64) * 4);
    h16x4 bs0 = *(const h16x4*)(KFPB + (size_t)fi * 4);
    h16x4 bs1 = *(const h16x4*)(KFPB + (size_t)(fi + 64) * 4);
#pragma unroll
    for (int mt = 0; mt < 4; ++mt) {
      accY[mt][0] = mfma16(a[mt], by0, accY[mt][0]);
      accY[mt][1] = mfma16(a[mt], by1, accY[mt][1]);
      accS[mt][0] = mfma16(a[mt], bs0, accS[mt][0]);
      accS[mt][1] = mfma16(a[mt], bs1, accS[mt][1]);
    }
  }
#pragma unroll
  for (int cc = 0; cc < 2; ++cc) {
    int co = (2 * w + cc) * 16 + (l & 15);
#pragma unroll
    for (int mt = 0; mt < 4; ++mt)
#pragma unroll
      for (int r = 0; r < 4; ++r) {
        int pix = mt * 16 + 4 * (l >> 4) + r;
        if (pix < 49) {
          size_t off = ((size_t)(b * 128) + co) * NKk + p0 + pix;
          y_kf[off] = accY[mt][cc][r];
          skip_kf[off] = accS[mt][cc][r];
        }
      }
  }
}

// ---------- merged SFT + RMSNorm + k-proj (MFMA) ----------

__global__ __launch_bounds__(256) void k_ksft(
    const float* __restrict__ y_kf, const float* __restrict__ skip_kf,
    const float* __restrict__ kf_murs, const float* __restrict__ kgn_murs,
    const _Float16* __restrict__ GB, const _Float16* __restrict__ BBf,
    const _Float16* __restrict__ KPB,
    const float* __restrict__ k_pool, const float* __restrict__ k_proj_b,
    float* __restrict__ kpb) {
  __shared__ __align__(16) _Float16 kfF[8 * 4 * 64 * 4];  // 16KB A-frags
  __shared__ float msL[4][64];
  __shared__ float sMu[8], sRs[8], sGmu[8], sGrs[8];
  int t = threadIdx.x, l = t & 63, w = t >> 6;
  int b = blockIdx.x >> 2, tile = blockIdx.x & 3;
  int p0 = tile * 49;
  if (t < 8) {
    sMu[t] = kf_murs[(b * 8 + t) * 2];
    sRs[t] = kf_murs[(b * 8 + t) * 2 + 1];
    sGmu[t] = kgn_murs[(b * 8 + t) * 2];
    sGrs[t] = kgn_murs[(b * 8 + t) * 2 + 1];
  }
  __syncthreads();
  for (int i = t; i < 128 * 64; i += 256) {
    int c = i >> 6, p = i & 63;
    float v = 0.f;
    if (p < 49) {
      size_t off = ((size_t)(b * 128) + c) * NKk + p0 + p;
      int g = c >> 4;
      v = silu_f((y_kf[off] - sMu[g]) * sRs[g]) + skip_kf[off];
    }
    int kt = c >> 4, kr = c & 15, u = kr >> 2, j = kr & 3, mt = p >> 4;
    kfF[(((kt * 4 + mt) * 64) + (p & 15) + 16 * u) * 4 + j] = (_Float16)v;
  }
  __syncthreads();
  f32x4 z = {0.f, 0.f, 0.f, 0.f};
  f32x4 accG[4][2], accB[4][2];
#pragma unroll
  for (int mt = 0; mt < 4; ++mt)
#pragma unroll
    for (int cc = 0; cc < 2; ++cc) { accG[mt][cc] = z; accB[mt][cc] = z; }
  for (int kt = 0; kt < 8; ++kt) {
    h16x4 a[4];
#pragma unroll
    for (int mt = 0; mt < 4; ++mt)
      a[mt] = *(const h16x4*)&kfF[((kt * 4 + mt) * 64 + l) * 4];
    int fi = (kt * 8 + 2 * w) * 64 + l;
    h16x4 bg0 = *(const h16x4*)(GB + (size_t)fi * 4);
    h16x4 bg1 = *(const h16x4*)(GB + (size_t)(fi + 64) * 4);
    h16x4 bb0 = *(const h16x4*)(BBf + (size_t)fi * 4);
    h16x4 bb1 = *(const h16x4*)(BBf + (size_t)(fi + 64) * 4);
#pragma unroll
    for (int mt = 0; mt < 4; ++mt) {
      accG[mt][0] = mfma16(a[mt], bg0, accG[mt][0]);
      accG[mt][1] = mfma16(a[mt], bg1, accG[mt][1]);
      accB[mt][0] = mfma16(a[mt], bb0, accB[mt][0]);
      accB[mt][1] = mfma16(a[mt], bb1, accB[mt][1]);
    }
  }
  float kfin[4][2][4];
#pragma unroll
  for (int cc = 0; cc < 2; ++cc) {
    int g = 2 * w + cc;
    int co = g * 16 + (l & 15);
    float gmu = sGmu[g], grs = sGrs[g];
#pragma unroll
    for (int mt = 0; mt < 4; ++mt)
#pragma unroll
      for (int r = 0; r < 4; ++r) {
        int pix = mt * 16 + 4 * (l >> 4) + r;
        float v = 0.f;
        if (pix < 49) {
          float kn = (k_pool[((size_t)(b * 128) + co) * NKk + p0 + pix] - gmu) * grs;
          v = fmaf(accG[mt][cc][r], kn, accB[mt][cc][r]);
        }
        kfin[mt][cc][r] = v;
      }
  }
#pragma unroll
  for (int mt = 0; mt < 4; ++mt)
#pragma unroll
    for (int r = 0; r < 4; ++r) {
      float s2 = kfin[mt][0][r] * kfin[mt][0][r] + kfin[mt][1][r] * kfin[mt][1][r];
      for (int m = 1; m < 16; m <<= 1) s2 += __shfl_xor(s2, m);
      if ((l & 15) == 0) msL[w][mt * 16 + 4 * (l >> 4) + r] = s2;
    }
  __syncthreads();
#pragma unroll
  for (int cc = 0; cc < 2; ++cc) {
    int ktn = 2 * w + cc;
    int u = (l & 15) >> 2, j = (l & 15) & 3;
#pragma unroll
    for (int mt = 0; mt < 4; ++mt)
#pragma unroll
      for (int r = 0; r < 4; ++r) {
        int lane = (4 * (l >> 4) + r) + 16 * u;
        kfF[((ktn * 4 + mt) * 64 + lane) * 4 + j] = (_Float16)kfin[mt][cc][r];
      }
  }
  __syncthreads();
  f32x4 accP[4][2];
#pragma unroll
  for (int mt = 0; mt < 4; ++mt)
#pragma unroll
    for (int cc = 0; cc < 2; ++cc) accP[mt][cc] = z;
  for (int kt = 0; kt < 8; ++kt) {
    h16x4 a[4];
#pragma unroll
    for (int mt = 0; mt < 4; ++mt)
      a[mt] = *(const h16x4*)&kfF[((kt * 4 + mt) * 64 + l) * 4];
    int fi = (kt * 8 + 2 * w) * 64 + l;
    h16x4 b0 = *(const h16x4*)(KPB + (size_t)fi * 4);
    h16x4 b1 = *(const h16x4*)(KPB + (size_t)(fi + 64) * 4);
#pragma unroll
    for (int mt = 0; mt < 4; ++mt) {
      accP[mt][0] = mfma16(a[mt], b0, accP[mt][0]);
      accP[mt][1] = mfma16(a[mt], b1, accP[mt][1]);
    }
  }
#pragma unroll
  for (int mt = 0; mt < 4; ++mt)
#pragma unroll
    for (int r = 0; r < 4; ++r) {
      int pix = mt * 16 + 4 * (l >> 4) + r;
      if (pix >= 49) continue;
      float ms = msL[0][pix] + msL[1][pix] + msL[2][pix] + msL[3][pix];
      float rr = rsqrtf(ms * (1.f / 128.f) + EPS_RMS);
#pragma unroll
      for (int cc = 0; cc < 2; ++cc) {
        int co = (2 * w + cc) * 16 + (l & 15);
        kpb[((size_t)(b * 196) + p0 + pix) * 128 + co] =
            accP[mt][cc][r] * rr + k_proj_b[co];
      }
    }
}

// ---------- fused 3x3 conv + RMSNorm + q-proj (MFMA, LDS-staged input) ----------
// grid = BB*196. Block = 8x8 output tile; wave w owns rows [2w,2w+1] (16 px).
// 10x10 halo input tile staged once in LDS (GN'd fp16). Conv computed with
// swapped operands (A=W3 frag, B=input frag) so D = [co][pixel] — which IS
// the B-frag layout the projection needs: pure register conversion, no
// LDS re-stage, no extra barrier. RMS via 2 shfl_xor.
__global__ __launch_bounds__(256) void k_conv3f(
    const float* __restrict__ q_pool, const float* __restrict__ murs2,
    const _Float16* __restrict__ W3B, const _Float16* __restrict__ QPB,
    const float* __restrict__ bias, float* __restrict__ qp) {
  __shared__ __align__(16) _Float16 tileL[100 * 132];  // 26.4 KB
  __shared__ float sMu[8], sRs[8];
  int t = threadIdx.x, l = t & 63, w = t >> 6;
  int b = blockIdx.x / 196, reg = blockIdx.x % 196;
  int y0 = (reg / 14) * 8, x0 = (reg % 14) * 8;
  if (t < 8) { sMu[t] = murs2[(b * 8 + t) * 2]; sRs[t] = murs2[(b * 8 + t) * 2 + 1]; }
  __syncthreads();
  // stage 10x10 halo tile, GN-normalized fp16 (zero outside image)
  for (int i = t; i < 3200; i += 256) {
    int rowp = i >> 5, c4 = i & 31;
    int gy = y0 - 1 + rowp / 10, gx = x0 - 1 + rowp % 10;
    h16x4 hv = {(_Float16)0.f, (_Float16)0.f, (_Float16)0.f, (_Float16)0.f};
    if (gy >= 0 && gy < 112 && gx >= 0 && gx < 112) {
      f32x4 v = *(const f32x4*)(q_pool + ((size_t)(b * NQ) + gy * 112 + gx) * 128 +
                                c4 * 4);
      int g = c4 >> 2;
      float mu = sMu[g], rs = sRs[g];
#pragma unroll
      for (int j = 0; j < 4; ++j) hv[j] = (_Float16)((v[j] - mu) * rs);
    }
    *(h16x4*)&tileL[rowp * 132 + c4 * 4] = hv;
  }
  __syncthreads();
  f32x4 z = {0.f, 0.f, 0.f, 0.f};
  f32x4 acc[8];
#pragma unroll
  for (int ct = 0; ct < 8; ++ct) acc[ct] = z;
  int lm = l & 15;
  int mrow = lm >> 3, mcol = lm & 7;
  int chof = 4 * (l >> 4);
  const h16x4* W3 = (const h16x4*)W3B;
  for (int tap = 0; tap < 9; ++tap) {
    int dy = tap / 3, dx = tap % 3;
    int prow = (2 * w + mrow + dy) * 10 + (mcol + dx);
    const h16x4* wt = W3 + tap * 4096 + l;
#pragma unroll
    for (int kt = 0; kt < 8; ++kt) {
      h16x4 bf = *(const h16x4*)&tileL[prow * 132 + kt * 16 + chof];
#pragma unroll
      for (int ct = 0; ct < 8; ++ct)
        acc[ct] = mfma16(wt[(kt * 8 + ct) * 64], bf, acc[ct]);
    }
  }
  // RMS sumsq: thread holds conv[co=ct*16+chof+r][pixel=lm]; lanes lm, lm+16,
  // lm+32, lm+48 cover all 128 channels of pixel lm.
  float sq = 0.f;
#pragma unroll
  for (int ct = 0; ct < 8; ++ct)
#pragma unroll
    for (int r = 0; r < 4; ++r) sq += acc[ct][r] * acc[ct][r];
  sq += __shfl_xor(sq, 16);
  sq += __shfl_xor(sq, 32);
  float rr = rsqrtf(sq * (1.f / 128.f) + EPS_RMS);
  // conv result is already in projection-B-frag layout: register convert
  h16x4 pb[8];
#pragma unroll
  for (int kt = 0; kt < 8; ++kt)
#pragma unroll
    for (int j = 0; j < 4; ++j) pb[kt][j] = (_Float16)acc[kt][j];
  // projection: A = QPB frag, B = pb
  f32x4 accP[8];
#pragma unroll
  for (int ct = 0; ct < 8; ++ct) accP[ct] = z;
  const h16x4* QP = (const h16x4*)QPB + l;
#pragma unroll
  for (int kt = 0; kt < 8; ++kt) {
#pragma unroll
    for (int ct = 0; ct < 8; ++ct)
      accP[ct] = mfma16(QP[(kt * 8 + ct) * 64], pb[kt], accP[ct]);
  }
  // write qp[pixel][ch]: ch = ct*16 + chof + r, pixel = lm
  int py = y0 + 2 * w + mrow, px = x0 + mcol;
  size_t pbase = ((size_t)(b * NQ) + py * 112 + px) * 128;
#pragma unroll
  for (int ct = 0; ct < 8; ++ct) {
    f32x4 o;
#pragma unroll
    for (int r = 0; r < 4; ++r)
      o[r] = accP[ct][r] * rr + bias[ct * 16 + chof + r];
    *(f32x4*)(qp + pbase + ct * 16 + chof) = o;
  }
}

// ---------- attention: QK^T + softmax + head-mean -> packed fp16 P ----------

__global__ __launch_bounds__(256) void k_attn1m(
    const float* __restrict__ qp, const float* __restrict__ kpb,
    _Float16* __restrict__ Ph) {
  __shared__ float sP[4][16][212];
  int t = threadIdx.x, l = t & 63, h = t >> 6;
  int b = blockIdx.x / 784, qt = blockIdx.x % 784;
  int q0 = qt * 16;
  constexpr float SC = 0.17677669529663687f;  // 1/sqrt(32)
  h16x4 aq[2];
#pragma unroll
  for (int kt = 0; kt < 2; ++kt) {
    f32x4 v = *(const f32x4*)(qp + ((size_t)(b * NQ) + q0 + (l & 15)) * 128 +
                              h * 32 + kt * 16 + 4 * (l >> 4));
    h16x4 ah;
#pragma unroll
    for (int j = 0; j < 4; ++j) ah[j] = (_Float16)v[j];
    aq[kt] = ah;
  }
  f32x4 z = {0.f, 0.f, 0.f, 0.f};
  f32x4 acc[13];
#pragma unroll
  for (int nt = 0; nt < 13; ++nt) acc[nt] = z;
#pragma unroll
  for (int nt = 0; nt < 13; ++nt) {
    int key = nt * 16 + (l & 15);
    bool ok = key < 196;
#pragma unroll
    for (int kt = 0; kt < 2; ++kt) {
      h16x4 bf = {(_Float16)0.f, (_Float16)0.f, (_Float16)0.f, (_Float16)0.f};
      if (ok) {
        f32x4 v = *(const f32x4*)(kpb + ((size_t)(b * 196) + key) * 128 +
                                  h * 32 + kt * 16 + 4 * (l >> 4));
#pragma unroll
        for (int j = 0; j < 4; ++j) bf[j] = (_Float16)v[j];
      }
      acc[nt] = mfma16(aq[kt], bf, acc[nt]);
    }
  }
#pragma unroll
  for (int r = 0; r < 4; ++r) {
    float mx = -3e38f;
#pragma unroll
    for (int nt = 0; nt < 13; ++nt) {
      bool ok = nt * 16 + (l & 15) < 196;
      float v = ok ? acc[nt][r] * SC : -3e38f;
      acc[nt][r] = v;
      mx = fmaxf(mx, v);
    }
    for (int m = 1; m < 16; m <<= 1) mx = fmaxf(mx, __shfl_xor(mx, m));
    float sum = 0.f;
#pragma unroll
    for (int nt = 0; nt < 13; ++nt) {
      bool ok = nt * 16 + (l & 15) < 196;
      float e = ok ? __expf(acc[nt][r] - mx) : 0.f;
      acc[nt][r] = e;
      sum += e;
    }
    for (int m = 1; m < 16; m <<= 1) sum += __shfl_xor(sum, m);
    float inv = 1.f / sum;
#pragma unroll
    for (int nt = 0; nt < 13; ++nt)
      sP[h][4 * (l >> 4) + r][nt * 16 + (l & 15)] = acc[nt][r] * inv;
  }
  __syncthreads();
  _Float16* pb = Ph + (size_t)(b * 784 + qt) * 13 * 256;
  for (int i = t; i < 832; i += 256) {
    int kt = i >> 6, ll = i & 63;
    int q = ll & 15, kb = kt * 16 + 4 * (ll >> 4);
    h16x4 v;
#pragma unroll
    for (int j = 0; j < 4; ++j) {
      int k = kb + j;
      float s = 0.25f * (sP[0][q][k] + sP[1][q][k] + sP[2][q][k] + sP[3][q][k]);
      v[j] = (_Float16)s;
    }
    *(h16x4*)(pb + (size_t)i * 4) = v;
  }
}

// ---------- attention PV: pure fragment streaming, no LDS ----------

__global__ __launch_bounds__(256) void k_attn2m(
    const _Float16* __restrict__ Ph, const _Float16* __restrict__ featB,
    float* __restrict__ out) {
  int t = threadIdx.x, l = t & 63, w = t >> 6;
  int b = blockIdx.x / 196, qt = blockIdx.x % 196;
  int q16 = qt * 4 + w;
  f32x4 z = {0.f, 0.f, 0.f, 0.f};
  f32x4 acc[24];
#pragma unroll
  for (int dt = 0; dt < 24; ++dt) acc[dt] = z;
  const h16x4* PB = (const h16x4*)Ph + ((size_t)(b * 784 + q16) * 13) * 64 + l;
  const h16x4* FB = (const h16x4*)featB + (size_t)b * 13 * 24 * 64 + l;
  for (int kt = 0; kt < 13; ++kt) {
    h16x4 bp = PB[kt * 64];
    const h16x4* fb = FB + kt * 24 * 64;
#pragma unroll
    for (int dt = 0; dt < 24; ++dt)
      acc[dt] = mfma16(fb[(size_t)dt * 64], bp, acc[dt]);
  }
  int qg = q16 * 16 + (l & 15);
#pragma unroll
  for (int dt = 0; dt < 24; ++dt)
#pragma unroll
    for (int r = 0; r < 4; ++r) {
      int d = dt * 16 + 4 * (l >> 4) + r;
      out[((size_t)(b * 384) + d) * NQ + qg] = acc[dt][r];
    }
}

}  // namespace

extern "C" void kernel_launch(void* const* d_in, const int* in_sizes, int n_in,
                              void* d_out, int out_size, void* d_ws,
                              size_t ws_size, hipStream_t stream) {
  (void)in_sizes; (void)n_in; (void)out_size; (void)ws_size;
  const float* image        = (const float*)d_in[0];
  const float* features     = (const float*)d_in[1];
  const float* rope_f       = (const float*)d_in[2];
  const float* img_conv_w   = (const float*)d_in[3];
  const float* img_proj_w   = (const float*)d_in[4];
  const float* qenc_w       = (const float*)d_in[5];
  const float* kenc_w       = (const float*)d_in[6];
  const float* kfeat_conv_w = (const float*)d_in[7];
  const float* kfeat_proj_w = (const float*)d_in[8];
  const float* sft_gamma_w  = (const float*)d_in[9];
  const float* sft_beta_w   = (const float*)d_in[10];
  const float* block_conv_w = (const float*)d_in[11];
  const float* rms_q_w      = (const float*)d_in[12];
  const float* rms_k_w      = (const float*)d_in[13];
  const float* q_proj_w     = (const float*)d_in[14];
  const float* q_proj_b     = (const float*)d_in[15];
  const float* k_proj_w     = (const float*)d_in[16];
  const float* k_proj_b     = (const float*)d_in[17];
  float* out = (float*)d_out;
  float* ws = (float*)d_ws;

  size_t off = 0;
  auto alloc = [&](size_t n) {
    size_t r = off;
    off += (n + 63) & ~(size_t)63;
    return r;
  };
  _Float16* WqB  = (_Float16*)(ws + alloc(8192));
  _Float16* WkB  = (_Float16*)(ws + alloc(8192));
  _Float16* QPB  = (_Float16*)(ws + alloc(8192));
  _Float16* W3B  = (_Float16*)(ws + alloc(73728));
  _Float16* KFB  = (_Float16*)(ws + alloc(24576));
  _Float16* KFPB = (_Float16*)(ws + alloc(24576));
  _Float16* GB   = (_Float16*)(ws + alloc(8192));
  _Float16* BBf  = (_Float16*)(ws + alloc(8192));
  _Float16* KPB  = (_Float16*)(ws + alloc(8192));
  float* cosT     = ws + alloc(14336);
  float* sinT     = ws + alloc(14336);
  _Float16* featB = (_Float16*)(ws + alloc(159744));
  float* imgpart  = ws + alloc(2304);
  float* img_murs = ws + alloc(64);
  float* qk_murs  = ws + alloc(128);
  float* murs2    = ws + alloc(64);
  float* kgn_murs = ws + alloc(64);
  float* kf_murs  = ws + alloc(64);
  float* G        = ws + alloc(65536);
  float* mvec     = ws + alloc(512);
  float* mpart    = ws + alloc(392 * 128);
  float* Qpart    = ws + alloc((size_t)BB * 784 * 16);
  float* kpp      = ws + alloc((size_t)BB * 784 * 128);
  float* y_kf     = ws + alloc(100352);
  float* skip_kf  = ws + alloc(100352);
  float* k_pool   = ws + alloc(100352);
  float* kpb      = ws + alloc(100352);
  // RA (25.7MB): Gpart -> q_pool
  float* RA = ws + alloc((size_t)BB * NQ * 128);
  // ENC (51.4MB): encF -> (qp, Ph)
  float* ENCp = ws + alloc((size_t)BB * 784 * 8192 / 2);
  float* Gpart  = RA;
  float* q_pool = RA;
  _Float16* encF = (_Float16*)ENCp;
  float* qp      = ENCp;                                      // after encF dead
  _Float16* Ph   = (_Float16*)(ENCp + (size_t)BB * NQ * 128); // after qp

  k_prep<<<2648, 256, 0, stream>>>(qenc_w, kenc_w, q_proj_w, rms_q_w,
                                   block_conv_w, kfeat_conv_w, kfeat_proj_w,
                                   sft_gamma_w, sft_beta_w, k_proj_w, rms_k_w,
                                   rope_f, features,
                                   WqB, WkB, QPB, W3B, KFB, KFPB, GB, BBf, KPB,
                                   cosT, sinT, featB);

  k_imgstat1<<<BB * 64, 256, 0, stream>>>(image, imgpart);
  k_imgstat2<<<BB, 128, 0, stream>>>(imgpart, img_conv_w, img_murs);

  k_kf<<<BB * 4, 256, 0, stream>>>(features, KFB, KFPB, y_kf, skip_kf);
  k_gnstats<<<32, 256, 0, stream>>>(y_kf, kf_murs, NKk, EPS_GN);

  k_gram<<<BB * 98, 256, 0, stream>>>(image, cosT, sinT, img_conv_w,
                                      img_proj_w, img_murs, encF, Gpart, mpart);
  k_gred<<<BB * 64, 256, 0, stream>>>(Gpart, mpart, G, mvec);
  k_gstats<<<64, 256, 0, stream>>>(G, mvec, qenc_w, kenc_w, qk_murs);

  k_passA2<<<BB * 784, 256, 0, stream>>>(encF, qk_murs, WqB, WkB,
                                         q_pool, kpp, Qpart);
  k_qstatfin<<<32, 256, 0, stream>>>(Qpart, murs2);
  k_kpred<<<392, 256, 0, stream>>>(kpp, k_pool);
  k_gnstats<<<32, 256, 0, stream>>>(k_pool, kgn_murs, NKk, EPS_GN);

  k_ksft<<<BB * 4, 256, 0, stream>>>(y_kf, skip_kf, kf_murs, kgn_murs,
                                     GB, BBf, KPB, k_pool, k_proj_b, kpb);

  // fused 3x3 conv + RMS + q-proj (LDS-staged input, register-chained proj)
  k_conv3f<<<BB * 196, 256, 0, stream>>>(q_pool, murs2, W3B, QPB, q_proj_b, qp);

  k_attn1m<<<BB * 784, 256, 0, stream>>>(qp, kpb, Ph);
  k_attn2m<<<BB * 196, 256, 0, stream>>>(Ph, featB, out);
}

// Round 13
// 453.896 us; speedup vs baseline: 1.0449x; 1.0449x over previous
//
#include <hip/hip_runtime.h>
#include <cstdint>
#include <cstddef>

#define DEV __device__ __forceinline__

namespace {

constexpr int BB   = 4;
constexpr int HWP  = 50176;   // 224*224
constexpr int NQ   = 12544;   // 112*112
constexpr int NKk  = 196;     // 14*14
constexpr int VD   = 384;
constexpr float EPS_GN  = 1e-5f;
constexpr float EPS_RMS = 1.1920929e-7f;

typedef __attribute__((ext_vector_type(4))) float f32x4;
typedef __attribute__((ext_vector_type(4))) _Float16 h16x4;

DEV float silu_f(float z) { return z / (1.f + __expf(-z)); }
DEV int rfl(int v) { return __builtin_amdgcn_readfirstlane(v); }

DEV f32x4 mfma16(h16x4 a, h16x4 b, f32x4 c) {
  return __builtin_amdgcn_mfma_f32_16x16x16f16(a, b, c, 0, 0, 0);
}

// ---------- fused weight prep (one launch) ----------
DEV void pack16_one(int id, const float* W, const float* rowscale,
                    _Float16* dst) {
  int j = id & 3, l = (id >> 2) & 63, tile = id >> 8;
  int ct = tile & 7, kt = tile >> 3;
  int ci = kt * 16 + 4 * (l >> 4) + j;
  int co = ct * 16 + (l & 15);
  float v = W[(size_t)co * 128 + ci];
  if (rowscale) v *= rowscale[ci];
  dst[id] = (_Float16)v;
}
// pack 128x384 weight into frag order, K=384 (24 kt)
DEV void pack384_one(int id, const float* W, _Float16* dst) {
  int j = id & 3, l = (id >> 2) & 63, rest = id >> 8;
  int ct = rest & 7, kt = rest >> 3;          // kt 0..23
  int ci = kt * 16 + 4 * (l >> 4) + j;
  int co = ct * 16 + (l & 15);
  dst[id] = (_Float16)W[(size_t)co * 384 + ci];
}

__global__ __launch_bounds__(256) void k_prep(
    const float* __restrict__ qenc_w, const float* __restrict__ kenc_w,
    const float* __restrict__ q_proj_w, const float* __restrict__ rms_q_w,
    const float* __restrict__ block_conv_w,
    const float* __restrict__ kfeat_conv_w, const float* __restrict__ kfeat_proj_w,
    const float* __restrict__ sft_gamma_w, const float* __restrict__ sft_beta_w,
    const float* __restrict__ k_proj_w, const float* __restrict__ rms_k_w,
    const float* __restrict__ ropef, const float* __restrict__ feat,
    _Float16* __restrict__ WqB, _Float16* __restrict__ WkB,
    _Float16* __restrict__ QPB, _Float16* __restrict__ W3B,
    _Float16* __restrict__ KFB, _Float16* __restrict__ KFPB,
    _Float16* __restrict__ GB, _Float16* __restrict__ BBf,
    _Float16* __restrict__ KPB,
    float* __restrict__ cosT, float* __restrict__ sinT,
    _Float16* __restrict__ featB) {
  int idx = blockIdx.x * 256 + threadIdx.x;
  if (idx < 16384) {
    pack16_one(idx, qenc_w, nullptr, WqB);
  } else if (idx < 32768) {
    pack16_one(idx - 16384, kenc_w, nullptr, WkB);
  } else if (idx < 49152) {
    pack16_one(idx - 32768, q_proj_w, rms_q_w, QPB);
  } else if (idx < 196608) {
    int id = idx - 49152;
    int j = id & 3, l = (id >> 2) & 63, tile = (id >> 8) & 63, tap = id >> 14;
    int ct = tile & 7, kt = tile >> 3;
    int ci = kt * 16 + 4 * (l >> 4) + j;
    int co = ct * 16 + (l & 15);
    W3B[id] = (_Float16)block_conv_w[((size_t)co * 128 + ci) * 9 + tap];
  } else if (idx < 245760) {
    pack384_one(idx - 196608, kfeat_conv_w, KFB);
  } else if (idx < 294912) {
    pack384_one(idx - 245760, kfeat_proj_w, KFPB);
  } else if (idx < 311296) {
    pack16_one(idx - 294912, sft_gamma_w, nullptr, GB);
  } else if (idx < 327680) {
    pack16_one(idx - 311296, sft_beta_w, nullptr, BBf);
  } else if (idx < 344064) {
    pack16_one(idx - 327680, k_proj_w, rms_k_w, KPB);
  } else if (idx < 358400) {
    int id = idx - 344064;            // pos*64 + d
    int pos = id >> 6, d = id & 63;
    float a = (pos + 0.5f) * (1.f / 224.f) * ropef[d];
    float s, c;
    __sincosf(a, &s, &c);
    cosT[id] = c;
    sinT[id] = s;
  } else if (idx < 677888) {
    int id = idx - 358400;            // (((b*13+kt)*24+dt)*64+l)*4+j
    int j = id & 3, l = (id >> 2) & 63;
    int rest = id >> 8;
    int dt = rest % 24;
    int kt = (rest / 24) % 13;
    int b = rest / (24 * 13);
    int key = kt * 16 + 4 * (l >> 4) + j;
    int d = dt * 16 + (l & 15);
    float v = (key < 196) ? feat[((size_t)(b * 384) + d) * 196 + key] : 0.f;
    featB[id] = (_Float16)v;
  }
}

// ---------- image GN stats via 3x3 Gram ----------

__global__ __launch_bounds__(256) void k_imgstat1(
    const float* __restrict__ img, float* __restrict__ part) {
  __shared__ float lds[4][9];
  int b = blockIdx.x >> 6, blk = blockIdx.x & 63;
  int t = threadIdx.x;
  float a[9];
#pragma unroll
  for (int j = 0; j < 9; ++j) a[j] = 0.f;
  const float* ib = img + (size_t)b * 3 * HWP;
  for (int pix = blk * 784 + t; pix < blk * 784 + 784; pix += 256) {
    float x0 = ib[pix], x1 = ib[HWP + pix], x2 = ib[2 * HWP + pix];
    a[0] += x0; a[1] += x1; a[2] += x2;
    a[3] += x0 * x0; a[4] += x0 * x1; a[5] += x0 * x2;
    a[6] += x1 * x1; a[7] += x1 * x2; a[8] += x2 * x2;
  }
#pragma unroll
  for (int j = 0; j < 9; ++j)
    for (int m = 1; m < 64; m <<= 1) a[j] += __shfl_xor(a[j], m);
  if ((t & 63) == 0)
    for (int j = 0; j < 9; ++j) lds[t >> 6][j] = a[j];
  __syncthreads();
  if (t < 9)
    part[(size_t)blockIdx.x * 9 + t] =
        lds[0][t] + lds[1][t] + lds[2][t] + lds[3][t];
}

__global__ __launch_bounds__(128) void k_imgstat2(
    const float* __restrict__ part, const float* __restrict__ wimg,
    float* __restrict__ img_murs) {
  __shared__ float MG[9];
  int b = blockIdx.x, t = threadIdx.x;
  if (t < 9) {
    float s = 0.f;
    for (int i = 0; i < 64; ++i) s += part[(size_t)(b * 64 + i) * 9 + t];
    MG[t] = s;
  }
  __syncthreads();
  int c = t;
  float w0 = wimg[c * 3], w1 = wimg[c * 3 + 1], w2 = wimg[c * 3 + 2];
  float s1 = w0 * MG[0] + w1 * MG[1] + w2 * MG[2];
  float s2 = w0 * w0 * MG[3] + w1 * w1 * MG[6] + w2 * w2 * MG[8] +
             2.f * (w0 * w1 * MG[4] + w0 * w2 * MG[5] + w1 * w2 * MG[7]);
  for (int m = 1; m < 16; m <<= 1) {
    s1 += __shfl_xor(s1, m);
    s2 += __shfl_xor(s2, m);
  }
  if ((c & 15) == 0) {
    int g = c >> 4;
    float invN = 1.f / (16.f * HWP);
    float mu = s1 * invN;
    float var = s2 * invN - mu * mu;
    img_murs[b * 16 + g] = mu;
    img_murs[b * 16 + 8 + g] = rsqrtf(var + EPS_GN);
  }
}

// ---------- enc producer + Gram + enc_frag materialization ----------

__global__ __launch_bounds__(256) void k_gram(
    const float* __restrict__ img, const float* __restrict__ cosT,
    const float* __restrict__ sinT,
    const float* __restrict__ wimg, const float* __restrict__ wimgp,
    const float* __restrict__ img_murs,
    _Float16* __restrict__ encF,
    float* __restrict__ Gpart, float* __restrict__ mpart) {
  __shared__ __align__(16) _Float16 fragP[2080 * 4];   // [kt*4+mt][lane(65 pad)][j]
  __shared__ __align__(16) _Float16 fragC[8192];       // [pk][ct][lane][j]
  __shared__ float sWc[384], sWp[384], sMu[8], sRs[8];
  int t = threadIdx.x, l = t & 63, w = t >> 6;
  int b = blockIdx.x / 98, blk = blockIdx.x % 98;
  for (int i = t; i < 384; i += 256) { sWc[i] = wimg[i]; sWp[i] = wimgp[i]; }
  if (t < 8) { sMu[t] = img_murs[b * 16 + t]; sRs[t] = img_murs[b * 16 + 8 + t]; }
  f32x4 acc[2][8];
  f32x4 macc[2];
  f32x4 z = {0.f, 0.f, 0.f, 0.f};
#pragma unroll
  for (int e = 0; e < 2; ++e) {
    macc[e] = z;
#pragma unroll
    for (int nt = 0; nt < 8; ++nt) acc[e][nt] = z;
  }
  h16x4 hone = {(_Float16)1.f, (_Float16)1.f, (_Float16)1.f, (_Float16)1.f};
  int mt = l >> 4;
  int laneCbase = 16 * ((l & 15) >> 2);
  int jC = (l & 15) & 3;
  for (int s = 0; s < 8; ++s) {
    int sub = blk * 8 + s;
    int tile = sub >> 2, st = sub & 3;
    int py = (tile / 14) * 16 + ((st >> 1) << 3) + (l >> 3);
    int px = (tile % 14) * 16 + ((st & 1) << 3) + (l & 7);
    __syncthreads();
    {
      const float* ip = img + (size_t)b * 3 * HWP + py * 224 + px;
      float x0 = ip[0], x1 = ip[HWP], x2 = ip[2 * HWP];
      const float* cy = cosT + py * 64 + w * 16;
      const float* sy = sinT + py * 64 + w * 16;
      const float* cx = cosT + px * 64 + w * 16;
      const float* sx = sinT + px * 64 + w * 16;
#pragma unroll
      for (int jj = 0; jj < 4; ++jj) {
        f32x4 cyv = *(const f32x4*)(cy + jj * 4);
        f32x4 syv = *(const f32x4*)(sy + jj * 4);
        f32x4 cxv = *(const f32x4*)(cx + jj * 4);
        f32x4 sxv = *(const f32x4*)(sx + jj * 4);
        h16x4 lo4, hi4;
#pragma unroll
        for (int u = 0; u < 4; ++u) {
          int d = w * 16 + jj * 4 + u;
          int c2 = d + 64;
          float y1 = sWc[d * 3] * x0 + sWc[d * 3 + 1] * x1 + sWc[d * 3 + 2] * x2;
          float s1 = sWp[d * 3] * x0 + sWp[d * 3 + 1] * x1 + sWp[d * 3 + 2] * x2;
          float y2 = sWc[c2 * 3] * x0 + sWc[c2 * 3 + 1] * x1 + sWc[c2 * 3 + 2] * x2;
          float s2 = sWp[c2 * 3] * x0 + sWp[c2 * 3 + 1] * x1 + sWp[c2 * 3 + 2] * x2;
          int g1 = d >> 4, g2 = g1 + 4;
          float t1 = silu_f((y1 - sMu[g1]) * sRs[g1]) + s1;
          float t2 = silu_f((y2 - sMu[g2]) * sRs[g2]) + s2;
          lo4[u] = (_Float16)(t1 * cyv[u] - t2 * syv[u]);
          hi4[u] = (_Float16)(t2 * cxv[u] + t1 * sxv[u]);
        }
        int lane = (l & 15) + 16 * jj;
        *(h16x4*)&fragP[((w * 4 + mt) * 65 + lane) * 4]       = lo4;
        *(h16x4*)&fragP[(((w + 4) * 4 + mt) * 65 + lane) * 4] = hi4;
#pragma unroll
        for (int u = 0; u < 4; ++u) {
          int laneC = jj * 4 + u + laneCbase;
          fragC[((mt * 8 + w) * 64 + laneC) * 4 + jC]     = lo4[u];
          fragC[((mt * 8 + w + 4) * 64 + laneC) * 4 + jC] = hi4[u];
        }
      }
    }
    __syncthreads();
    _Float16* ef = encF + ((size_t)(b * 784) + sub) * 8192;
    for (int i = t; i < 2048; i += 256) {
      int kt = i >> 8, m2 = (i >> 6) & 3, ln = i & 63;
      *(h16x4*)(ef + (size_t)i * 4) =
          *(const h16x4*)&fragP[((kt * 4 + m2) * 65 + ln) * 4];
    }
#pragma unroll
    for (int pk = 0; pk < 4; ++pk) {
      h16x4 a0 = *(const h16x4*)&fragC[((pk * 8 + 2 * w) * 64 + l) * 4];
      h16x4 a1 = *(const h16x4*)&fragC[((pk * 8 + 2 * w + 1) * 64 + l) * 4];
      macc[0] = mfma16(a0, hone, macc[0]);
      macc[1] = mfma16(a1, hone, macc[1]);
#pragma unroll
      for (int nt = 0; nt < 8; ++nt) {
        h16x4 bv = *(const h16x4*)&fragC[((pk * 8 + nt) * 64 + l) * 4];
        acc[0][nt] = mfma16(a0, bv, acc[0][nt]);
        acc[1][nt] = mfma16(a1, bv, acc[1][nt]);
      }
    }
  }
  float* gp = Gpart + (size_t)(b * 98 + blk) * 16384;
#pragma unroll
  for (int e = 0; e < 2; ++e)
#pragma unroll
    for (int nt = 0; nt < 8; ++nt)
#pragma unroll
      for (int r = 0; r < 4; ++r) {
        int row = (2 * w + e) * 16 + 4 * (l >> 4) + r;
        int col = nt * 16 + (l & 15);
        gp[row * 128 + col] = acc[e][nt][r];
      }
  if ((l & 15) == 0) {
    float* mp = mpart + (size_t)(b * 98 + blk) * 128;
#pragma unroll
    for (int e = 0; e < 2; ++e)
#pragma unroll
      for (int r = 0; r < 4; ++r)
        mp[(2 * w + e) * 16 + 4 * (l >> 4) + r] = macc[e][r];
  }
}

__global__ void k_gred(const float* __restrict__ Gpart,
                       const float* __restrict__ mpart,
                       float* __restrict__ G, float* __restrict__ mvec) {
  int b = blockIdx.x >> 6, chunk = blockIdx.x & 63;
  int idx = chunk * 256 + threadIdx.x;
  float s = 0.f;
  for (int i = 0; i < 98; ++i) s += Gpart[(size_t)(b * 98 + i) * 16384 + idx];
  G[(size_t)b * 16384 + idx] = s;
  if (idx < 128) {
    float sm = 0.f;
    for (int i = 0; i < 98; ++i) sm += mpart[(size_t)(b * 98 + i) * 128 + idx];
    mvec[b * 128 + idx] = sm;
  }
}

__global__ __launch_bounds__(256) void k_gstats(
    const float* __restrict__ G, const float* __restrict__ mvec,
    const float* __restrict__ qw, const float* __restrict__ kw,
    float* __restrict__ qk_murs) {
  __shared__ float red1[4], red2[4];
  int bi = blockIdx.x;               // conv*32 + b*8 + g
  int conv = bi >> 5, b = (bi >> 3) & 3, g = bi & 7;
  const float* W = conv ? kw : qw;
  int t = threadIdx.x;
  int c = g * 16 + (t >> 4);
  int i0 = (t & 15) * 8;
  const float* wc = W + (size_t)c * 128;
  const float* Gb = G + (size_t)b * 16384;
  const float* mb = mvec + b * 128;
  float s1 = 0.f, s2 = 0.f;
  for (int i = i0; i < i0 + 8; ++i) {
    float gi = 0.f;
    for (int j = 0; j < 128; ++j) gi += Gb[i * 128 + j] * wc[j];
    s2 += wc[i] * gi;
    s1 += wc[i] * mb[i];
  }
  for (int m = 1; m < 64; m <<= 1) { s1 += __shfl_xor(s1, m); s2 += __shfl_xor(s2, m); }
  if ((t & 63) == 0) { red1[t >> 6] = s1; red2[t >> 6] = s2; }
  __syncthreads();
  if (t == 0) {
    float S1 = red1[0] + red1[1] + red1[2] + red1[3];
    float S2 = red2[0] + red2[1] + red2[2] + red2[3];
    float invN = 1.f / 802816.f;
    float mu = S1 * invN;
    float var = S2 * invN - mu * mu;
    qk_murs[bi * 2] = mu;
    qk_murs[bi * 2 + 1] = rsqrtf(var + EPS_GN);
  }
}

// ---------- pass A: q/k enc_blocks from encF, swapped operands ----------

__global__ __launch_bounds__(256) void k_passA2(
    const _Float16* __restrict__ encF, const float* __restrict__ qk_murs,
    const _Float16* __restrict__ WqB, const _Float16* __restrict__ WkB,
    float* __restrict__ q_pool, float* __restrict__ kpp,
    float* __restrict__ Qpart) {
  int t = threadIdx.x, l = t & 63;
  int wu = rfl(t >> 6);
  int bi = blockIdx.x;
  int b = bi / 784, sub = bi % 784;
  int tile = sub >> 2, st = sub & 3;
  int by = (tile / 14) * 16, bx = (tile % 14) * 16;
  float qmu[2], qrs[2], kmu[2], krs[2];
#pragma unroll
  for (int cc = 0; cc < 2; ++cc) {
    int g = 2 * wu + cc;
    qmu[cc] = qk_murs[(b * 8 + g) * 2];
    qrs[cc] = qk_murs[(b * 8 + g) * 2 + 1];
    kmu[cc] = qk_murs[(32 + b * 8 + g) * 2];
    krs[cc] = qk_murs[(32 + b * 8 + g) * 2 + 1];
  }
  const h16x4* EF = (const h16x4*)encF + ((size_t)(b * 784) + sub) * 2048;
  f32x4 z = {0.f, 0.f, 0.f, 0.f};
  f32x4 accQ[4][2], accK[4][2];
  h16x4 sf[2][4];
#pragma unroll
  for (int mt = 0; mt < 4; ++mt)
#pragma unroll
    for (int cc = 0; cc < 2; ++cc) { accQ[mt][cc] = z; accK[mt][cc] = z; }
  for (int kt = 0; kt < 8; ++kt) {
    h16x4 a[4];
#pragma unroll
    for (int mt = 0; mt < 4; ++mt) a[mt] = EF[(kt * 4 + mt) * 64 + l];
    if ((kt >> 1) == wu) {
#pragma unroll
      for (int mt = 0; mt < 4; ++mt) sf[kt & 1][mt] = a[mt];
    }
    int fi = (kt * 8 + 2 * wu) * 64 + l;
    h16x4 bq0 = *(const h16x4*)(WqB + (size_t)fi * 4);
    h16x4 bq1 = *(const h16x4*)(WqB + (size_t)(fi + 64) * 4);
    h16x4 bk0 = *(const h16x4*)(WkB + (size_t)fi * 4);
    h16x4 bk1 = *(const h16x4*)(WkB + (size_t)(fi + 64) * 4);
#pragma unroll
    for (int mt = 0; mt < 4; ++mt) {
      accQ[mt][0] = mfma16(bq0, a[mt], accQ[mt][0]);
      accQ[mt][1] = mfma16(bq1, a[mt], accQ[mt][1]);
      accK[mt][0] = mfma16(bk0, a[mt], accK[mt][0]);
      accK[mt][1] = mfma16(bk1, a[mt], accK[mt][1]);
    }
  }
  int q = l & 15;
  bool act = (q & 9) == 0;
  float kacc[2][4];
  float qs1[2] = {0.f, 0.f}, qs2[2] = {0.f, 0.f};
#pragma unroll
  for (int cc = 0; cc < 2; ++cc)
#pragma unroll
    for (int r = 0; r < 4; ++r) kacc[cc][r] = 0.f;
#pragma unroll
  for (int cc = 0; cc < 2; ++cc) {
    int g = 2 * wu + cc;
#pragma unroll
    for (int mt = 0; mt < 4; ++mt) {
      f32x4 pv;
#pragma unroll
      for (int r = 0; r < 4; ++r) {
        float skip = (float)sf[cc][mt][r];
        pv[r] = silu_f((accQ[mt][cc][r] - qmu[cc]) * qrs[cc]) + skip;
        kacc[cc][r] += silu_f((accK[mt][cc][r] - kmu[cc]) * krs[cc]) + skip;
      }
#pragma unroll
      for (int r = 0; r < 4; ++r) {
        float v = pv[r] + __shfl_xor(pv[r], 1);
        v += __shfl_xor(v, 8);
        pv[r] = v * 0.25f;
      }
      if (act) {
        int p = mt * 16 + q;
        int py = by + (st >> 1) * 8 + (p >> 3);
        int px = bx + (st & 1) * 8 + (p & 7);
        size_t base = ((size_t)(b * NQ) + (py >> 1) * 112 + (px >> 1)) * 128 +
                      g * 16 + 4 * (l >> 4);
        *(f32x4*)(q_pool + base) = pv;
        qs1[cc] += pv[0] + pv[1] + pv[2] + pv[3];
        qs2[cc] += pv[0] * pv[0] + pv[1] * pv[1] + pv[2] * pv[2] + pv[3] * pv[3];
      }
    }
  }
#pragma unroll
  for (int cc = 0; cc < 2; ++cc) {
#pragma unroll
    for (int r = 0; r < 4; ++r) {
      float v = kacc[cc][r];
      v += __shfl_xor(v, 1);
      v += __shfl_xor(v, 2);
      v += __shfl_xor(v, 4);
      v += __shfl_xor(v, 8);
      kacc[cc][r] = v;
    }
    if (q == 0) {
      f32x4 kv = {kacc[cc][0], kacc[cc][1], kacc[cc][2], kacc[cc][3]};
      *(f32x4*)(kpp + (size_t)bi * 128 + (2 * wu + cc) * 16 + 4 * (l >> 4)) = kv;
    }
  }
#pragma unroll
  for (int cc = 0; cc < 2; ++cc) {
    float a1 = qs1[cc], a2 = qs2[cc];
    for (int m = 1; m < 64; m <<= 1) {
      a1 += __shfl_xor(a1, m);
      a2 += __shfl_xor(a2, m);
    }
    if (l == 0) {
      Qpart[(size_t)bi * 16 + (2 * wu + cc) * 2] = a1;
      Qpart[(size_t)bi * 16 + (2 * wu + cc) * 2 + 1] = a2;
    }
  }
}

__global__ __launch_bounds__(256) void k_kpred(
    const float* __restrict__ kpp, float* __restrict__ k_pool) {
  int idx = blockIdx.x * 256 + threadIdx.x;
  if (idx >= BB * 128 * NKk) return;
  int b = idx / (128 * NKk);
  int rem = idx % (128 * NKk);
  int c = rem / NKk, tile = rem % NKk;
  const float* base = kpp + ((size_t)(b * 196 + tile) * 4) * 128 + c;
  float s = base[0] + base[128] + base[256] + base[384];
  k_pool[idx] = s * (1.f / 256.f);
}

__global__ __launch_bounds__(256) void k_qstatfin(
    const float* __restrict__ Qpart, float* __restrict__ murs2) {
  __shared__ float l1[4], l2[4];
  int b = blockIdx.x >> 3, g = blockIdx.x & 7, t = threadIdx.x;
  float s1 = 0.f, s2 = 0.f;
  for (int i = t; i < 784; i += 256) {
    s1 += Qpart[((size_t)(b * 784) + i) * 16 + g * 2];
    s2 += Qpart[((size_t)(b * 784) + i) * 16 + g * 2 + 1];
  }
  for (int m = 1; m < 64; m <<= 1) { s1 += __shfl_xor(s1, m); s2 += __shfl_xor(s2, m); }
  if ((t & 63) == 0) { l1[t >> 6] = s1; l2[t >> 6] = s2; }
  __syncthreads();
  if (t == 0) {
    float a = l1[0] + l1[1] + l1[2] + l1[3];
    float bq = l2[0] + l2[1] + l2[2] + l2[3];
    float invN = 1.f / (16.f * (float)NQ);
    float mu = a * invN;
    float var = bq * invN - mu * mu;
    murs2[blockIdx.x * 2] = mu;
    murs2[blockIdx.x * 2 + 1] = rsqrtf(var + EPS_GN);
  }
}

// ---------- GN stats (channel-major src[b][c][P]) ----------

__global__ __launch_bounds__(256) void k_gnstats(
    const float* __restrict__ src, float* __restrict__ murs, int P, float eps) {
  __shared__ float l1[4], l2[4];
  int b = blockIdx.x >> 3, g = blockIdx.x & 7, t = threadIdx.x;
  const float* base = src + ((size_t)(b * 128) + g * 16) * P;
  float s1 = 0.f, s2 = 0.f;
  for (int i = t; i < 16 * P; i += 256) {
    float v = base[i];
    s1 += v; s2 += v * v;
  }
  for (int m = 1; m < 64; m <<= 1) { s1 += __shfl_xor(s1, m); s2 += __shfl_xor(s2, m); }
  if ((t & 63) == 0) { l1[t >> 6] = s1; l2[t >> 6] = s2; }
  __syncthreads();
  if (t == 0) {
    float invN = 1.f / (16.f * (float)P);
    float a = l1[0] + l1[1] + l1[2] + l1[3];
    float bq = l2[0] + l2[1] + l2[2] + l2[3];
    float mu = a * invN;
    float var = bq * invN - mu * mu;
    murs[blockIdx.x * 2] = mu;
    murs[blockIdx.x * 2 + 1] = rsqrtf(var + eps);
  }
}

// ---------- kf branch: fused L2-norm + 384->128 conv+proj (MFMA) ----------

__global__ __launch_bounds__(256) void k_kf(
    const float* __restrict__ feat,
    const _Float16* __restrict__ KFB, const _Float16* __restrict__ KFPB,
    float* __restrict__ y_kf, float* __restrict__ skip_kf) {
  __shared__ __align__(16) _Float16 fnF[24 * 4 * 64 * 4];  // 48KB, A-frags
  __shared__ float ssqL[4][64];
  __shared__ float rsqL[64];
  int t = threadIdx.x, l = t & 63, w = t >> 6;
  int b = blockIdx.x >> 2, tile = blockIdx.x & 3;
  int p0 = tile * 49;
  const float* fb = feat + (size_t)b * VD * NKk;
  {
    float s = 0.f;
    if (l < 49) {
#pragma unroll 4
      for (int k = w; k < VD; k += 4) {
        float v = fb[(size_t)k * NKk + p0 + l];
        s += v * v;
      }
    }
    ssqL[w][l] = s;
  }
  __syncthreads();
  if (t < 64) {
    float s = ssqL[0][t] + ssqL[1][t] + ssqL[2][t] + ssqL[3][t];
    rsqL[t] = rsqrtf(fmaxf(s, 1e-24f));
  }
  __syncthreads();
  for (int i = t; i < VD * 64; i += 256) {
    int k = i >> 6, p = i & 63;
    float v = 0.f;
    if (p < 49) v = fb[(size_t)k * NKk + p0 + p] * rsqL[p];
    int kt = k >> 4, kr = k & 15, u = kr >> 2, j = kr & 3, mt = p >> 4;
    fnF[(((kt * 4 + mt) * 64) + (p & 15) + 16 * u) * 4 + j] = (_Float16)v;
  }
  __syncthreads();
  f32x4 z = {0.f, 0.f, 0.f, 0.f};
  f32x4 accY[4][2], accS[4][2];
#pragma unroll
  for (int mt = 0; mt < 4; ++mt)
#pragma unroll
    for (int cc = 0; cc < 2; ++cc) { accY[mt][cc] = z; accS[mt][cc] = z; }
  for (int kt = 0; kt < 24; ++kt) {
    h16x4 a[4];
#pragma unroll
    for (int mt = 0; mt < 4; ++mt)
      a[mt] = *(const h16x4*)&fnF[((kt * 4 + mt) * 64 + l) * 4];
    int fi = (kt * 8 + 2 * w) * 64 + l;
    h16x4 by0 = *(const h16x4*)(KFB + (size_t)fi * 4);
    h16x4 by1 = *(const h16x4*)(KFB + (size_t)(fi + 64) * 4);
    h16x4 bs0 = *(const h16x4*)(KFPB + (size_t)fi * 4);
    h16x4 bs1 = *(const h16x4*)(KFPB + (size_t)(fi + 64) * 4);
#pragma unroll
    for (int mt = 0; mt < 4; ++mt) {
      accY[mt][0] = mfma16(a[mt], by0, accY[mt][0]);
      accY[mt][1] = mfma16(a[mt], by1, accY[mt][1]);
      accS[mt][0] = mfma16(a[mt], bs0, accS[mt][0]);
      accS[mt][1] = mfma16(a[mt], bs1, accS[mt][1]);
    }
  }
#pragma unroll
  for (int cc = 0; cc < 2; ++cc) {
    int co = (2 * w + cc) * 16 + (l & 15);
#pragma unroll
    for (int mt = 0; mt < 4; ++mt)
#pragma unroll
      for (int r = 0; r < 4; ++r) {
        int pix = mt * 16 + 4 * (l >> 4) + r;
        if (pix < 49) {
          size_t off = ((size_t)(b * 128) + co) * NKk + p0 + pix;
          y_kf[off] = accY[mt][cc][r];
          skip_kf[off] = accS[mt][cc][r];
        }
      }
  }
}

// ---------- merged SFT + RMSNorm + k-proj (MFMA) ----------

__global__ __launch_bounds__(256) void k_ksft(
    const float* __restrict__ y_kf, const float* __restrict__ skip_kf,
    const float* __restrict__ kf_murs, const float* __restrict__ kgn_murs,
    const _Float16* __restrict__ GB, const _Float16* __restrict__ BBf,
    const _Float16* __restrict__ KPB,
    const float* __restrict__ k_pool, const float* __restrict__ k_proj_b,
    float* __restrict__ kpb) {
  __shared__ __align__(16) _Float16 kfF[8 * 4 * 64 * 4];  // 16KB A-frags
  __shared__ float msL[4][64];
  __shared__ float sMu[8], sRs[8], sGmu[8], sGrs[8];
  int t = threadIdx.x, l = t & 63, w = t >> 6;
  int b = blockIdx.x >> 2, tile = blockIdx.x & 3;
  int p0 = tile * 49;
  if (t < 8) {
    sMu[t] = kf_murs[(b * 8 + t) * 2];
    sRs[t] = kf_murs[(b * 8 + t) * 2 + 1];
    sGmu[t] = kgn_murs[(b * 8 + t) * 2];
    sGrs[t] = kgn_murs[(b * 8 + t) * 2 + 1];
  }
  __syncthreads();
  for (int i = t; i < 128 * 64; i += 256) {
    int c = i >> 6, p = i & 63;
    float v = 0.f;
    if (p < 49) {
      size_t off = ((size_t)(b * 128) + c) * NKk + p0 + p;
      int g = c >> 4;
      v = silu_f((y_kf[off] - sMu[g]) * sRs[g]) + skip_kf[off];
    }
    int kt = c >> 4, kr = c & 15, u = kr >> 2, j = kr & 3, mt = p >> 4;
    kfF[(((kt * 4 + mt) * 64) + (p & 15) + 16 * u) * 4 + j] = (_Float16)v;
  }
  __syncthreads();
  f32x4 z = {0.f, 0.f, 0.f, 0.f};
  f32x4 accG[4][2], accB[4][2];
#pragma unroll
  for (int mt = 0; mt < 4; ++mt)
#pragma unroll
    for (int cc = 0; cc < 2; ++cc) { accG[mt][cc] = z; accB[mt][cc] = z; }
  for (int kt = 0; kt < 8; ++kt) {
    h16x4 a[4];
#pragma unroll
    for (int mt = 0; mt < 4; ++mt)
      a[mt] = *(const h16x4*)&kfF[((kt * 4 + mt) * 64 + l) * 4];
    int fi = (kt * 8 + 2 * w) * 64 + l;
    h16x4 bg0 = *(const h16x4*)(GB + (size_t)fi * 4);
    h16x4 bg1 = *(const h16x4*)(GB + (size_t)(fi + 64) * 4);
    h16x4 bb0 = *(const h16x4*)(BBf + (size_t)fi * 4);
    h16x4 bb1 = *(const h16x4*)(BBf + (size_t)(fi + 64) * 4);
#pragma unroll
    for (int mt = 0; mt < 4; ++mt) {
      accG[mt][0] = mfma16(a[mt], bg0, accG[mt][0]);
      accG[mt][1] = mfma16(a[mt], bg1, accG[mt][1]);
      accB[mt][0] = mfma16(a[mt], bb0, accB[mt][0]);
      accB[mt][1] = mfma16(a[mt], bb1, accB[mt][1]);
    }
  }
  float kfin[4][2][4];
#pragma unroll
  for (int cc = 0; cc < 2; ++cc) {
    int g = 2 * w + cc;
    int co = g * 16 + (l & 15);
    float gmu = sGmu[g], grs = sGrs[g];
#pragma unroll
    for (int mt = 0; mt < 4; ++mt)
#pragma unroll
      for (int r = 0; r < 4; ++r) {
        int pix = mt * 16 + 4 * (l >> 4) + r;
        float v = 0.f;
        if (pix < 49) {
          float kn = (k_pool[((size_t)(b * 128) + co) * NKk + p0 + pix] - gmu) * grs;
          v = fmaf(accG[mt][cc][r], kn, accB[mt][cc][r]);
        }
        kfin[mt][cc][r] = v;
      }
  }
#pragma unroll
  for (int mt = 0; mt < 4; ++mt)
#pragma unroll
    for (int r = 0; r < 4; ++r) {
      float s2 = kfin[mt][0][r] * kfin[mt][0][r] + kfin[mt][1][r] * kfin[mt][1][r];
      for (int m = 1; m < 16; m <<= 1) s2 += __shfl_xor(s2, m);
      if ((l & 15) == 0) msL[w][mt * 16 + 4 * (l >> 4) + r] = s2;
    }
  __syncthreads();
#pragma unroll
  for (int cc = 0; cc < 2; ++cc) {
    int ktn = 2 * w + cc;
    int u = (l & 15) >> 2, j = (l & 15) & 3;
#pragma unroll
    for (int mt = 0; mt < 4; ++mt)
#pragma unroll
      for (int r = 0; r < 4; ++r) {
        int lane = (4 * (l >> 4) + r) + 16 * u;
        kfF[((ktn * 4 + mt) * 64 + lane) * 4 + j] = (_Float16)kfin[mt][cc][r];
      }
  }
  __syncthreads();
  f32x4 accP[4][2];
#pragma unroll
  for (int mt = 0; mt < 4; ++mt)
#pragma unroll
    for (int cc = 0; cc < 2; ++cc) accP[mt][cc] = z;
  for (int kt = 0; kt < 8; ++kt) {
    h16x4 a[4];
#pragma unroll
    for (int mt = 0; mt < 4; ++mt)
      a[mt] = *(const h16x4*)&kfF[((kt * 4 + mt) * 64 + l) * 4];
    int fi = (kt * 8 + 2 * w) * 64 + l;
    h16x4 b0 = *(const h16x4*)(KPB + (size_t)fi * 4);
    h16x4 b1 = *(const h16x4*)(KPB + (size_t)(fi + 64) * 4);
#pragma unroll
    for (int mt = 0; mt < 4; ++mt) {
      accP[mt][0] = mfma16(a[mt], b0, accP[mt][0]);
      accP[mt][1] = mfma16(a[mt], b1, accP[mt][1]);
    }
  }
#pragma unroll
  for (int mt = 0; mt < 4; ++mt)
#pragma unroll
    for (int r = 0; r < 4; ++r) {
      int pix = mt * 16 + 4 * (l >> 4) + r;
      if (pix >= 49) continue;
      float ms = msL[0][pix] + msL[1][pix] + msL[2][pix] + msL[3][pix];
      float rr = rsqrtf(ms * (1.f / 128.f) + EPS_RMS);
#pragma unroll
      for (int cc = 0; cc < 2; ++cc) {
        int co = (2 * w + cc) * 16 + (l & 15);
        kpb[((size_t)(b * 196) + p0 + pix) * 128 + co] =
            accP[mt][cc][r] * rr + k_proj_b[co];
      }
    }
}

// ---------- fused 3x3 conv + RMSNorm + q-proj (MFMA, LDS input, SW-pipelined
// weight stream) ----------
// grid = BB*196. Block = 8x8 output tile; wave w owns rows [2w,2w+1] (16 px).
// 10x10 halo input staged once in LDS (GN'd fp16). Weight frags streamed
// from L2 with an explicit distance-2 prefetch (3 register buffers, loop
// fully unrolled so all buffer indices are compile-time).
__global__ __launch_bounds__(256) void k_conv3f(
    const float* __restrict__ q_pool, const float* __restrict__ murs2,
    const _Float16* __restrict__ W3B, const _Float16* __restrict__ QPB,
    const float* __restrict__ bias, float* __restrict__ qp) {
  __shared__ __align__(16) _Float16 tileL[100 * 132];  // 26.4 KB
  __shared__ float sMu[8], sRs[8];
  int t = threadIdx.x, l = t & 63, w = t >> 6;
  int b = blockIdx.x / 196, reg = blockIdx.x % 196;
  int y0 = (reg / 14) * 8, x0 = (reg % 14) * 8;
  if (t < 8) { sMu[t] = murs2[(b * 8 + t) * 2]; sRs[t] = murs2[(b * 8 + t) * 2 + 1]; }
  __syncthreads();
  // stage 10x10 halo tile, GN-normalized fp16 (zero outside image)
  for (int i = t; i < 3200; i += 256) {
    int rowp = i >> 5, c4 = i & 31;
    int gy = y0 - 1 + rowp / 10, gx = x0 - 1 + rowp % 10;
    h16x4 hv = {(_Float16)0.f, (_Float16)0.f, (_Float16)0.f, (_Float16)0.f};
    if (gy >= 0 && gy < 112 && gx >= 0 && gx < 112) {
      f32x4 v = *(const f32x4*)(q_pool + ((size_t)(b * NQ) + gy * 112 + gx) * 128 +
                                c4 * 4);
      int g = c4 >> 2;
      float mu = sMu[g], rs = sRs[g];
#pragma unroll
      for (int j = 0; j < 4; ++j) hv[j] = (_Float16)((v[j] - mu) * rs);
    }
    *(h16x4*)&tileL[rowp * 132 + c4 * 4] = hv;
  }
  __syncthreads();
  f32x4 z = {0.f, 0.f, 0.f, 0.f};
  f32x4 acc[8];
#pragma unroll
  for (int ct = 0; ct < 8; ++ct) acc[ct] = z;
  int lm = l & 15;
  int mrow = lm >> 3, mcol = lm & 7;
  int chof = 4 * (l >> 4);
  const h16x4* W3l = (const h16x4*)W3B + l;
  // software-pipelined weight stream: distance-2 prefetch, 3 buffers
  h16x4 wbuf[3][8];
#pragma unroll
  for (int ct = 0; ct < 8; ++ct) wbuf[0][ct] = W3l[ct * 64];             // s=0
#pragma unroll
  for (int ct = 0; ct < 8; ++ct) wbuf[1][ct] = W3l[(8 + ct) * 64];       // s=1
#pragma unroll
  for (int s = 0; s < 72; ++s) {
    if (s + 2 < 72) {
      int tap2 = (s + 2) >> 3, kt2 = (s + 2) & 7;
#pragma unroll
      for (int ct = 0; ct < 8; ++ct)
        wbuf[(s + 2) % 3][ct] = W3l[tap2 * 4096 + (kt2 * 8 + ct) * 64];
    }
    int tap = s >> 3, kt = s & 7;
    int prow = (2 * w + mrow + tap / 3) * 10 + (mcol + tap % 3);
    h16x4 bf = *(const h16x4*)&tileL[prow * 132 + kt * 16 + chof];
#pragma unroll
    for (int ct = 0; ct < 8; ++ct)
      acc[ct] = mfma16(wbuf[s % 3][ct], bf, acc[ct]);
  }
  // RMS sumsq: lanes lm, lm+16, lm+32, lm+48 cover all 128 ch of pixel lm.
  float sq = 0.f;
#pragma unroll
  for (int ct = 0; ct < 8; ++ct)
#pragma unroll
    for (int r = 0; r < 4; ++r) sq += acc[ct][r] * acc[ct][r];
  sq += __shfl_xor(sq, 16);
  sq += __shfl_xor(sq, 32);
  float rr = rsqrtf(sq * (1.f / 128.f) + EPS_RMS);
  // conv result is already in projection-B-frag layout: register convert
  h16x4 pb[8];
#pragma unroll
  for (int kt = 0; kt < 8; ++kt)
#pragma unroll
    for (int j = 0; j < 4; ++j) pb[kt][j] = (_Float16)acc[kt][j];
  // projection: A = QPB frag, B = pb
  f32x4 accP[8];
#pragma unroll
  for (int ct = 0; ct < 8; ++ct) accP[ct] = z;
  const h16x4* QP = (const h16x4*)QPB + l;
#pragma unroll
  for (int kt = 0; kt < 8; ++kt) {
#pragma unroll
    for (int ct = 0; ct < 8; ++ct)
      accP[ct] = mfma16(QP[(kt * 8 + ct) * 64], pb[kt], accP[ct]);
  }
  // write qp[pixel][ch]: ch = ct*16 + chof + r, pixel = lm
  int py = y0 + 2 * w + mrow, px = x0 + mcol;
  size_t pbase = ((size_t)(b * NQ) + py * 112 + px) * 128;
#pragma unroll
  for (int ct = 0; ct < 8; ++ct) {
    f32x4 o;
#pragma unroll
    for (int r = 0; r < 4; ++r)
      o[r] = accP[ct][r] * rr + bias[ct * 16 + chof + r];
    *(f32x4*)(qp + pbase + ct * 16 + chof) = o;
  }
}

// ---------- attention: QK^T + softmax + head-mean -> packed fp16 P ----------

__global__ __launch_bounds__(256) void k_attn1m(
    const float* __restrict__ qp, const float* __restrict__ kpb,
    _Float16* __restrict__ Ph) {
  __shared__ float sP[4][16][212];
  int t = threadIdx.x, l = t & 63, h = t >> 6;
  int b = blockIdx.x / 784, qt = blockIdx.x % 784;
  int q0 = qt * 16;
  constexpr float SC = 0.17677669529663687f;  // 1/sqrt(32)
  h16x4 aq[2];
#pragma unroll
  for (int kt = 0; kt < 2; ++kt) {
    f32x4 v = *(const f32x4*)(qp + ((size_t)(b * NQ) + q0 + (l & 15)) * 128 +
                              h * 32 + kt * 16 + 4 * (l >> 4));
    h16x4 ah;
#pragma unroll
    for (int j = 0; j < 4; ++j) ah[j] = (_Float16)v[j];
    aq[kt] = ah;
  }
  f32x4 z = {0.f, 0.f, 0.f, 0.f};
  f32x4 acc[13];
#pragma unroll
  for (int nt = 0; nt < 13; ++nt) acc[nt] = z;
#pragma unroll
  for (int nt = 0; nt < 13; ++nt) {
    int key = nt * 16 + (l & 15);
    bool ok = key < 196;
#pragma unroll
    for (int kt = 0; kt < 2; ++kt) {
      h16x4 bf = {(_Float16)0.f, (_Float16)0.f, (_Float16)0.f, (_Float16)0.f};
      if (ok) {
        f32x4 v = *(const f32x4*)(kpb + ((size_t)(b * 196) + key) * 128 +
                                  h * 32 + kt * 16 + 4 * (l >> 4));
#pragma unroll
        for (int j = 0; j < 4; ++j) bf[j] = (_Float16)v[j];
      }
      acc[nt] = mfma16(aq[kt], bf, acc[nt]);
    }
  }
#pragma unroll
  for (int r = 0; r < 4; ++r) {
    float mx = -3e38f;
#pragma unroll
    for (int nt = 0; nt < 13; ++nt) {
      bool ok = nt * 16 + (l & 15) < 196;
      float v = ok ? acc[nt][r] * SC : -3e38f;
      acc[nt][r] = v;
      mx = fmaxf(mx, v);
    }
    for (int m = 1; m < 16; m <<= 1) mx = fmaxf(mx, __shfl_xor(mx, m));
    float sum = 0.f;
#pragma unroll
    for (int nt = 0; nt < 13; ++nt) {
      bool ok = nt * 16 + (l & 15) < 196;
      float e = ok ? __expf(acc[nt][r] - mx) : 0.f;
      acc[nt][r] = e;
      sum += e;
    }
    for (int m = 1; m < 16; m <<= 1) sum += __shfl_xor(sum, m);
    float inv = 1.f / sum;
#pragma unroll
    for (int nt = 0; nt < 13; ++nt)
      sP[h][4 * (l >> 4) + r][nt * 16 + (l & 15)] = acc[nt][r] * inv;
  }
  __syncthreads();
  _Float16* pb = Ph + (size_t)(b * 784 + qt) * 13 * 256;
  for (int i = t; i < 832; i += 256) {
    int kt = i >> 6, ll = i & 63;
    int q = ll & 15, kb = kt * 16 + 4 * (ll >> 4);
    h16x4 v;
#pragma unroll
    for (int j = 0; j < 4; ++j) {
      int k = kb + j;
      float s = 0.25f * (sP[0][q][k] + sP[1][q][k] + sP[2][q][k] + sP[3][q][k]);
      v[j] = (_Float16)s;
    }
    *(h16x4*)(pb + (size_t)i * 4) = v;
  }
}

// ---------- attention PV: pure fragment streaming, no LDS ----------

__global__ __launch_bounds__(256) void k_attn2m(
    const _Float16* __restrict__ Ph, const _Float16* __restrict__ featB,
    float* __restrict__ out) {
  int t = threadIdx.x, l = t & 63, w = t >> 6;
  int b = blockIdx.x / 196, qt = blockIdx.x % 196;
  int q16 = qt * 4 + w;
  f32x4 z = {0.f, 0.f, 0.f, 0.f};
  f32x4 acc[24];
#pragma unroll
  for (int dt = 0; dt < 24; ++dt) acc[dt] = z;
  const h16x4* PB = (const h16x4*)Ph + ((size_t)(b * 784 + q16) * 13) * 64 + l;
  const h16x4* FB = (const h16x4*)featB + (size_t)b * 13 * 24 * 64 + l;
  for (int kt = 0; kt < 13; ++kt) {
    h16x4 bp = PB[kt * 64];
    const h16x4* fb = FB + kt * 24 * 64;
#pragma unroll
    for (int dt = 0; dt < 24; ++dt)
      acc[dt] = mfma16(fb[(size_t)dt * 64], bp, acc[dt]);
  }
  int qg = q16 * 16 + (l & 15);
#pragma unroll
  for (int dt = 0; dt < 24; ++dt)
#pragma unroll
    for (int r = 0; r < 4; ++r) {
      int d = dt * 16 + 4 * (l >> 4) + r;
      out[((size_t)(b * 384) + d) * NQ + qg] = acc[dt][r];
    }
}

}  // namespace

extern "C" void kernel_launch(void* const* d_in, const int* in_sizes, int n_in,
                              void* d_out, int out_size, void* d_ws,
                              size_t ws_size, hipStream_t stream) {
  (void)in_sizes; (void)n_in; (void)out_size; (void)ws_size;
  const float* image        = (const float*)d_in[0];
  const float* features     = (const float*)d_in[1];
  const float* rope_f       = (const float*)d_in[2];
  const float* img_conv_w   = (const float*)d_in[3];
  const float* img_proj_w   = (const float*)d_in[4];
  const float* qenc_w       = (const float*)d_in[5];
  const float* kenc_w       = (const float*)d_in[6];
  const float* kfeat_conv_w = (const float*)d_in[7];
  const float* kfeat_proj_w = (const float*)d_in[8];
  const float* sft_gamma_w  = (const float*)d_in[9];
  const float* sft_beta_w   = (const float*)d_in[10];
  const float* block_conv_w = (const float*)d_in[11];
  const float* rms_q_w      = (const float*)d_in[12];
  const float* rms_k_w      = (const float*)d_in[13];
  const float* q_proj_w     = (const float*)d_in[14];
  const float* q_proj_b     = (const float*)d_in[15];
  const float* k_proj_w     = (const float*)d_in[16];
  const float* k_proj_b     = (const float*)d_in[17];
  float* out = (float*)d_out;
  float* ws = (float*)d_ws;

  size_t off = 0;
  auto alloc = [&](size_t n) {
    size_t r = off;
    off += (n + 63) & ~(size_t)63;
    return r;
  };
  _Float16* WqB  = (_Float16*)(ws + alloc(8192));
  _Float16* WkB  = (_Float16*)(ws + alloc(8192));
  _Float16* QPB  = (_Float16*)(ws + alloc(8192));
  _Float16* W3B  = (_Float16*)(ws + alloc(73728));
  _Float16* KFB  = (_Float16*)(ws + alloc(24576));
  _Float16* KFPB = (_Float16*)(ws + alloc(24576));
  _Float16* GB   = (_Float16*)(ws + alloc(8192));
  _Float16* BBf  = (_Float16*)(ws + alloc(8192));
  _Float16* KPB  = (_Float16*)(ws + alloc(8192));
  float* cosT     = ws + alloc(14336);
  float* sinT     = ws + alloc(14336);
  _Float16* featB = (_Float16*)(ws + alloc(159744));
  float* imgpart  = ws + alloc(2304);
  float* img_murs = ws + alloc(64);
  float* qk_murs  = ws + alloc(128);
  float* murs2    = ws + alloc(64);
  float* kgn_murs = ws + alloc(64);
  float* kf_murs  = ws + alloc(64);
  float* G        = ws + alloc(65536);
  float* mvec     = ws + alloc(512);
  float* mpart    = ws + alloc(392 * 128);
  float* Qpart    = ws + alloc((size_t)BB * 784 * 16);
  float* kpp      = ws + alloc((size_t)BB * 784 * 128);
  float* y_kf     = ws + alloc(100352);
  float* skip_kf  = ws + alloc(100352);
  float* k_pool   = ws + alloc(100352);
  float* kpb      = ws + alloc(100352);
  // RA (25.7MB): Gpart -> q_pool
  float* RA = ws + alloc((size_t)BB * NQ * 128);
  // ENC (51.4MB): encF -> (qp, Ph)
  float* ENCp = ws + alloc((size_t)BB * 784 * 8192 / 2);
  float* Gpart  = RA;
  float* q_pool = RA;
  _Float16* encF = (_Float16*)ENCp;
  float* qp      = ENCp;                                      // after encF dead
  _Float16* Ph   = (_Float16*)(ENCp + (size_t)BB * NQ * 128); // after qp

  k_prep<<<2648, 256, 0, stream>>>(qenc_w, kenc_w, q_proj_w, rms_q_w,
                                   block_conv_w, kfeat_conv_w, kfeat_proj_w,
                                   sft_gamma_w, sft_beta_w, k_proj_w, rms_k_w,
                                   rope_f, features,
                                   WqB, WkB, QPB, W3B, KFB, KFPB, GB, BBf, KPB,
                                   cosT, sinT, featB);

  k_imgstat1<<<BB * 64, 256, 0, stream>>>(image, imgpart);
  k_imgstat2<<<BB, 128, 0, stream>>>(imgpart, img_conv_w, img_murs);

  k_kf<<<BB * 4, 256, 0, stream>>>(features, KFB, KFPB, y_kf, skip_kf);
  k_gnstats<<<32, 256, 0, stream>>>(y_kf, kf_murs, NKk, EPS_GN);

  k_gram<<<BB * 98, 256, 0, stream>>>(image, cosT, sinT, img_conv_w,
                                      img_proj_w, img_murs, encF, Gpart, mpart);
  k_gred<<<BB * 64, 256, 0, stream>>>(Gpart, mpart, G, mvec);
  k_gstats<<<64, 256, 0, stream>>>(G, mvec, qenc_w, kenc_w, qk_murs);

  k_passA2<<<BB * 784, 256, 0, stream>>>(encF, qk_murs, WqB, WkB,
                                         q_pool, kpp, Qpart);
  k_qstatfin<<<32, 256, 0, stream>>>(Qpart, murs2);
  k_kpred<<<392, 256, 0, stream>>>(kpp, k_pool);
  k_gnstats<<<32, 256, 0, stream>>>(k_pool, kgn_murs, NKk, EPS_GN);

  k_ksft<<<BB * 4, 256, 0, stream>>>(y_kf, skip_kf, kf_murs, kgn_murs,
                                     GB, BBf, KPB, k_pool, k_proj_b, kpb);

  // fused 3x3 conv + RMS + q-proj (LDS input, SW-pipelined weight stream)
  k_conv3f<<<BB * 196, 256, 0, stream>>>(q_pool, murs2, W3B, QPB, q_proj_b, qp);

  k_attn1m<<<BB * 784, 256, 0, stream>>>(qp, kpb, Ph);
  k_attn2m<<<BB * 196, 256, 0, stream>>>(Ph, featB, out);
}

// Round 14
// 411.218 us; speedup vs baseline: 1.1534x; 1.1038x over previous
//
#include <hip/hip_runtime.h>
#include <cstdint>
#include <cstddef>

#define DEV __device__ __forceinline__

namespace {

constexpr int BB   = 4;
constexpr int HWP  = 50176;   // 224*224
constexpr int NQ   = 12544;   // 112*112
constexpr int NKk  = 196;     // 14*14
constexpr int VD   = 384;
constexpr float EPS_GN  = 1e-5f;
constexpr float EPS_RMS = 1.1920929e-7f;

typedef __attribute__((ext_vector_type(4))) float f32x4;
typedef __attribute__((ext_vector_type(4))) _Float16 h16x4;
typedef __attribute__((ext_vector_type(8))) _Float16 h16x8;

DEV float silu_f(float z) { return z / (1.f + __expf(-z)); }
DEV int rfl(int v) { return __builtin_amdgcn_readfirstlane(v); }

DEV f32x4 mfma16(h16x4 a, h16x4 b, f32x4 c) {
  return __builtin_amdgcn_mfma_f32_16x16x16f16(a, b, c, 0, 0, 0);
}
DEV f32x4 mfma32(h16x8 a, h16x8 b, f32x4 c) {
  return __builtin_amdgcn_mfma_f32_16x16x32_f16(a, b, c, 0, 0, 0);
}

// ---------- fused weight prep (one launch) ----------
DEV void pack16_one(int id, const float* W, const float* rowscale,
                    _Float16* dst) {
  int j = id & 3, l = (id >> 2) & 63, tile = id >> 8;
  int ct = tile & 7, kt = tile >> 3;
  int ci = kt * 16 + 4 * (l >> 4) + j;
  int co = ct * 16 + (l & 15);
  float v = W[(size_t)co * 128 + ci];
  if (rowscale) v *= rowscale[ci];
  dst[id] = (_Float16)v;
}
// pack 128x384 weight into frag order, K=384 (24 kt)
DEV void pack384_one(int id, const float* W, _Float16* dst) {
  int j = id & 3, l = (id >> 2) & 63, rest = id >> 8;
  int ct = rest & 7, kt = rest >> 3;          // kt 0..23
  int ci = kt * 16 + 4 * (l >> 4) + j;
  int co = ct * 16 + (l & 15);
  dst[id] = (_Float16)W[(size_t)co * 384 + ci];
}

__global__ __launch_bounds__(256) void k_prep(
    const float* __restrict__ qenc_w, const float* __restrict__ kenc_w,
    const float* __restrict__ q_proj_w, const float* __restrict__ rms_q_w,
    const float* __restrict__ block_conv_w,
    const float* __restrict__ kfeat_conv_w, const float* __restrict__ kfeat_proj_w,
    const float* __restrict__ sft_gamma_w, const float* __restrict__ sft_beta_w,
    const float* __restrict__ k_proj_w, const float* __restrict__ rms_k_w,
    const float* __restrict__ ropef, const float* __restrict__ feat,
    _Float16* __restrict__ WqB, _Float16* __restrict__ WkB,
    _Float16* __restrict__ QPB, _Float16* __restrict__ W3B,
    _Float16* __restrict__ KFB, _Float16* __restrict__ KFPB,
    _Float16* __restrict__ GB, _Float16* __restrict__ BBf,
    _Float16* __restrict__ KPB,
    float* __restrict__ cosT, float* __restrict__ sinT,
    _Float16* __restrict__ featB) {
  int idx = blockIdx.x * 256 + threadIdx.x;
  if (idx < 16384) {
    pack16_one(idx, qenc_w, nullptr, WqB);
  } else if (idx < 32768) {
    pack16_one(idx - 16384, kenc_w, nullptr, WkB);
  } else if (idx < 49152) {
    pack16_one(idx - 32768, q_proj_w, rms_q_w, QPB);
  } else if (idx < 196608) {
    // K=32 frag order for conv: frag id = (tap*4+kt2)*8+ct, lane l, elem j
    int id = idx - 49152;
    int j = id & 7, l = (id >> 3) & 63, ct = (id >> 9) & 7;
    int kt2 = (id >> 12) & 3, tap = id >> 14;
    int ci = kt2 * 32 + 8 * (l >> 4) + j;
    int co = ct * 16 + (l & 15);
    W3B[id] = (_Float16)block_conv_w[((size_t)co * 128 + ci) * 9 + tap];
  } else if (idx < 245760) {
    pack384_one(idx - 196608, kfeat_conv_w, KFB);
  } else if (idx < 294912) {
    pack384_one(idx - 245760, kfeat_proj_w, KFPB);
  } else if (idx < 311296) {
    pack16_one(idx - 294912, sft_gamma_w, nullptr, GB);
  } else if (idx < 327680) {
    pack16_one(idx - 311296, sft_beta_w, nullptr, BBf);
  } else if (idx < 344064) {
    pack16_one(idx - 327680, k_proj_w, rms_k_w, KPB);
  } else if (idx < 358400) {
    int id = idx - 344064;            // pos*64 + d
    int pos = id >> 6, d = id & 63;
    float a = (pos + 0.5f) * (1.f / 224.f) * ropef[d];
    float s, c;
    __sincosf(a, &s, &c);
    cosT[id] = c;
    sinT[id] = s;
  } else if (idx < 677888) {
    int id = idx - 358400;            // (((b*13+kt)*24+dt)*64+l)*4+j
    int j = id & 3, l = (id >> 2) & 63;
    int rest = id >> 8;
    int dt = rest % 24;
    int kt = (rest / 24) % 13;
    int b = rest / (24 * 13);
    int key = kt * 16 + 4 * (l >> 4) + j;
    int d = dt * 16 + (l & 15);
    float v = (key < 196) ? feat[((size_t)(b * 384) + d) * 196 + key] : 0.f;
    featB[id] = (_Float16)v;
  }
}

// ---------- image GN stats via 3x3 Gram ----------

__global__ __launch_bounds__(256) void k_imgstat1(
    const float* __restrict__ img, float* __restrict__ part) {
  __shared__ float lds[4][9];
  int b = blockIdx.x >> 6, blk = blockIdx.x & 63;
  int t = threadIdx.x;
  float a[9];
#pragma unroll
  for (int j = 0; j < 9; ++j) a[j] = 0.f;
  const float* ib = img + (size_t)b * 3 * HWP;
  for (int pix = blk * 784 + t; pix < blk * 784 + 784; pix += 256) {
    float x0 = ib[pix], x1 = ib[HWP + pix], x2 = ib[2 * HWP + pix];
    a[0] += x0; a[1] += x1; a[2] += x2;
    a[3] += x0 * x0; a[4] += x0 * x1; a[5] += x0 * x2;
    a[6] += x1 * x1; a[7] += x1 * x2; a[8] += x2 * x2;
  }
#pragma unroll
  for (int j = 0; j < 9; ++j)
    for (int m = 1; m < 64; m <<= 1) a[j] += __shfl_xor(a[j], m);
  if ((t & 63) == 0)
    for (int j = 0; j < 9; ++j) lds[t >> 6][j] = a[j];
  __syncthreads();
  if (t < 9)
    part[(size_t)blockIdx.x * 9 + t] =
        lds[0][t] + lds[1][t] + lds[2][t] + lds[3][t];
}

__global__ __launch_bounds__(128) void k_imgstat2(
    const float* __restrict__ part, const float* __restrict__ wimg,
    float* __restrict__ img_murs) {
  __shared__ float MG[9];
  int b = blockIdx.x, t = threadIdx.x;
  if (t < 9) {
    float s = 0.f;
    for (int i = 0; i < 64; ++i) s += part[(size_t)(b * 64 + i) * 9 + t];
    MG[t] = s;
  }
  __syncthreads();
  int c = t;
  float w0 = wimg[c * 3], w1 = wimg[c * 3 + 1], w2 = wimg[c * 3 + 2];
  float s1 = w0 * MG[0] + w1 * MG[1] + w2 * MG[2];
  float s2 = w0 * w0 * MG[3] + w1 * w1 * MG[6] + w2 * w2 * MG[8] +
             2.f * (w0 * w1 * MG[4] + w0 * w2 * MG[5] + w1 * w2 * MG[7]);
  for (int m = 1; m < 16; m <<= 1) {
    s1 += __shfl_xor(s1, m);
    s2 += __shfl_xor(s2, m);
  }
  if ((c & 15) == 0) {
    int g = c >> 4;
    float invN = 1.f / (16.f * HWP);
    float mu = s1 * invN;
    float var = s2 * invN - mu * mu;
    img_murs[b * 16 + g] = mu;
    img_murs[b * 16 + 8 + g] = rsqrtf(var + EPS_GN);
  }
}

// ---------- enc producer + Gram + enc_frag materialization ----------

__global__ __launch_bounds__(256) void k_gram(
    const float* __restrict__ img, const float* __restrict__ cosT,
    const float* __restrict__ sinT,
    const float* __restrict__ wimg, const float* __restrict__ wimgp,
    const float* __restrict__ img_murs,
    _Float16* __restrict__ encF,
    float* __restrict__ Gpart, float* __restrict__ mpart) {
  __shared__ __align__(16) _Float16 fragP[2080 * 4];   // [kt*4+mt][lane(65 pad)][j]
  __shared__ __align__(16) _Float16 fragC[8192];       // [pk][ct][lane][j]
  __shared__ float sWc[384], sWp[384], sMu[8], sRs[8];
  int t = threadIdx.x, l = t & 63, w = t >> 6;
  int b = blockIdx.x / 98, blk = blockIdx.x % 98;
  for (int i = t; i < 384; i += 256) { sWc[i] = wimg[i]; sWp[i] = wimgp[i]; }
  if (t < 8) { sMu[t] = img_murs[b * 16 + t]; sRs[t] = img_murs[b * 16 + 8 + t]; }
  f32x4 acc[2][8];
  f32x4 macc[2];
  f32x4 z = {0.f, 0.f, 0.f, 0.f};
#pragma unroll
  for (int e = 0; e < 2; ++e) {
    macc[e] = z;
#pragma unroll
    for (int nt = 0; nt < 8; ++nt) acc[e][nt] = z;
  }
  h16x4 hone = {(_Float16)1.f, (_Float16)1.f, (_Float16)1.f, (_Float16)1.f};
  int mt = l >> 4;
  int laneCbase = 16 * ((l & 15) >> 2);
  int jC = (l & 15) & 3;
  for (int s = 0; s < 8; ++s) {
    int sub = blk * 8 + s;
    int tile = sub >> 2, st = sub & 3;
    int py = (tile / 14) * 16 + ((st >> 1) << 3) + (l >> 3);
    int px = (tile % 14) * 16 + ((st & 1) << 3) + (l & 7);
    __syncthreads();
    {
      const float* ip = img + (size_t)b * 3 * HWP + py * 224 + px;
      float x0 = ip[0], x1 = ip[HWP], x2 = ip[2 * HWP];
      const float* cy = cosT + py * 64 + w * 16;
      const float* sy = sinT + py * 64 + w * 16;
      const float* cx = cosT + px * 64 + w * 16;
      const float* sx = sinT + px * 64 + w * 16;
#pragma unroll
      for (int jj = 0; jj < 4; ++jj) {
        f32x4 cyv = *(const f32x4*)(cy + jj * 4);
        f32x4 syv = *(const f32x4*)(sy + jj * 4);
        f32x4 cxv = *(const f32x4*)(cx + jj * 4);
        f32x4 sxv = *(const f32x4*)(sx + jj * 4);
        h16x4 lo4, hi4;
#pragma unroll
        for (int u = 0; u < 4; ++u) {
          int d = w * 16 + jj * 4 + u;
          int c2 = d + 64;
          float y1 = sWc[d * 3] * x0 + sWc[d * 3 + 1] * x1 + sWc[d * 3 + 2] * x2;
          float s1 = sWp[d * 3] * x0 + sWp[d * 3 + 1] * x1 + sWp[d * 3 + 2] * x2;
          float y2 = sWc[c2 * 3] * x0 + sWc[c2 * 3 + 1] * x1 + sWc[c2 * 3 + 2] * x2;
          float s2 = sWp[c2 * 3] * x0 + sWp[c2 * 3 + 1] * x1 + sWp[c2 * 3 + 2] * x2;
          int g1 = d >> 4, g2 = g1 + 4;
          float t1 = silu_f((y1 - sMu[g1]) * sRs[g1]) + s1;
          float t2 = silu_f((y2 - sMu[g2]) * sRs[g2]) + s2;
          lo4[u] = (_Float16)(t1 * cyv[u] - t2 * syv[u]);
          hi4[u] = (_Float16)(t2 * cxv[u] + t1 * sxv[u]);
        }
        int lane = (l & 15) + 16 * jj;
        *(h16x4*)&fragP[((w * 4 + mt) * 65 + lane) * 4]       = lo4;
        *(h16x4*)&fragP[(((w + 4) * 4 + mt) * 65 + lane) * 4] = hi4;
#pragma unroll
        for (int u = 0; u < 4; ++u) {
          int laneC = jj * 4 + u + laneCbase;
          fragC[((mt * 8 + w) * 64 + laneC) * 4 + jC]     = lo4[u];
          fragC[((mt * 8 + w + 4) * 64 + laneC) * 4 + jC] = hi4[u];
        }
      }
    }
    __syncthreads();
    _Float16* ef = encF + ((size_t)(b * 784) + sub) * 8192;
    for (int i = t; i < 2048; i += 256) {
      int kt = i >> 8, m2 = (i >> 6) & 3, ln = i & 63;
      *(h16x4*)(ef + (size_t)i * 4) =
          *(const h16x4*)&fragP[((kt * 4 + m2) * 65 + ln) * 4];
    }
#pragma unroll
    for (int pk = 0; pk < 4; ++pk) {
      h16x4 a0 = *(const h16x4*)&fragC[((pk * 8 + 2 * w) * 64 + l) * 4];
      h16x4 a1 = *(const h16x4*)&fragC[((pk * 8 + 2 * w + 1) * 64 + l) * 4];
      macc[0] = mfma16(a0, hone, macc[0]);
      macc[1] = mfma16(a1, hone, macc[1]);
#pragma unroll
      for (int nt = 0; nt < 8; ++nt) {
        h16x4 bv = *(const h16x4*)&fragC[((pk * 8 + nt) * 64 + l) * 4];
        acc[0][nt] = mfma16(a0, bv, acc[0][nt]);
        acc[1][nt] = mfma16(a1, bv, acc[1][nt]);
      }
    }
  }
  float* gp = Gpart + (size_t)(b * 98 + blk) * 16384;
#pragma unroll
  for (int e = 0; e < 2; ++e)
#pragma unroll
    for (int nt = 0; nt < 8; ++nt)
#pragma unroll
      for (int r = 0; r < 4; ++r) {
        int row = (2 * w + e) * 16 + 4 * (l >> 4) + r;
        int col = nt * 16 + (l & 15);
        gp[row * 128 + col] = acc[e][nt][r];
      }
  if ((l & 15) == 0) {
    float* mp = mpart + (size_t)(b * 98 + blk) * 128;
#pragma unroll
    for (int e = 0; e < 2; ++e)
#pragma unroll
      for (int r = 0; r < 4; ++r)
        mp[(2 * w + e) * 16 + 4 * (l >> 4) + r] = macc[e][r];
  }
}

__global__ void k_gred(const float* __restrict__ Gpart,
                       const float* __restrict__ mpart,
                       float* __restrict__ G, float* __restrict__ mvec) {
  int b = blockIdx.x >> 6, chunk = blockIdx.x & 63;
  int idx = chunk * 256 + threadIdx.x;
  float s = 0.f;
  for (int i = 0; i < 98; ++i) s += Gpart[(size_t)(b * 98 + i) * 16384 + idx];
  G[(size_t)b * 16384 + idx] = s;
  if (idx < 128) {
    float sm = 0.f;
    for (int i = 0; i < 98; ++i) sm += mpart[(size_t)(b * 98 + i) * 128 + idx];
    mvec[b * 128 + idx] = sm;
  }
}

__global__ __launch_bounds__(256) void k_gstats(
    const float* __restrict__ G, const float* __restrict__ mvec,
    const float* __restrict__ qw, const float* __restrict__ kw,
    float* __restrict__ qk_murs) {
  __shared__ float red1[4], red2[4];
  int bi = blockIdx.x;               // conv*32 + b*8 + g
  int conv = bi >> 5, b = (bi >> 3) & 3, g = bi & 7;
  const float* W = conv ? kw : qw;
  int t = threadIdx.x;
  int c = g * 16 + (t >> 4);
  int i0 = (t & 15) * 8;
  const float* wc = W + (size_t)c * 128;
  const float* Gb = G + (size_t)b * 16384;
  const float* mb = mvec + b * 128;
  float s1 = 0.f, s2 = 0.f;
  for (int i = i0; i < i0 + 8; ++i) {
    float gi = 0.f;
    for (int j = 0; j < 128; ++j) gi += Gb[i * 128 + j] * wc[j];
    s2 += wc[i] * gi;
    s1 += wc[i] * mb[i];
  }
  for (int m = 1; m < 64; m <<= 1) { s1 += __shfl_xor(s1, m); s2 += __shfl_xor(s2, m); }
  if ((t & 63) == 0) { red1[t >> 6] = s1; red2[t >> 6] = s2; }
  __syncthreads();
  if (t == 0) {
    float S1 = red1[0] + red1[1] + red1[2] + red1[3];
    float S2 = red2[0] + red2[1] + red2[2] + red2[3];
    float invN = 1.f / 802816.f;
    float mu = S1 * invN;
    float var = S2 * invN - mu * mu;
    qk_murs[bi * 2] = mu;
    qk_murs[bi * 2 + 1] = rsqrtf(var + EPS_GN);
  }
}

// ---------- pass A: q/k enc_blocks from encF, swapped operands ----------

__global__ __launch_bounds__(256) void k_passA2(
    const _Float16* __restrict__ encF, const float* __restrict__ qk_murs,
    const _Float16* __restrict__ WqB, const _Float16* __restrict__ WkB,
    float* __restrict__ q_pool, float* __restrict__ kpp,
    float* __restrict__ Qpart) {
  int t = threadIdx.x, l = t & 63;
  int wu = rfl(t >> 6);
  int bi = blockIdx.x;
  int b = bi / 784, sub = bi % 784;
  int tile = sub >> 2, st = sub & 3;
  int by = (tile / 14) * 16, bx = (tile % 14) * 16;
  float qmu[2], qrs[2], kmu[2], krs[2];
#pragma unroll
  for (int cc = 0; cc < 2; ++cc) {
    int g = 2 * wu + cc;
    qmu[cc] = qk_murs[(b * 8 + g) * 2];
    qrs[cc] = qk_murs[(b * 8 + g) * 2 + 1];
    kmu[cc] = qk_murs[(32 + b * 8 + g) * 2];
    krs[cc] = qk_murs[(32 + b * 8 + g) * 2 + 1];
  }
  const h16x4* EF = (const h16x4*)encF + ((size_t)(b * 784) + sub) * 2048;
  f32x4 z = {0.f, 0.f, 0.f, 0.f};
  f32x4 accQ[4][2], accK[4][2];
  h16x4 sf[2][4];
#pragma unroll
  for (int mt = 0; mt < 4; ++mt)
#pragma unroll
    for (int cc = 0; cc < 2; ++cc) { accQ[mt][cc] = z; accK[mt][cc] = z; }
  for (int kt = 0; kt < 8; ++kt) {
    h16x4 a[4];
#pragma unroll
    for (int mt = 0; mt < 4; ++mt) a[mt] = EF[(kt * 4 + mt) * 64 + l];
    if ((kt >> 1) == wu) {
#pragma unroll
      for (int mt = 0; mt < 4; ++mt) sf[kt & 1][mt] = a[mt];
    }
    int fi = (kt * 8 + 2 * wu) * 64 + l;
    h16x4 bq0 = *(const h16x4*)(WqB + (size_t)fi * 4);
    h16x4 bq1 = *(const h16x4*)(WqB + (size_t)(fi + 64) * 4);
    h16x4 bk0 = *(const h16x4*)(WkB + (size_t)fi * 4);
    h16x4 bk1 = *(const h16x4*)(WkB + (size_t)(fi + 64) * 4);
#pragma unroll
    for (int mt = 0; mt < 4; ++mt) {
      accQ[mt][0] = mfma16(bq0, a[mt], accQ[mt][0]);
      accQ[mt][1] = mfma16(bq1, a[mt], accQ[mt][1]);
      accK[mt][0] = mfma16(bk0, a[mt], accK[mt][0]);
      accK[mt][1] = mfma16(bk1, a[mt], accK[mt][1]);
    }
  }
  int q = l & 15;
  bool act = (q & 9) == 0;
  float kacc[2][4];
  float qs1[2] = {0.f, 0.f}, qs2[2] = {0.f, 0.f};
#pragma unroll
  for (int cc = 0; cc < 2; ++cc)
#pragma unroll
    for (int r = 0; r < 4; ++r) kacc[cc][r] = 0.f;
#pragma unroll
  for (int cc = 0; cc < 2; ++cc) {
    int g = 2 * wu + cc;
#pragma unroll
    for (int mt = 0; mt < 4; ++mt) {
      f32x4 pv;
#pragma unroll
      for (int r = 0; r < 4; ++r) {
        float skip = (float)sf[cc][mt][r];
        pv[r] = silu_f((accQ[mt][cc][r] - qmu[cc]) * qrs[cc]) + skip;
        kacc[cc][r] += silu_f((accK[mt][cc][r] - kmu[cc]) * krs[cc]) + skip;
      }
#pragma unroll
      for (int r = 0; r < 4; ++r) {
        float v = pv[r] + __shfl_xor(pv[r], 1);
        v += __shfl_xor(v, 8);
        pv[r] = v * 0.25f;
      }
      if (act) {
        int p = mt * 16 + q;
        int py = by + (st >> 1) * 8 + (p >> 3);
        int px = bx + (st & 1) * 8 + (p & 7);
        size_t base = ((size_t)(b * NQ) + (py >> 1) * 112 + (px >> 1)) * 128 +
                      g * 16 + 4 * (l >> 4);
        *(f32x4*)(q_pool + base) = pv;
        qs1[cc] += pv[0] + pv[1] + pv[2] + pv[3];
        qs2[cc] += pv[0] * pv[0] + pv[1] * pv[1] + pv[2] * pv[2] + pv[3] * pv[3];
      }
    }
  }
#pragma unroll
  for (int cc = 0; cc < 2; ++cc) {
#pragma unroll
    for (int r = 0; r < 4; ++r) {
      float v = kacc[cc][r];
      v += __shfl_xor(v, 1);
      v += __shfl_xor(v, 2);
      v += __shfl_xor(v, 4);
      v += __shfl_xor(v, 8);
      kacc[cc][r] = v;
    }
    if (q == 0) {
      f32x4 kv = {kacc[cc][0], kacc[cc][1], kacc[cc][2], kacc[cc][3]};
      *(f32x4*)(kpp + (size_t)bi * 128 + (2 * wu + cc) * 16 + 4 * (l >> 4)) = kv;
    }
  }
#pragma unroll
  for (int cc = 0; cc < 2; ++cc) {
    float a1 = qs1[cc], a2 = qs2[cc];
    for (int m = 1; m < 64; m <<= 1) {
      a1 += __shfl_xor(a1, m);
      a2 += __shfl_xor(a2, m);
    }
    if (l == 0) {
      Qpart[(size_t)bi * 16 + (2 * wu + cc) * 2] = a1;
      Qpart[(size_t)bi * 16 + (2 * wu + cc) * 2 + 1] = a2;
    }
  }
}

__global__ __launch_bounds__(256) void k_kpred(
    const float* __restrict__ kpp, float* __restrict__ k_pool) {
  int idx = blockIdx.x * 256 + threadIdx.x;
  if (idx >= BB * 128 * NKk) return;
  int b = idx / (128 * NKk);
  int rem = idx % (128 * NKk);
  int c = rem / NKk, tile = rem % NKk;
  const float* base = kpp + ((size_t)(b * 196 + tile) * 4) * 128 + c;
  float s = base[0] + base[128] + base[256] + base[384];
  k_pool[idx] = s * (1.f / 256.f);
}

__global__ __launch_bounds__(256) void k_qstatfin(
    const float* __restrict__ Qpart, float* __restrict__ murs2) {
  __shared__ float l1[4], l2[4];
  int b = blockIdx.x >> 3, g = blockIdx.x & 7, t = threadIdx.x;
  float s1 = 0.f, s2 = 0.f;
  for (int i = t; i < 784; i += 256) {
    s1 += Qpart[((size_t)(b * 784) + i) * 16 + g * 2];
    s2 += Qpart[((size_t)(b * 784) + i) * 16 + g * 2 + 1];
  }
  for (int m = 1; m < 64; m <<= 1) { s1 += __shfl_xor(s1, m); s2 += __shfl_xor(s2, m); }
  if ((t & 63) == 0) { l1[t >> 6] = s1; l2[t >> 6] = s2; }
  __syncthreads();
  if (t == 0) {
    float a = l1[0] + l1[1] + l1[2] + l1[3];
    float bq = l2[0] + l2[1] + l2[2] + l2[3];
    float invN = 1.f / (16.f * (float)NQ);
    float mu = a * invN;
    float var = bq * invN - mu * mu;
    murs2[blockIdx.x * 2] = mu;
    murs2[blockIdx.x * 2 + 1] = rsqrtf(var + EPS_GN);
  }
}

// ---------- GN stats (channel-major src[b][c][P]) ----------

__global__ __launch_bounds__(256) void k_gnstats(
    const float* __restrict__ src, float* __restrict__ murs, int P, float eps) {
  __shared__ float l1[4], l2[4];
  int b = blockIdx.x >> 3, g = blockIdx.x & 7, t = threadIdx.x;
  const float* base = src + ((size_t)(b * 128) + g * 16) * P;
  float s1 = 0.f, s2 = 0.f;
  for (int i = t; i < 16 * P; i += 256) {
    float v = base[i];
    s1 += v; s2 += v * v;
  }
  for (int m = 1; m < 64; m <<= 1) { s1 += __shfl_xor(s1, m); s2 += __shfl_xor(s2, m); }
  if ((t & 63) == 0) { l1[t >> 6] = s1; l2[t >> 6] = s2; }
  __syncthreads();
  if (t == 0) {
    float invN = 1.f / (16.f * (float)P);
    float a = l1[0] + l1[1] + l1[2] + l1[3];
    float bq = l2[0] + l2[1] + l2[2] + l2[3];
    float mu = a * invN;
    float var = bq * invN - mu * mu;
    murs[blockIdx.x * 2] = mu;
    murs[blockIdx.x * 2 + 1] = rsqrtf(var + eps);
  }
}

// ---------- kf branch: fused L2-norm + 384->128 conv+proj (MFMA) ----------

__global__ __launch_bounds__(256) void k_kf(
    const float* __restrict__ feat,
    const _Float16* __restrict__ KFB, const _Float16* __restrict__ KFPB,
    float* __restrict__ y_kf, float* __restrict__ skip_kf) {
  __shared__ __align__(16) _Float16 fnF[24 * 4 * 64 * 4];  // 48KB, A-frags
  __shared__ float ssqL[4][64];
  __shared__ float rsqL[64];
  int t = threadIdx.x, l = t & 63, w = t >> 6;
  int b = blockIdx.x >> 2, tile = blockIdx.x & 3;
  int p0 = tile * 49;
  const float* fb = feat + (size_t)b * VD * NKk;
  {
    float s = 0.f;
    if (l < 49) {
#pragma unroll 4
      for (int k = w; k < VD; k += 4) {
        float v = fb[(size_t)k * NKk + p0 + l];
        s += v * v;
      }
    }
    ssqL[w][l] = s;
  }
  __syncthreads();
  if (t < 64) {
    float s = ssqL[0][t] + ssqL[1][t] + ssqL[2][t] + ssqL[3][t];
    rsqL[t] = rsqrtf(fmaxf(s, 1e-24f));
  }
  __syncthreads();
  for (int i = t; i < VD * 64; i += 256) {
    int k = i >> 6, p = i & 63;
    float v = 0.f;
    if (p < 49) v = fb[(size_t)k * NKk + p0 + p] * rsqL[p];
    int kt = k >> 4, kr = k & 15, u = kr >> 2, j = kr & 3, mt = p >> 4;
    fnF[(((kt * 4 + mt) * 64) + (p & 15) + 16 * u) * 4 + j] = (_Float16)v;
  }
  __syncthreads();
  f32x4 z = {0.f, 0.f, 0.f, 0.f};
  f32x4 accY[4][2], accS[4][2];
#pragma unroll
  for (int mt = 0; mt < 4; ++mt)
#pragma unroll
    for (int cc = 0; cc < 2; ++cc) { accY[mt][cc] = z; accS[mt][cc] = z; }
  for (int kt = 0; kt < 24; ++kt) {
    h16x4 a[4];
#pragma unroll
    for (int mt = 0; mt < 4; ++mt)
      a[mt] = *(const h16x4*)&fnF[((kt * 4 + mt) * 64 + l) * 4];
    int fi = (kt * 8 + 2 * w) * 64 + l;
    h16x4 by0 = *(const h16x4*)(KFB + (size_t)fi * 4);
    h16x4 by1 = *(const h16x4*)(KFB + (size_t)(fi + 64) * 4);
    h16x4 bs0 = *(const h16x4*)(KFPB + (size_t)fi * 4);
    h16x4 bs1 = *(const h16x4*)(KFPB + (size_t)(fi + 64) * 4);
#pragma unroll
    for (int mt = 0; mt < 4; ++mt) {
      accY[mt][0] = mfma16(a[mt], by0, accY[mt][0]);
      accY[mt][1] = mfma16(a[mt], by1, accY[mt][1]);
      accS[mt][0] = mfma16(a[mt], bs0, accS[mt][0]);
      accS[mt][1] = mfma16(a[mt], bs1, accS[mt][1]);
    }
  }
#pragma unroll
  for (int cc = 0; cc < 2; ++cc) {
    int co = (2 * w + cc) * 16 + (l & 15);
#pragma unroll
    for (int mt = 0; mt < 4; ++mt)
#pragma unroll
      for (int r = 0; r < 4; ++r) {
        int pix = mt * 16 + 4 * (l >> 4) + r;
        if (pix < 49) {
          size_t off = ((size_t)(b * 128) + co) * NKk + p0 + pix;
          y_kf[off] = accY[mt][cc][r];
          skip_kf[off] = accS[mt][cc][r];
        }
      }
  }
}

// ---------- merged SFT + RMSNorm + k-proj (MFMA) ----------

__global__ __launch_bounds__(256) void k_ksft(
    const float* __restrict__ y_kf, const float* __restrict__ skip_kf,
    const float* __restrict__ kf_murs, const float* __restrict__ kgn_murs,
    const _Float16* __restrict__ GB, const _Float16* __restrict__ BBf,
    const _Float16* __restrict__ KPB,
    const float* __restrict__ k_pool, const float* __restrict__ k_proj_b,
    float* __restrict__ kpb) {
  __shared__ __align__(16) _Float16 kfF[8 * 4 * 64 * 4];  // 16KB A-frags
  __shared__ float msL[4][64];
  __shared__ float sMu[8], sRs[8], sGmu[8], sGrs[8];
  int t = threadIdx.x, l = t & 63, w = t >> 6;
  int b = blockIdx.x >> 2, tile = blockIdx.x & 3;
  int p0 = tile * 49;
  if (t < 8) {
    sMu[t] = kf_murs[(b * 8 + t) * 2];
    sRs[t] = kf_murs[(b * 8 + t) * 2 + 1];
    sGmu[t] = kgn_murs[(b * 8 + t) * 2];
    sGrs[t] = kgn_murs[(b * 8 + t) * 2 + 1];
  }
  __syncthreads();
  for (int i = t; i < 128 * 64; i += 256) {
    int c = i >> 6, p = i & 63;
    float v = 0.f;
    if (p < 49) {
      size_t off = ((size_t)(b * 128) + c) * NKk + p0 + p;
      int g = c >> 4;
      v = silu_f((y_kf[off] - sMu[g]) * sRs[g]) + skip_kf[off];
    }
    int kt = c >> 4, kr = c & 15, u = kr >> 2, j = kr & 3, mt = p >> 4;
    kfF[(((kt * 4 + mt) * 64) + (p & 15) + 16 * u) * 4 + j] = (_Float16)v;
  }
  __syncthreads();
  f32x4 z = {0.f, 0.f, 0.f, 0.f};
  f32x4 accG[4][2], accB[4][2];
#pragma unroll
  for (int mt = 0; mt < 4; ++mt)
#pragma unroll
    for (int cc = 0; cc < 2; ++cc) { accG[mt][cc] = z; accB[mt][cc] = z; }
  for (int kt = 0; kt < 8; ++kt) {
    h16x4 a[4];
#pragma unroll
    for (int mt = 0; mt < 4; ++mt)
      a[mt] = *(const h16x4*)&kfF[((kt * 4 + mt) * 64 + l) * 4];
    int fi = (kt * 8 + 2 * w) * 64 + l;
    h16x4 bg0 = *(const h16x4*)(GB + (size_t)fi * 4);
    h16x4 bg1 = *(const h16x4*)(GB + (size_t)(fi + 64) * 4);
    h16x4 bb0 = *(const h16x4*)(BBf + (size_t)fi * 4);
    h16x4 bb1 = *(const h16x4*)(BBf + (size_t)(fi + 64) * 4);
#pragma unroll
    for (int mt = 0; mt < 4; ++mt) {
      accG[mt][0] = mfma16(a[mt], bg0, accG[mt][0]);
      accG[mt][1] = mfma16(a[mt], bg1, accG[mt][1]);
      accB[mt][0] = mfma16(a[mt], bb0, accB[mt][0]);
      accB[mt][1] = mfma16(a[mt], bb1, accB[mt][1]);
    }
  }
  float kfin[4][2][4];
#pragma unroll
  for (int cc = 0; cc < 2; ++cc) {
    int g = 2 * w + cc;
    int co = g * 16 + (l & 15);
    float gmu = sGmu[g], grs = sGrs[g];
#pragma unroll
    for (int mt = 0; mt < 4; ++mt)
#pragma unroll
      for (int r = 0; r < 4; ++r) {
        int pix = mt * 16 + 4 * (l >> 4) + r;
        float v = 0.f;
        if (pix < 49) {
          float kn = (k_pool[((size_t)(b * 128) + co) * NKk + p0 + pix] - gmu) * grs;
          v = fmaf(accG[mt][cc][r], kn, accB[mt][cc][r]);
        }
        kfin[mt][cc][r] = v;
      }
  }
#pragma unroll
  for (int mt = 0; mt < 4; ++mt)
#pragma unroll
    for (int r = 0; r < 4; ++r) {
      float s2 = kfin[mt][0][r] * kfin[mt][0][r] + kfin[mt][1][r] * kfin[mt][1][r];
      for (int m = 1; m < 16; m <<= 1) s2 += __shfl_xor(s2, m);
      if ((l & 15) == 0) msL[w][mt * 16 + 4 * (l >> 4) + r] = s2;
    }
  __syncthreads();
#pragma unroll
  for (int cc = 0; cc < 2; ++cc) {
    int ktn = 2 * w + cc;
    int u = (l & 15) >> 2, j = (l & 15) & 3;
#pragma unroll
    for (int mt = 0; mt < 4; ++mt)
#pragma unroll
      for (int r = 0; r < 4; ++r) {
        int lane = (4 * (l >> 4) + r) + 16 * u;
        kfF[((ktn * 4 + mt) * 64 + lane) * 4 + j] = (_Float16)kfin[mt][cc][r];
      }
  }
  __syncthreads();
  f32x4 accP[4][2];
#pragma unroll
  for (int mt = 0; mt < 4; ++mt)
#pragma unroll
    for (int cc = 0; cc < 2; ++cc) accP[mt][cc] = z;
  for (int kt = 0; kt < 8; ++kt) {
    h16x4 a[4];
#pragma unroll
    for (int mt = 0; mt < 4; ++mt)
      a[mt] = *(const h16x4*)&kfF[((kt * 4 + mt) * 64 + l) * 4];
    int fi = (kt * 8 + 2 * w) * 64 + l;
    h16x4 b0 = *(const h16x4*)(KPB + (size_t)fi * 4);
    h16x4 b1 = *(const h16x4*)(KPB + (size_t)(fi + 64) * 4);
#pragma unroll
    for (int mt = 0; mt < 4; ++mt) {
      accP[mt][0] = mfma16(a[mt], b0, accP[mt][0]);
      accP[mt][1] = mfma16(a[mt], b1, accP[mt][1]);
    }
  }
#pragma unroll
  for (int mt = 0; mt < 4; ++mt)
#pragma unroll
    for (int r = 0; r < 4; ++r) {
      int pix = mt * 16 + 4 * (l >> 4) + r;
      if (pix >= 49) continue;
      float ms = msL[0][pix] + msL[1][pix] + msL[2][pix] + msL[3][pix];
      float rr = rsqrtf(ms * (1.f / 128.f) + EPS_RMS);
#pragma unroll
      for (int cc = 0; cc < 2; ++cc) {
        int co = (2 * w + cc) * 16 + (l & 15);
        kpb[((size_t)(b * 196) + p0 + pix) * 128 + co] =
            accP[mt][cc][r] * rr + k_proj_b[co];
      }
    }
}

// ---------- fused 3x3 conv + RMSNorm + q-proj (K=32 MFMA conv, LDS input,
// SW-pipelined weight stream) ----------
// grid = BB*196. Block = 8x8 output tile; wave w owns rows [2w,2w+1] (16 px).
// Conv uses mfma_f32_16x16x32_f16 (A/B packed with the SAME k-index formula,
// so any hardware k-permutation cancels); D layout equals the K=16 one, so
// the register-chained K=16 projection is unchanged.
__global__ __launch_bounds__(256) void k_conv3f(
    const float* __restrict__ q_pool, const float* __restrict__ murs2,
    const _Float16* __restrict__ W3B, const _Float16* __restrict__ QPB,
    const float* __restrict__ bias, float* __restrict__ qp) {
  __shared__ __align__(16) _Float16 tileL[100 * 136];  // 27.2 KB (16B-aligned rows)
  __shared__ float sMu[8], sRs[8];
  int t = threadIdx.x, l = t & 63, w = t >> 6;
  int b = blockIdx.x / 196, reg = blockIdx.x % 196;
  int y0 = (reg / 14) * 8, x0 = (reg % 14) * 8;
  if (t < 8) { sMu[t] = murs2[(b * 8 + t) * 2]; sRs[t] = murs2[(b * 8 + t) * 2 + 1]; }
  __syncthreads();
  // stage 10x10 halo tile, GN-normalized fp16 (zero outside image)
  for (int i = t; i < 3200; i += 256) {
    int rowp = i >> 5, c4 = i & 31;
    int gy = y0 - 1 + rowp / 10, gx = x0 - 1 + rowp % 10;
    h16x4 hv = {(_Float16)0.f, (_Float16)0.f, (_Float16)0.f, (_Float16)0.f};
    if (gy >= 0 && gy < 112 && gx >= 0 && gx < 112) {
      f32x4 v = *(const f32x4*)(q_pool + ((size_t)(b * NQ) + gy * 112 + gx) * 128 +
                                c4 * 4);
      int g = c4 >> 2;
      float mu = sMu[g], rs = sRs[g];
#pragma unroll
      for (int j = 0; j < 4; ++j) hv[j] = (_Float16)((v[j] - mu) * rs);
    }
    *(h16x4*)&tileL[rowp * 136 + c4 * 4] = hv;
  }
  __syncthreads();
  f32x4 z = {0.f, 0.f, 0.f, 0.f};
  f32x4 acc[8];
#pragma unroll
  for (int ct = 0; ct < 8; ++ct) acc[ct] = z;
  int lm = l & 15;
  int mrow = lm >> 3, mcol = lm & 7;
  const h16x8* W3l = (const h16x8*)W3B + l;
  // software-pipelined K=32 weight stream: distance-2 prefetch, 3 buffers
  h16x8 wbuf[3][8];
#pragma unroll
  for (int ct = 0; ct < 8; ++ct) wbuf[0][ct] = W3l[ct * 64];           // s=0
#pragma unroll
  for (int ct = 0; ct < 8; ++ct) wbuf[1][ct] = W3l[(8 + ct) * 64];     // s=1
#pragma unroll
  for (int s = 0; s < 36; ++s) {
    if (s + 2 < 36) {
#pragma unroll
      for (int ct = 0; ct < 8; ++ct)
        wbuf[(s + 2) % 3][ct] = W3l[((s + 2) * 8 + ct) * 64];
    }
    int tap = s >> 2, kt2 = s & 3;
    int prow = (2 * w + mrow + tap / 3) * 10 + (mcol + tap % 3);
    h16x8 bf = *(const h16x8*)&tileL[prow * 136 + kt2 * 32 + 8 * (l >> 4)];
#pragma unroll
    for (int ct = 0; ct < 8; ++ct)
      acc[ct] = mfma32(wbuf[s % 3][ct], bf, acc[ct]);
  }
  // RMS sumsq: lanes lm, lm+16, lm+32, lm+48 cover all 128 ch of pixel lm.
  float sq = 0.f;
#pragma unroll
  for (int ct = 0; ct < 8; ++ct)
#pragma unroll
    for (int r = 0; r < 4; ++r) sq += acc[ct][r] * acc[ct][r];
  sq += __shfl_xor(sq, 16);
  sq += __shfl_xor(sq, 32);
  float rr = rsqrtf(sq * (1.f / 128.f) + EPS_RMS);
  // conv result is already in (K=16) projection-B-frag layout: reg convert
  int chof = 4 * (l >> 4);
  h16x4 pb[8];
#pragma unroll
  for (int kt = 0; kt < 8; ++kt)
#pragma unroll
    for (int j = 0; j < 4; ++j) pb[kt][j] = (_Float16)acc[kt][j];
  // projection: A = QPB frag (K=16), B = pb
  f32x4 accP[8];
#pragma unroll
  for (int ct = 0; ct < 8; ++ct) accP[ct] = z;
  const h16x4* QP = (const h16x4*)QPB + l;
#pragma unroll
  for (int kt = 0; kt < 8; ++kt) {
#pragma unroll
    for (int ct = 0; ct < 8; ++ct)
      accP[ct] = mfma16(QP[(kt * 8 + ct) * 64], pb[kt], accP[ct]);
  }
  // write qp[pixel][ch]: ch = ct*16 + chof + r, pixel = lm
  int py = y0 + 2 * w + mrow, px = x0 + mcol;
  size_t pbase = ((size_t)(b * NQ) + py * 112 + px) * 128;
#pragma unroll
  for (int ct = 0; ct < 8; ++ct) {
    f32x4 o;
#pragma unroll
    for (int r = 0; r < 4; ++r)
      o[r] = accP[ct][r] * rr + bias[ct * 16 + chof + r];
    *(f32x4*)(qp + pbase + ct * 16 + chof) = o;
  }
}

// ---------- attention: QK^T + softmax + head-mean -> packed fp16 P ----------

__global__ __launch_bounds__(256) void k_attn1m(
    const float* __restrict__ qp, const float* __restrict__ kpb,
    _Float16* __restrict__ Ph) {
  __shared__ float sP[4][16][212];
  int t = threadIdx.x, l = t & 63, h = t >> 6;
  int b = blockIdx.x / 784, qt = blockIdx.x % 784;
  int q0 = qt * 16;
  constexpr float SC = 0.17677669529663687f;  // 1/sqrt(32)
  h16x4 aq[2];
#pragma unroll
  for (int kt = 0; kt < 2; ++kt) {
    f32x4 v = *(const f32x4*)(qp + ((size_t)(b * NQ) + q0 + (l & 15)) * 128 +
                              h * 32 + kt * 16 + 4 * (l >> 4));
    h16x4 ah;
#pragma unroll
    for (int j = 0; j < 4; ++j) ah[j] = (_Float16)v[j];
    aq[kt] = ah;
  }
  f32x4 z = {0.f, 0.f, 0.f, 0.f};
  f32x4 acc[13];
#pragma unroll
  for (int nt = 0; nt < 13; ++nt) acc[nt] = z;
#pragma unroll
  for (int nt = 0; nt < 13; ++nt) {
    int key = nt * 16 + (l & 15);
    bool ok = key < 196;
#pragma unroll
    for (int kt = 0; kt < 2; ++kt) {
      h16x4 bf = {(_Float16)0.f, (_Float16)0.f, (_Float16)0.f, (_Float16)0.f};
      if (ok) {
        f32x4 v = *(const f32x4*)(kpb + ((size_t)(b * 196) + key) * 128 +
                                  h * 32 + kt * 16 + 4 * (l >> 4));
#pragma unroll
        for (int j = 0; j < 4; ++j) bf[j] = (_Float16)v[j];
      }
      acc[nt] = mfma16(aq[kt], bf, acc[nt]);
    }
  }
#pragma unroll
  for (int r = 0; r < 4; ++r) {
    float mx = -3e38f;
#pragma unroll
    for (int nt = 0; nt < 13; ++nt) {
      bool ok = nt * 16 + (l & 15) < 196;
      float v = ok ? acc[nt][r] * SC : -3e38f;
      acc[nt][r] = v;
      mx = fmaxf(mx, v);
    }
    for (int m = 1; m < 16; m <<= 1) mx = fmaxf(mx, __shfl_xor(mx, m));
    float sum = 0.f;
#pragma unroll
    for (int nt = 0; nt < 13; ++nt) {
      bool ok = nt * 16 + (l & 15) < 196;
      float e = ok ? __expf(acc[nt][r] - mx) : 0.f;
      acc[nt][r] = e;
      sum += e;
    }
    for (int m = 1; m < 16; m <<= 1) sum += __shfl_xor(sum, m);
    float inv = 1.f / sum;
#pragma unroll
    for (int nt = 0; nt < 13; ++nt)
      sP[h][4 * (l >> 4) + r][nt * 16 + (l & 15)] = acc[nt][r] * inv;
  }
  __syncthreads();
  _Float16* pb = Ph + (size_t)(b * 784 + qt) * 13 * 256;
  for (int i = t; i < 832; i += 256) {
    int kt = i >> 6, ll = i & 63;
    int q = ll & 15, kb = kt * 16 + 4 * (ll >> 4);
    h16x4 v;
#pragma unroll
    for (int j = 0; j < 4; ++j) {
      int k = kb + j;
      float s = 0.25f * (sP[0][q][k] + sP[1][q][k] + sP[2][q][k] + sP[3][q][k]);
      v[j] = (_Float16)s;
    }
    *(h16x4*)(pb + (size_t)i * 4) = v;
  }
}

// ---------- attention PV: pure fragment streaming, no LDS ----------

__global__ __launch_bounds__(256) void k_attn2m(
    const _Float16* __restrict__ Ph, const _Float16* __restrict__ featB,
    float* __restrict__ out) {
  int t = threadIdx.x, l = t & 63, w = t >> 6;
  int b = blockIdx.x / 196, qt = blockIdx.x % 196;
  int q16 = qt * 4 + w;
  f32x4 z = {0.f, 0.f, 0.f, 0.f};
  f32x4 acc[24];
#pragma unroll
  for (int dt = 0; dt < 24; ++dt) acc[dt] = z;
  const h16x4* PB = (const h16x4*)Ph + ((size_t)(b * 784 + q16) * 13) * 64 + l;
  const h16x4* FB = (const h16x4*)featB + (size_t)b * 13 * 24 * 64 + l;
  for (int kt = 0; kt < 13; ++kt) {
    h16x4 bp = PB[kt * 64];
    const h16x4* fb = FB + kt * 24 * 64;
#pragma unroll
    for (int dt = 0; dt < 24; ++dt)
      acc[dt] = mfma16(fb[(size_t)dt * 64], bp, acc[dt]);
  }
  int qg = q16 * 16 + (l & 15);
#pragma unroll
  for (int dt = 0; dt < 24; ++dt)
#pragma unroll
    for (int r = 0; r < 4; ++r) {
      int d = dt * 16 + 4 * (l >> 4) + r;
      out[((size_t)(b * 384) + d) * NQ + qg] = acc[dt][r];
    }
}

}  // namespace

extern "C" void kernel_launch(void* const* d_in, const int* in_sizes, int n_in,
                              void* d_out, int out_size, void* d_ws,
                              size_t ws_size, hipStream_t stream) {
  (void)in_sizes; (void)n_in; (void)out_size; (void)ws_size;
  const float* image        = (const float*)d_in[0];
  const float* features     = (const float*)d_in[1];
  const float* rope_f       = (const float*)d_in[2];
  const float* img_conv_w   = (const float*)d_in[3];
  const float* img_proj_w   = (const float*)d_in[4];
  const float* qenc_w       = (const float*)d_in[5];
  const float* kenc_w       = (const float*)d_in[6];
  const float* kfeat_conv_w = (const float*)d_in[7];
  const float* kfeat_proj_w = (const float*)d_in[8];
  const float* sft_gamma_w  = (const float*)d_in[9];
  const float* sft_beta_w   = (const float*)d_in[10];
  const float* block_conv_w = (const float*)d_in[11];
  const float* rms_q_w      = (const float*)d_in[12];
  const float* rms_k_w      = (const float*)d_in[13];
  const float* q_proj_w     = (const float*)d_in[14];
  const float* q_proj_b     = (const float*)d_in[15];
  const float* k_proj_w     = (const float*)d_in[16];
  const float* k_proj_b     = (const float*)d_in[17];
  float* out = (float*)d_out;
  float* ws = (float*)d_ws;

  size_t off = 0;
  auto alloc = [&](size_t n) {
    size_t r = off;
    off += (n + 63) & ~(size_t)63;
    return r;
  };
  _Float16* WqB  = (_Float16*)(ws + alloc(8192));
  _Float16* WkB  = (_Float16*)(ws + alloc(8192));
  _Float16* QPB  = (_Float16*)(ws + alloc(8192));
  _Float16* W3B  = (_Float16*)(ws + alloc(73728));
  _Float16* KFB  = (_Float16*)(ws + alloc(24576));
  _Float16* KFPB = (_Float16*)(ws + alloc(24576));
  _Float16* GB   = (_Float16*)(ws + alloc(8192));
  _Float16* BBf  = (_Float16*)(ws + alloc(8192));
  _Float16* KPB  = (_Float16*)(ws + alloc(8192));
  float* cosT     = ws + alloc(14336);
  float* sinT     = ws + alloc(14336);
  _Float16* featB = (_Float16*)(ws + alloc(159744));
  float* imgpart  = ws + alloc(2304);
  float* img_murs = ws + alloc(64);
  float* qk_murs  = ws + alloc(128);
  float* murs2    = ws + alloc(64);
  float* kgn_murs = ws + alloc(64);
  float* kf_murs  = ws + alloc(64);
  float* G        = ws + alloc(65536);
  float* mvec     = ws + alloc(512);
  float* mpart    = ws + alloc(392 * 128);
  float* Qpart    = ws + alloc((size_t)BB * 784 * 16);
  float* kpp      = ws + alloc((size_t)BB * 784 * 128);
  float* y_kf     = ws + alloc(100352);
  float* skip_kf  = ws + alloc(100352);
  float* k_pool   = ws + alloc(100352);
  float* kpb      = ws + alloc(100352);
  // RA (25.7MB): Gpart -> q_pool
  float* RA = ws + alloc((size_t)BB * NQ * 128);
  // ENC (51.4MB): encF -> (qp, Ph)
  float* ENCp = ws + alloc((size_t)BB * 784 * 8192 / 2);
  float* Gpart  = RA;
  float* q_pool = RA;
  _Float16* encF = (_Float16*)ENCp;
  float* qp      = ENCp;                                      // after encF dead
  _Float16* Ph   = (_Float16*)(ENCp + (size_t)BB * NQ * 128); // after qp

  k_prep<<<2648, 256, 0, stream>>>(qenc_w, kenc_w, q_proj_w, rms_q_w,
                                   block_conv_w, kfeat_conv_w, kfeat_proj_w,
                                   sft_gamma_w, sft_beta_w, k_proj_w, rms_k_w,
                                   rope_f, features,
                                   WqB, WkB, QPB, W3B, KFB, KFPB, GB, BBf, KPB,
                                   cosT, sinT, featB);

  k_imgstat1<<<BB * 64, 256, 0, stream>>>(image, imgpart);
  k_imgstat2<<<BB, 128, 0, stream>>>(imgpart, img_conv_w, img_murs);

  k_kf<<<BB * 4, 256, 0, stream>>>(features, KFB, KFPB, y_kf, skip_kf);
  k_gnstats<<<32, 256, 0, stream>>>(y_kf, kf_murs, NKk, EPS_GN);

  k_gram<<<BB * 98, 256, 0, stream>>>(image, cosT, sinT, img_conv_w,
                                      img_proj_w, img_murs, encF, Gpart, mpart);
  k_gred<<<BB * 64, 256, 0, stream>>>(Gpart, mpart, G, mvec);
  k_gstats<<<64, 256, 0, stream>>>(G, mvec, qenc_w, kenc_w, qk_murs);

  k_passA2<<<BB * 784, 256, 0, stream>>>(encF, qk_murs, WqB, WkB,
                                         q_pool, kpp, Qpart);
  k_qstatfin<<<32, 256, 0, stream>>>(Qpart, murs2);
  k_kpred<<<392, 256, 0, stream>>>(kpp, k_pool);
  k_gnstats<<<32, 256, 0, stream>>>(k_pool, kgn_murs, NKk, EPS_GN);

  k_ksft<<<BB * 4, 256, 0, stream>>>(y_kf, skip_kf, kf_murs, kgn_murs,
                                     GB, BBf, KPB, k_pool, k_proj_b, kpb);

  // fused 3x3 conv + RMS + q-proj (K=32 conv, LDS input, prefetched weights)
  k_conv3f<<<BB * 196, 256, 0, stream>>>(q_pool, murs2, W3B, QPB, q_proj_b, qp);

  k_attn1m<<<BB * 784, 256, 0, stream>>>(qp, kpb, Ph);
  k_attn2m<<<BB * 196, 256, 0, stream>>>(Ph, featB, out);
}

// Round 15
// 390.105 us; speedup vs baseline: 1.2158x; 1.0541x over previous
//
#include <hip/hip_runtime.h>
#include <cstdint>
#include <cstddef>

#define DEV __device__ __forceinline__

namespace {

constexpr int BB   = 4;
constexpr int HWP  = 50176;   // 224*224
constexpr int NQ   = 12544;   // 112*112
constexpr int NKk  = 196;     // 14*14
constexpr int VD   = 384;
constexpr float EPS_GN  = 1e-5f;
constexpr float EPS_RMS = 1.1920929e-7f;

typedef __attribute__((ext_vector_type(4))) float f32x4;
typedef __attribute__((ext_vector_type(4))) _Float16 h16x4;
typedef __attribute__((ext_vector_type(8))) _Float16 h16x8;

DEV float silu_f(float z) { return z / (1.f + __expf(-z)); }
DEV int rfl(int v) { return __builtin_amdgcn_readfirstlane(v); }

DEV f32x4 mfma16(h16x4 a, h16x4 b, f32x4 c) {
  return __builtin_amdgcn_mfma_f32_16x16x16f16(a, b, c, 0, 0, 0);
}
DEV f32x4 mfma32(h16x8 a, h16x8 b, f32x4 c) {
  return __builtin_amdgcn_mfma_f32_16x16x32_f16(a, b, c, 0, 0, 0);
}

// ---------- fused weight prep (one launch) ----------
DEV void pack16_one(int id, const float* W, const float* rowscale,
                    _Float16* dst) {
  int j = id & 3, l = (id >> 2) & 63, tile = id >> 8;
  int ct = tile & 7, kt = tile >> 3;
  int ci = kt * 16 + 4 * (l >> 4) + j;
  int co = ct * 16 + (l & 15);
  float v = W[(size_t)co * 128 + ci];
  if (rowscale) v *= rowscale[ci];
  dst[id] = (_Float16)v;
}
// K=32 pack for 128x128 weight, channel map matching paired K=16 enc frags:
// elem j of lane-group u -> ci = kt2*32 + (j<4 ? 4u+j : 16 + 4u + (j-4))
DEV void pack32_one(int id, const float* W, _Float16* dst) {
  int j = id & 7, l = (id >> 3) & 63, ct = (id >> 9) & 7, kt2 = id >> 12;
  int u = l >> 4;
  int ci = kt2 * 32 + ((j < 4) ? (4 * u + j) : (16 + 4 * u + (j - 4)));
  int co = ct * 16 + (l & 15);
  dst[id] = (_Float16)W[(size_t)co * 128 + ci];
}
// pack 128x384 weight into frag order, K=384 (24 kt)
DEV void pack384_one(int id, const float* W, _Float16* dst) {
  int j = id & 3, l = (id >> 2) & 63, rest = id >> 8;
  int ct = rest & 7, kt = rest >> 3;          // kt 0..23
  int ci = kt * 16 + 4 * (l >> 4) + j;
  int co = ct * 16 + (l & 15);
  dst[id] = (_Float16)W[(size_t)co * 384 + ci];
}

__global__ __launch_bounds__(256) void k_prep(
    const float* __restrict__ qenc_w, const float* __restrict__ kenc_w,
    const float* __restrict__ q_proj_w, const float* __restrict__ rms_q_w,
    const float* __restrict__ block_conv_w,
    const float* __restrict__ kfeat_conv_w, const float* __restrict__ kfeat_proj_w,
    const float* __restrict__ sft_gamma_w, const float* __restrict__ sft_beta_w,
    const float* __restrict__ k_proj_w, const float* __restrict__ rms_k_w,
    const float* __restrict__ ropef, const float* __restrict__ feat,
    _Float16* __restrict__ WqB, _Float16* __restrict__ WkB,
    _Float16* __restrict__ QPB, _Float16* __restrict__ W3B,
    _Float16* __restrict__ KFB, _Float16* __restrict__ KFPB,
    _Float16* __restrict__ GB, _Float16* __restrict__ BBf,
    _Float16* __restrict__ KPB,
    float* __restrict__ cosT, float* __restrict__ sinT,
    _Float16* __restrict__ featB) {
  int idx = blockIdx.x * 256 + threadIdx.x;
  if (idx < 16384) {
    pack32_one(idx, qenc_w, WqB);                 // K=32 pack
  } else if (idx < 32768) {
    pack32_one(idx - 16384, kenc_w, WkB);         // K=32 pack
  } else if (idx < 49152) {
    pack16_one(idx - 32768, q_proj_w, rms_q_w, QPB);
  } else if (idx < 196608) {
    // K=32 frag order for conv: frag id = (tap*4+kt2)*8+ct, lane l, elem j
    int id = idx - 49152;
    int j = id & 7, l = (id >> 3) & 63, ct = (id >> 9) & 7;
    int kt2 = (id >> 12) & 3, tap = id >> 14;
    int ci = kt2 * 32 + 8 * (l >> 4) + j;
    int co = ct * 16 + (l & 15);
    W3B[id] = (_Float16)block_conv_w[((size_t)co * 128 + ci) * 9 + tap];
  } else if (idx < 245760) {
    pack384_one(idx - 196608, kfeat_conv_w, KFB);
  } else if (idx < 294912) {
    pack384_one(idx - 245760, kfeat_proj_w, KFPB);
  } else if (idx < 311296) {
    pack16_one(idx - 294912, sft_gamma_w, nullptr, GB);
  } else if (idx < 327680) {
    pack16_one(idx - 311296, sft_beta_w, nullptr, BBf);
  } else if (idx < 344064) {
    pack16_one(idx - 327680, k_proj_w, rms_k_w, KPB);
  } else if (idx < 358400) {
    int id = idx - 344064;            // pos*64 + d
    int pos = id >> 6, d = id & 63;
    float a = (pos + 0.5f) * (1.f / 224.f) * ropef[d];
    float s, c;
    __sincosf(a, &s, &c);
    cosT[id] = c;
    sinT[id] = s;
  } else if (idx < 677888) {
    int id = idx - 358400;            // (((b*13+kt)*24+dt)*64+l)*4+j
    int j = id & 3, l = (id >> 2) & 63;
    int rest = id >> 8;
    int dt = rest % 24;
    int kt = (rest / 24) % 13;
    int b = rest / (24 * 13);
    int key = kt * 16 + 4 * (l >> 4) + j;
    int d = dt * 16 + (l & 15);
    float v = (key < 196) ? feat[((size_t)(b * 384) + d) * 196 + key] : 0.f;
    featB[id] = (_Float16)v;
  }
}

// ---------- image GN stats via 3x3 Gram ----------

__global__ __launch_bounds__(256) void k_imgstat1(
    const float* __restrict__ img, float* __restrict__ part) {
  __shared__ float lds[4][9];
  int b = blockIdx.x >> 6, blk = blockIdx.x & 63;
  int t = threadIdx.x;
  float a[9];
#pragma unroll
  for (int j = 0; j < 9; ++j) a[j] = 0.f;
  const float* ib = img + (size_t)b * 3 * HWP;
  for (int pix = blk * 784 + t; pix < blk * 784 + 784; pix += 256) {
    float x0 = ib[pix], x1 = ib[HWP + pix], x2 = ib[2 * HWP + pix];
    a[0] += x0; a[1] += x1; a[2] += x2;
    a[3] += x0 * x0; a[4] += x0 * x1; a[5] += x0 * x2;
    a[6] += x1 * x1; a[7] += x1 * x2; a[8] += x2 * x2;
  }
#pragma unroll
  for (int j = 0; j < 9; ++j)
    for (int m = 1; m < 64; m <<= 1) a[j] += __shfl_xor(a[j], m);
  if ((t & 63) == 0)
    for (int j = 0; j < 9; ++j) lds[t >> 6][j] = a[j];
  __syncthreads();
  if (t < 9)
    part[(size_t)blockIdx.x * 9 + t] =
        lds[0][t] + lds[1][t] + lds[2][t] + lds[3][t];
}

__global__ __launch_bounds__(128) void k_imgstat2(
    const float* __restrict__ part, const float* __restrict__ wimg,
    float* __restrict__ img_murs) {
  __shared__ float MG[9];
  int b = blockIdx.x, t = threadIdx.x;
  if (t < 9) {
    float s = 0.f;
    for (int i = 0; i < 64; ++i) s += part[(size_t)(b * 64 + i) * 9 + t];
    MG[t] = s;
  }
  __syncthreads();
  int c = t;
  float w0 = wimg[c * 3], w1 = wimg[c * 3 + 1], w2 = wimg[c * 3 + 2];
  float s1 = w0 * MG[0] + w1 * MG[1] + w2 * MG[2];
  float s2 = w0 * w0 * MG[3] + w1 * w1 * MG[6] + w2 * w2 * MG[8] +
             2.f * (w0 * w1 * MG[4] + w0 * w2 * MG[5] + w1 * w2 * MG[7]);
  for (int m = 1; m < 16; m <<= 1) {
    s1 += __shfl_xor(s1, m);
    s2 += __shfl_xor(s2, m);
  }
  if ((c & 15) == 0) {
    int g = c >> 4;
    float invN = 1.f / (16.f * HWP);
    float mu = s1 * invN;
    float var = s2 * invN - mu * mu;
    img_murs[b * 16 + g] = mu;
    img_murs[b * 16 + 8 + g] = rsqrtf(var + EPS_GN);
  }
}

// ---------- enc producer + Gram + enc_frag materialization ----------
// encF is written as paired K=32 fragments: h16x8 index (kt2*4+mt)*64+l,
// elems 0-3 from K=16 frag kt=2kt2, elems 4-7 from kt=2kt2+1.

__global__ __launch_bounds__(256) void k_gram(
    const float* __restrict__ img, const float* __restrict__ cosT,
    const float* __restrict__ sinT,
    const float* __restrict__ wimg, const float* __restrict__ wimgp,
    const float* __restrict__ img_murs,
    _Float16* __restrict__ encF,
    float* __restrict__ Gpart, float* __restrict__ mpart) {
  __shared__ __align__(16) _Float16 fragP[2080 * 4];   // [kt*4+mt][lane(65 pad)][j]
  __shared__ __align__(16) _Float16 fragC[8192];       // [pk][ct][lane][j]
  __shared__ float sWc[384], sWp[384], sMu[8], sRs[8];
  int t = threadIdx.x, l = t & 63, w = t >> 6;
  int b = blockIdx.x / 98, blk = blockIdx.x % 98;
  for (int i = t; i < 384; i += 256) { sWc[i] = wimg[i]; sWp[i] = wimgp[i]; }
  if (t < 8) { sMu[t] = img_murs[b * 16 + t]; sRs[t] = img_murs[b * 16 + 8 + t]; }
  f32x4 acc[2][8];
  f32x4 macc[2];
  f32x4 z = {0.f, 0.f, 0.f, 0.f};
#pragma unroll
  for (int e = 0; e < 2; ++e) {
    macc[e] = z;
#pragma unroll
    for (int nt = 0; nt < 8; ++nt) acc[e][nt] = z;
  }
  h16x4 hone = {(_Float16)1.f, (_Float16)1.f, (_Float16)1.f, (_Float16)1.f};
  int mt = l >> 4;
  int laneCbase = 16 * ((l & 15) >> 2);
  int jC = (l & 15) & 3;
  for (int s = 0; s < 8; ++s) {
    int sub = blk * 8 + s;
    int tile = sub >> 2, st = sub & 3;
    int py = (tile / 14) * 16 + ((st >> 1) << 3) + (l >> 3);
    int px = (tile % 14) * 16 + ((st & 1) << 3) + (l & 7);
    __syncthreads();
    {
      const float* ip = img + (size_t)b * 3 * HWP + py * 224 + px;
      float x0 = ip[0], x1 = ip[HWP], x2 = ip[2 * HWP];
      const float* cy = cosT + py * 64 + w * 16;
      const float* sy = sinT + py * 64 + w * 16;
      const float* cx = cosT + px * 64 + w * 16;
      const float* sx = sinT + px * 64 + w * 16;
#pragma unroll
      for (int jj = 0; jj < 4; ++jj) {
        f32x4 cyv = *(const f32x4*)(cy + jj * 4);
        f32x4 syv = *(const f32x4*)(sy + jj * 4);
        f32x4 cxv = *(const f32x4*)(cx + jj * 4);
        f32x4 sxv = *(const f32x4*)(sx + jj * 4);
        h16x4 lo4, hi4;
#pragma unroll
        for (int u = 0; u < 4; ++u) {
          int d = w * 16 + jj * 4 + u;
          int c2 = d + 64;
          float y1 = sWc[d * 3] * x0 + sWc[d * 3 + 1] * x1 + sWc[d * 3 + 2] * x2;
          float s1 = sWp[d * 3] * x0 + sWp[d * 3 + 1] * x1 + sWp[d * 3 + 2] * x2;
          float y2 = sWc[c2 * 3] * x0 + sWc[c2 * 3 + 1] * x1 + sWc[c2 * 3 + 2] * x2;
          float s2 = sWp[c2 * 3] * x0 + sWp[c2 * 3 + 1] * x1 + sWp[c2 * 3 + 2] * x2;
          int g1 = d >> 4, g2 = g1 + 4;
          float t1 = silu_f((y1 - sMu[g1]) * sRs[g1]) + s1;
          float t2 = silu_f((y2 - sMu[g2]) * sRs[g2]) + s2;
          lo4[u] = (_Float16)(t1 * cyv[u] - t2 * syv[u]);
          hi4[u] = (_Float16)(t2 * cxv[u] + t1 * sxv[u]);
        }
        int lane = (l & 15) + 16 * jj;
        *(h16x4*)&fragP[((w * 4 + mt) * 65 + lane) * 4]       = lo4;
        *(h16x4*)&fragP[(((w + 4) * 4 + mt) * 65 + lane) * 4] = hi4;
#pragma unroll
        for (int u = 0; u < 4; ++u) {
          int laneC = jj * 4 + u + laneCbase;
          fragC[((mt * 8 + w) * 64 + laneC) * 4 + jC]     = lo4[u];
          fragC[((mt * 8 + w + 4) * 64 + laneC) * 4 + jC] = hi4[u];
        }
      }
    }
    __syncthreads();
    // stream fragP -> encF as paired K=32 fragments (coalesced 16B stores)
    _Float16* ef = encF + ((size_t)(b * 784) + sub) * 8192;
    for (int i = t; i < 1024; i += 256) {
      int kt2 = i >> 8, m2 = (i >> 6) & 3, ln = i & 63;
      h16x4 lo = *(const h16x4*)&fragP[(((2 * kt2) * 4 + m2) * 65 + ln) * 4];
      h16x4 hi = *(const h16x4*)&fragP[(((2 * kt2 + 1) * 4 + m2) * 65 + ln) * 4];
      h16x8 v;
#pragma unroll
      for (int j = 0; j < 4; ++j) { v[j] = lo[j]; v[j + 4] = hi[j]; }
      *(h16x8*)(ef + (size_t)i * 8) = v;
    }
#pragma unroll
    for (int pk = 0; pk < 4; ++pk) {
      h16x4 a0 = *(const h16x4*)&fragC[((pk * 8 + 2 * w) * 64 + l) * 4];
      h16x4 a1 = *(const h16x4*)&fragC[((pk * 8 + 2 * w + 1) * 64 + l) * 4];
      macc[0] = mfma16(a0, hone, macc[0]);
      macc[1] = mfma16(a1, hone, macc[1]);
#pragma unroll
      for (int nt = 0; nt < 8; ++nt) {
        h16x4 bv = *(const h16x4*)&fragC[((pk * 8 + nt) * 64 + l) * 4];
        acc[0][nt] = mfma16(a0, bv, acc[0][nt]);
        acc[1][nt] = mfma16(a1, bv, acc[1][nt]);
      }
    }
  }
  float* gp = Gpart + (size_t)(b * 98 + blk) * 16384;
#pragma unroll
  for (int e = 0; e < 2; ++e)
#pragma unroll
    for (int nt = 0; nt < 8; ++nt)
#pragma unroll
      for (int r = 0; r < 4; ++r) {
        int row = (2 * w + e) * 16 + 4 * (l >> 4) + r;
        int col = nt * 16 + (l & 15);
        gp[row * 128 + col] = acc[e][nt][r];
      }
  if ((l & 15) == 0) {
    float* mp = mpart + (size_t)(b * 98 + blk) * 128;
#pragma unroll
    for (int e = 0; e < 2; ++e)
#pragma unroll
      for (int r = 0; r < 4; ++r)
        mp[(2 * w + e) * 16 + 4 * (l >> 4) + r] = macc[e][r];
  }
}

__global__ void k_gred(const float* __restrict__ Gpart,
                       const float* __restrict__ mpart,
                       float* __restrict__ G, float* __restrict__ mvec) {
  int b = blockIdx.x >> 6, chunk = blockIdx.x & 63;
  int idx = chunk * 256 + threadIdx.x;
  float s = 0.f;
  for (int i = 0; i < 98; ++i) s += Gpart[(size_t)(b * 98 + i) * 16384 + idx];
  G[(size_t)b * 16384 + idx] = s;
  if (idx < 128) {
    float sm = 0.f;
    for (int i = 0; i < 98; ++i) sm += mpart[(size_t)(b * 98 + i) * 128 + idx];
    mvec[b * 128 + idx] = sm;
  }
}

__global__ __launch_bounds__(256) void k_gstats(
    const float* __restrict__ G, const float* __restrict__ mvec,
    const float* __restrict__ qw, const float* __restrict__ kw,
    float* __restrict__ qk_murs) {
  __shared__ float red1[4], red2[4];
  int bi = blockIdx.x;               // conv*32 + b*8 + g
  int conv = bi >> 5, b = (bi >> 3) & 3, g = bi & 7;
  const float* W = conv ? kw : qw;
  int t = threadIdx.x;
  int c = g * 16 + (t >> 4);
  int i0 = (t & 15) * 8;
  const float* wc = W + (size_t)c * 128;
  const float* Gb = G + (size_t)b * 16384;
  const float* mb = mvec + b * 128;
  float s1 = 0.f, s2 = 0.f;
  for (int i = i0; i < i0 + 8; ++i) {
    float gi = 0.f;
    for (int j = 0; j < 128; ++j) gi += Gb[i * 128 + j] * wc[j];
    s2 += wc[i] * gi;
    s1 += wc[i] * mb[i];
  }
  for (int m = 1; m < 64; m <<= 1) { s1 += __shfl_xor(s1, m); s2 += __shfl_xor(s2, m); }
  if ((t & 63) == 0) { red1[t >> 6] = s1; red2[t >> 6] = s2; }
  __syncthreads();
  if (t == 0) {
    float S1 = red1[0] + red1[1] + red1[2] + red1[3];
    float S2 = red2[0] + red2[1] + red2[2] + red2[3];
    float invN = 1.f / 802816.f;
    float mu = S1 * invN;
    float var = S2 * invN - mu * mu;
    qk_murs[bi * 2] = mu;
    qk_murs[bi * 2 + 1] = rsqrtf(var + EPS_GN);
  }
}

// ---------- pass A: q/k enc_blocks from encF (K=32 MFMA) ----------
// encF holds paired K=32 B-frags; WqB/WkB packed with the matching channel
// map, so the k-permutation cancels. D layout = K=16 layout; skip values for
// group g=2wu+cc are elems cc*4+r of the kt2==wu fragment.

__global__ __launch_bounds__(256) void k_passA2(
    const _Float16* __restrict__ encF, const float* __restrict__ qk_murs,
    const _Float16* __restrict__ WqB, const _Float16* __restrict__ WkB,
    float* __restrict__ q_pool, float* __restrict__ kpp,
    float* __restrict__ Qpart) {
  int t = threadIdx.x, l = t & 63;
  int wu = rfl(t >> 6);
  int bi = blockIdx.x;
  int b = bi / 784, sub = bi % 784;
  int tile = sub >> 2, st = sub & 3;
  int by = (tile / 14) * 16, bx = (tile % 14) * 16;
  float qmu[2], qrs[2], kmu[2], krs[2];
#pragma unroll
  for (int cc = 0; cc < 2; ++cc) {
    int g = 2 * wu + cc;
    qmu[cc] = qk_murs[(b * 8 + g) * 2];
    qrs[cc] = qk_murs[(b * 8 + g) * 2 + 1];
    kmu[cc] = qk_murs[(32 + b * 8 + g) * 2];
    krs[cc] = qk_murs[(32 + b * 8 + g) * 2 + 1];
  }
  const h16x8* EF = (const h16x8*)encF + ((size_t)(b * 784) + sub) * 1024;
  const h16x8* WQ = (const h16x8*)WqB;
  const h16x8* WK = (const h16x8*)WkB;
  f32x4 z = {0.f, 0.f, 0.f, 0.f};
  f32x4 accQ[4][2], accK[4][2];
  h16x8 sf8[4];
#pragma unroll
  for (int mt = 0; mt < 4; ++mt)
#pragma unroll
    for (int cc = 0; cc < 2; ++cc) { accQ[mt][cc] = z; accK[mt][cc] = z; }
  for (int kt2 = 0; kt2 < 4; ++kt2) {
    h16x8 a[4];
#pragma unroll
    for (int mt = 0; mt < 4; ++mt) a[mt] = EF[(kt2 * 4 + mt) * 64 + l];
    if (kt2 == wu) {
#pragma unroll
      for (int mt = 0; mt < 4; ++mt) sf8[mt] = a[mt];
    }
    int fi = (kt2 * 8 + 2 * wu) * 64 + l;
    h16x8 bq0 = WQ[fi];
    h16x8 bq1 = WQ[fi + 64];
    h16x8 bk0 = WK[fi];
    h16x8 bk1 = WK[fi + 64];
#pragma unroll
    for (int mt = 0; mt < 4; ++mt) {
      accQ[mt][0] = mfma32(bq0, a[mt], accQ[mt][0]);
      accQ[mt][1] = mfma32(bq1, a[mt], accQ[mt][1]);
      accK[mt][0] = mfma32(bk0, a[mt], accK[mt][0]);
      accK[mt][1] = mfma32(bk1, a[mt], accK[mt][1]);
    }
  }
  int q = l & 15;
  bool act = (q & 9) == 0;
  float kacc[2][4];
  float qs1[2] = {0.f, 0.f}, qs2[2] = {0.f, 0.f};
#pragma unroll
  for (int cc = 0; cc < 2; ++cc)
#pragma unroll
    for (int r = 0; r < 4; ++r) kacc[cc][r] = 0.f;
#pragma unroll
  for (int cc = 0; cc < 2; ++cc) {
    int g = 2 * wu + cc;
#pragma unroll
    for (int mt = 0; mt < 4; ++mt) {
      f32x4 pv;
#pragma unroll
      for (int r = 0; r < 4; ++r) {
        float skip = (float)sf8[mt][cc * 4 + r];
        pv[r] = silu_f((accQ[mt][cc][r] - qmu[cc]) * qrs[cc]) + skip;
        kacc[cc][r] += silu_f((accK[mt][cc][r] - kmu[cc]) * krs[cc]) + skip;
      }
#pragma unroll
      for (int r = 0; r < 4; ++r) {
        float v = pv[r] + __shfl_xor(pv[r], 1);
        v += __shfl_xor(v, 8);
        pv[r] = v * 0.25f;
      }
      if (act) {
        int p = mt * 16 + q;
        int py = by + (st >> 1) * 8 + (p >> 3);
        int px = bx + (st & 1) * 8 + (p & 7);
        size_t base = ((size_t)(b * NQ) + (py >> 1) * 112 + (px >> 1)) * 128 +
                      g * 16 + 4 * (l >> 4);
        *(f32x4*)(q_pool + base) = pv;
        qs1[cc] += pv[0] + pv[1] + pv[2] + pv[3];
        qs2[cc] += pv[0] * pv[0] + pv[1] * pv[1] + pv[2] * pv[2] + pv[3] * pv[3];
      }
    }
  }
#pragma unroll
  for (int cc = 0; cc < 2; ++cc) {
#pragma unroll
    for (int r = 0; r < 4; ++r) {
      float v = kacc[cc][r];
      v += __shfl_xor(v, 1);
      v += __shfl_xor(v, 2);
      v += __shfl_xor(v, 4);
      v += __shfl_xor(v, 8);
      kacc[cc][r] = v;
    }
    if (q == 0) {
      f32x4 kv = {kacc[cc][0], kacc[cc][1], kacc[cc][2], kacc[cc][3]};
      *(f32x4*)(kpp + (size_t)bi * 128 + (2 * wu + cc) * 16 + 4 * (l >> 4)) = kv;
    }
  }
#pragma unroll
  for (int cc = 0; cc < 2; ++cc) {
    float a1 = qs1[cc], a2 = qs2[cc];
    for (int m = 1; m < 64; m <<= 1) {
      a1 += __shfl_xor(a1, m);
      a2 += __shfl_xor(a2, m);
    }
    if (l == 0) {
      Qpart[(size_t)bi * 16 + (2 * wu + cc) * 2] = a1;
      Qpart[(size_t)bi * 16 + (2 * wu + cc) * 2 + 1] = a2;
    }
  }
}

__global__ __launch_bounds__(256) void k_kpred(
    const float* __restrict__ kpp, float* __restrict__ k_pool) {
  int idx = blockIdx.x * 256 + threadIdx.x;
  if (idx >= BB * 128 * NKk) return;
  int b = idx / (128 * NKk);
  int rem = idx % (128 * NKk);
  int c = rem / NKk, tile = rem % NKk;
  const float* base = kpp + ((size_t)(b * 196 + tile) * 4) * 128 + c;
  float s = base[0] + base[128] + base[256] + base[384];
  k_pool[idx] = s * (1.f / 256.f);
}

__global__ __launch_bounds__(256) void k_qstatfin(
    const float* __restrict__ Qpart, float* __restrict__ murs2) {
  __shared__ float l1[4], l2[4];
  int b = blockIdx.x >> 3, g = blockIdx.x & 7, t = threadIdx.x;
  float s1 = 0.f, s2 = 0.f;
  for (int i = t; i < 784; i += 256) {
    s1 += Qpart[((size_t)(b * 784) + i) * 16 + g * 2];
    s2 += Qpart[((size_t)(b * 784) + i) * 16 + g * 2 + 1];
  }
  for (int m = 1; m < 64; m <<= 1) { s1 += __shfl_xor(s1, m); s2 += __shfl_xor(s2, m); }
  if ((t & 63) == 0) { l1[t >> 6] = s1; l2[t >> 6] = s2; }
  __syncthreads();
  if (t == 0) {
    float a = l1[0] + l1[1] + l1[2] + l1[3];
    float bq = l2[0] + l2[1] + l2[2] + l2[3];
    float invN = 1.f / (16.f * (float)NQ);
    float mu = a * invN;
    float var = bq * invN - mu * mu;
    murs2[blockIdx.x * 2] = mu;
    murs2[blockIdx.x * 2 + 1] = rsqrtf(var + EPS_GN);
  }
}

// ---------- GN stats (channel-major src[b][c][P]) ----------

__global__ __launch_bounds__(256) void k_gnstats(
    const float* __restrict__ src, float* __restrict__ murs, int P, float eps) {
  __shared__ float l1[4], l2[4];
  int b = blockIdx.x >> 3, g = blockIdx.x & 7, t = threadIdx.x;
  const float* base = src + ((size_t)(b * 128) + g * 16) * P;
  float s1 = 0.f, s2 = 0.f;
  for (int i = t; i < 16 * P; i += 256) {
    float v = base[i];
    s1 += v; s2 += v * v;
  }
  for (int m = 1; m < 64; m <<= 1) { s1 += __shfl_xor(s1, m); s2 += __shfl_xor(s2, m); }
  if ((t & 63) == 0) { l1[t >> 6] = s1; l2[t >> 6] = s2; }
  __syncthreads();
  if (t == 0) {
    float invN = 1.f / (16.f * (float)P);
    float a = l1[0] + l1[1] + l1[2] + l1[3];
    float bq = l2[0] + l2[1] + l2[2] + l2[3];
    float mu = a * invN;
    float var = bq * invN - mu * mu;
    murs[blockIdx.x * 2] = mu;
    murs[blockIdx.x * 2 + 1] = rsqrtf(var + eps);
  }
}

// ---------- kf branch: fused L2-norm + 384->128 conv+proj (MFMA) ----------

__global__ __launch_bounds__(256) void k_kf(
    const float* __restrict__ feat,
    const _Float16* __restrict__ KFB, const _Float16* __restrict__ KFPB,
    float* __restrict__ y_kf, float* __restrict__ skip_kf) {
  __shared__ __align__(16) _Float16 fnF[24 * 4 * 64 * 4];  // 48KB, A-frags
  __shared__ float ssqL[4][64];
  __shared__ float rsqL[64];
  int t = threadIdx.x, l = t & 63, w = t >> 6;
  int b = blockIdx.x >> 2, tile = blockIdx.x & 3;
  int p0 = tile * 49;
  const float* fb = feat + (size_t)b * VD * NKk;
  {
    float s = 0.f;
    if (l < 49) {
#pragma unroll 4
      for (int k = w; k < VD; k += 4) {
        float v = fb[(size_t)k * NKk + p0 + l];
        s += v * v;
      }
    }
    ssqL[w][l] = s;
  }
  __syncthreads();
  if (t < 64) {
    float s = ssqL[0][t] + ssqL[1][t] + ssqL[2][t] + ssqL[3][t];
    rsqL[t] = rsqrtf(fmaxf(s, 1e-24f));
  }
  __syncthreads();
  for (int i = t; i < VD * 64; i += 256) {
    int k = i >> 6, p = i & 63;
    float v = 0.f;
    if (p < 49) v = fb[(size_t)k * NKk + p0 + p] * rsqL[p];
    int kt = k >> 4, kr = k & 15, u = kr >> 2, j = kr & 3, mt = p >> 4;
    fnF[(((kt * 4 + mt) * 64) + (p & 15) + 16 * u) * 4 + j] = (_Float16)v;
  }
  __syncthreads();
  f32x4 z = {0.f, 0.f, 0.f, 0.f};
  f32x4 accY[4][2], accS[4][2];
#pragma unroll
  for (int mt = 0; mt < 4; ++mt)
#pragma unroll
    for (int cc = 0; cc < 2; ++cc) { accY[mt][cc] = z; accS[mt][cc] = z; }
  for (int kt = 0; kt < 24; ++kt) {
    h16x4 a[4];
#pragma unroll
    for (int mt = 0; mt < 4; ++mt)
      a[mt] = *(const h16x4*)&fnF[((kt * 4 + mt) * 64 + l) * 4];
    int fi = (kt * 8 + 2 * w) * 64 + l;
    h16x4 by0 = *(const h16x4*)(KFB + (size_t)fi * 4);
    h16x4 by1 = *(const h16x4*)(KFB + (size_t)(fi + 64) * 4);
    h16x4 bs0 = *(const h16x4*)(KFPB + (size_t)fi * 4);
    h16x4 bs1 = *(const h16x4*)(KFPB + (size_t)(fi + 64) * 4);
#pragma unroll
    for (int mt = 0; mt < 4; ++mt) {
      accY[mt][0] = mfma16(a[mt], by0, accY[mt][0]);
      accY[mt][1] = mfma16(a[mt], by1, accY[mt][1]);
      accS[mt][0] = mfma16(a[mt], bs0, accS[mt][0]);
      accS[mt][1] = mfma16(a[mt], bs1, accS[mt][1]);
    }
  }
#pragma unroll
  for (int cc = 0; cc < 2; ++cc) {
    int co = (2 * w + cc) * 16 + (l & 15);
#pragma unroll
    for (int mt = 0; mt < 4; ++mt)
#pragma unroll
      for (int r = 0; r < 4; ++r) {
        int pix = mt * 16 + 4 * (l >> 4) + r;
        if (pix < 49) {
          size_t off = ((size_t)(b * 128) + co) * NKk + p0 + pix;
          y_kf[off] = accY[mt][cc][r];
          skip_kf[off] = accS[mt][cc][r];
        }
      }
  }
}

// ---------- merged SFT + RMSNorm + k-proj (MFMA) ----------

__global__ __launch_bounds__(256) void k_ksft(
    const float* __restrict__ y_kf, const float* __restrict__ skip_kf,
    const float* __restrict__ kf_murs, const float* __restrict__ kgn_murs,
    const _Float16* __restrict__ GB, const _Float16* __restrict__ BBf,
    const _Float16* __restrict__ KPB,
    const float* __restrict__ k_pool, const float* __restrict__ k_proj_b,
    float* __restrict__ kpb) {
  __shared__ __align__(16) _Float16 kfF[8 * 4 * 64 * 4];  // 16KB A-frags
  __shared__ float msL[4][64];
  __shared__ float sMu[8], sRs[8], sGmu[8], sGrs[8];
  int t = threadIdx.x, l = t & 63, w = t >> 6;
  int b = blockIdx.x >> 2, tile = blockIdx.x & 3;
  int p0 = tile * 49;
  if (t < 8) {
    sMu[t] = kf_murs[(b * 8 + t) * 2];
    sRs[t] = kf_murs[(b * 8 + t) * 2 + 1];
    sGmu[t] = kgn_murs[(b * 8 + t) * 2];
    sGrs[t] = kgn_murs[(b * 8 + t) * 2 + 1];
  }
  __syncthreads();
  for (int i = t; i < 128 * 64; i += 256) {
    int c = i >> 6, p = i & 63;
    float v = 0.f;
    if (p < 49) {
      size_t off = ((size_t)(b * 128) + c) * NKk + p0 + p;
      int g = c >> 4;
      v = silu_f((y_kf[off] - sMu[g]) * sRs[g]) + skip_kf[off];
    }
    int kt = c >> 4, kr = c & 15, u = kr >> 2, j = kr & 3, mt = p >> 4;
    kfF[(((kt * 4 + mt) * 64) + (p & 15) + 16 * u) * 4 + j] = (_Float16)v;
  }
  __syncthreads();
  f32x4 z = {0.f, 0.f, 0.f, 0.f};
  f32x4 accG[4][2], accB[4][2];
#pragma unroll
  for (int mt = 0; mt < 4; ++mt)
#pragma unroll
    for (int cc = 0; cc < 2; ++cc) { accG[mt][cc] = z; accB[mt][cc] = z; }
  for (int kt = 0; kt < 8; ++kt) {
    h16x4 a[4];
#pragma unroll
    for (int mt = 0; mt < 4; ++mt)
      a[mt] = *(const h16x4*)&kfF[((kt * 4 + mt) * 64 + l) * 4];
    int fi = (kt * 8 + 2 * w) * 64 + l;
    h16x4 bg0 = *(const h16x4*)(GB + (size_t)fi * 4);
    h16x4 bg1 = *(const h16x4*)(GB + (size_t)(fi + 64) * 4);
    h16x4 bb0 = *(const h16x4*)(BBf + (size_t)fi * 4);
    h16x4 bb1 = *(const h16x4*)(BBf + (size_t)(fi + 64) * 4);
#pragma unroll
    for (int mt = 0; mt < 4; ++mt) {
      accG[mt][0] = mfma16(a[mt], bg0, accG[mt][0]);
      accG[mt][1] = mfma16(a[mt], bg1, accG[mt][1]);
      accB[mt][0] = mfma16(a[mt], bb0, accB[mt][0]);
      accB[mt][1] = mfma16(a[mt], bb1, accB[mt][1]);
    }
  }
  float kfin[4][2][4];
#pragma unroll
  for (int cc = 0; cc < 2; ++cc) {
    int g = 2 * w + cc;
    int co = g * 16 + (l & 15);
    float gmu = sGmu[g], grs = sGrs[g];
#pragma unroll
    for (int mt = 0; mt < 4; ++mt)
#pragma unroll
      for (int r = 0; r < 4; ++r) {
        int pix = mt * 16 + 4 * (l >> 4) + r;
        float v = 0.f;
        if (pix < 49) {
          float kn = (k_pool[((size_t)(b * 128) + co) * NKk + p0 + pix] - gmu) * grs;
          v = fmaf(accG[mt][cc][r], kn, accB[mt][cc][r]);
        }
        kfin[mt][cc][r] = v;
      }
  }
#pragma unroll
  for (int mt = 0; mt < 4; ++mt)
#pragma unroll
    for (int r = 0; r < 4; ++r) {
      float s2 = kfin[mt][0][r] * kfin[mt][0][r] + kfin[mt][1][r] * kfin[mt][1][r];
      for (int m = 1; m < 16; m <<= 1) s2 += __shfl_xor(s2, m);
      if ((l & 15) == 0) msL[w][mt * 16 + 4 * (l >> 4) + r] = s2;
    }
  __syncthreads();
#pragma unroll
  for (int cc = 0; cc < 2; ++cc) {
    int ktn = 2 * w + cc;
    int u = (l & 15) >> 2, j = (l & 15) & 3;
#pragma unroll
    for (int mt = 0; mt < 4; ++mt)
#pragma unroll
      for (int r = 0; r < 4; ++r) {
        int lane = (4 * (l >> 4) + r) + 16 * u;
        kfF[((ktn * 4 + mt) * 64 + lane) * 4 + j] = (_Float16)kfin[mt][cc][r];
      }
  }
  __syncthreads();
  f32x4 accP[4][2];
#pragma unroll
  for (int mt = 0; mt < 4; ++mt)
#pragma unroll
    for (int cc = 0; cc < 2; ++cc) accP[mt][cc] = z;
  for (int kt = 0; kt < 8; ++kt) {
    h16x4 a[4];
#pragma unroll
    for (int mt = 0; mt < 4; ++mt)
      a[mt] = *(const h16x4*)&kfF[((kt * 4 + mt) * 64 + l) * 4];
    int fi = (kt * 8 + 2 * w) * 64 + l;
    h16x4 b0 = *(const h16x4*)(KPB + (size_t)fi * 4);
    h16x4 b1 = *(const h16x4*)(KPB + (size_t)(fi + 64) * 4);
#pragma unroll
    for (int mt = 0; mt < 4; ++mt) {
      accP[mt][0] = mfma16(a[mt], b0, accP[mt][0]);
      accP[mt][1] = mfma16(a[mt], b1, accP[mt][1]);
    }
  }
#pragma unroll
  for (int mt = 0; mt < 4; ++mt)
#pragma unroll
    for (int r = 0; r < 4; ++r) {
      int pix = mt * 16 + 4 * (l >> 4) + r;
      if (pix >= 49) continue;
      float ms = msL[0][pix] + msL[1][pix] + msL[2][pix] + msL[3][pix];
      float rr = rsqrtf(ms * (1.f / 128.f) + EPS_RMS);
#pragma unroll
      for (int cc = 0; cc < 2; ++cc) {
        int co = (2 * w + cc) * 16 + (l & 15);
        kpb[((size_t)(b * 196) + p0 + pix) * 128 + co] =
            accP[mt][cc][r] * rr + k_proj_b[co];
      }
    }
}

// ---------- fused 3x3 conv + RMSNorm + q-proj (K=32 MFMA conv, LDS input,
// SW-pipelined weight stream) ----------

__global__ __launch_bounds__(256) void k_conv3f(
    const float* __restrict__ q_pool, const float* __restrict__ murs2,
    const _Float16* __restrict__ W3B, const _Float16* __restrict__ QPB,
    const float* __restrict__ bias, float* __restrict__ qp) {
  __shared__ __align__(16) _Float16 tileL[100 * 136];  // 27.2 KB
  __shared__ float sMu[8], sRs[8];
  int t = threadIdx.x, l = t & 63, w = t >> 6;
  int b = blockIdx.x / 196, reg = blockIdx.x % 196;
  int y0 = (reg / 14) * 8, x0 = (reg % 14) * 8;
  if (t < 8) { sMu[t] = murs2[(b * 8 + t) * 2]; sRs[t] = murs2[(b * 8 + t) * 2 + 1]; }
  __syncthreads();
  for (int i = t; i < 3200; i += 256) {
    int rowp = i >> 5, c4 = i & 31;
    int gy = y0 - 1 + rowp / 10, gx = x0 - 1 + rowp % 10;
    h16x4 hv = {(_Float16)0.f, (_Float16)0.f, (_Float16)0.f, (_Float16)0.f};
    if (gy >= 0 && gy < 112 && gx >= 0 && gx < 112) {
      f32x4 v = *(const f32x4*)(q_pool + ((size_t)(b * NQ) + gy * 112 + gx) * 128 +
                                c4 * 4);
      int g = c4 >> 2;
      float mu = sMu[g], rs = sRs[g];
#pragma unroll
      for (int j = 0; j < 4; ++j) hv[j] = (_Float16)((v[j] - mu) * rs);
    }
    *(h16x4*)&tileL[rowp * 136 + c4 * 4] = hv;
  }
  __syncthreads();
  f32x4 z = {0.f, 0.f, 0.f, 0.f};
  f32x4 acc[8];
#pragma unroll
  for (int ct = 0; ct < 8; ++ct) acc[ct] = z;
  int lm = l & 15;
  int mrow = lm >> 3, mcol = lm & 7;
  const h16x8* W3l = (const h16x8*)W3B + l;
  h16x8 wbuf[3][8];
#pragma unroll
  for (int ct = 0; ct < 8; ++ct) wbuf[0][ct] = W3l[ct * 64];
#pragma unroll
  for (int ct = 0; ct < 8; ++ct) wbuf[1][ct] = W3l[(8 + ct) * 64];
#pragma unroll
  for (int s = 0; s < 36; ++s) {
    if (s + 2 < 36) {
#pragma unroll
      for (int ct = 0; ct < 8; ++ct)
        wbuf[(s + 2) % 3][ct] = W3l[((s + 2) * 8 + ct) * 64];
    }
    int tap = s >> 2, kt2 = s & 3;
    int prow = (2 * w + mrow + tap / 3) * 10 + (mcol + tap % 3);
    h16x8 bf = *(const h16x8*)&tileL[prow * 136 + kt2 * 32 + 8 * (l >> 4)];
#pragma unroll
    for (int ct = 0; ct < 8; ++ct)
      acc[ct] = mfma32(wbuf[s % 3][ct], bf, acc[ct]);
  }
  float sq = 0.f;
#pragma unroll
  for (int ct = 0; ct < 8; ++ct)
#pragma unroll
    for (int r = 0; r < 4; ++r) sq += acc[ct][r] * acc[ct][r];
  sq += __shfl_xor(sq, 16);
  sq += __shfl_xor(sq, 32);
  float rr = rsqrtf(sq * (1.f / 128.f) + EPS_RMS);
  int chof = 4 * (l >> 4);
  h16x4 pb[8];
#pragma unroll
  for (int kt = 0; kt < 8; ++kt)
#pragma unroll
    for (int j = 0; j < 4; ++j) pb[kt][j] = (_Float16)acc[kt][j];
  f32x4 accP[8];
#pragma unroll
  for (int ct = 0; ct < 8; ++ct) accP[ct] = z;
  const h16x4* QP = (const h16x4*)QPB + l;
#pragma unroll
  for (int kt = 0; kt < 8; ++kt) {
#pragma unroll
    for (int ct = 0; ct < 8; ++ct)
      accP[ct] = mfma16(QP[(kt * 8 + ct) * 64], pb[kt], accP[ct]);
  }
  int py = y0 + 2 * w + mrow, px = x0 + mcol;
  size_t pbase = ((size_t)(b * NQ) + py * 112 + px) * 128;
#pragma unroll
  for (int ct = 0; ct < 8; ++ct) {
    f32x4 o;
#pragma unroll
    for (int r = 0; r < 4; ++r)
      o[r] = accP[ct][r] * rr + bias[ct * 16 + chof + r];
    *(f32x4*)(qp + pbase + ct * 16 + chof) = o;
  }
}

// ---------- attention: QK^T (K=32) + softmax + head-mean -> packed fp16 P ----------

__global__ __launch_bounds__(256) void k_attn1m(
    const float* __restrict__ qp, const float* __restrict__ kpb,
    _Float16* __restrict__ Ph) {
  __shared__ float sP[4][16][212];
  int t = threadIdx.x, l = t & 63, h = t >> 6;
  int b = blockIdx.x / 784, qt = blockIdx.x % 784;
  int q0 = qt * 16;
  constexpr float SC = 0.17677669529663687f;  // 1/sqrt(32)
  h16x8 aq;
  {
    const float* qrow = qp + ((size_t)(b * NQ) + q0 + (l & 15)) * 128 +
                        h * 32 + 8 * (l >> 4);
    f32x4 v0 = *(const f32x4*)qrow;
    f32x4 v1 = *(const f32x4*)(qrow + 4);
#pragma unroll
    for (int j = 0; j < 4; ++j) { aq[j] = (_Float16)v0[j]; aq[j + 4] = (_Float16)v1[j]; }
  }
  f32x4 z = {0.f, 0.f, 0.f, 0.f};
  f32x4 acc[13];
#pragma unroll
  for (int nt = 0; nt < 13; ++nt) acc[nt] = z;
#pragma unroll
  for (int nt = 0; nt < 13; ++nt) {
    int key = nt * 16 + (l & 15);
    bool ok = key < 196;
    h16x8 bf = {(_Float16)0.f, (_Float16)0.f, (_Float16)0.f, (_Float16)0.f,
                (_Float16)0.f, (_Float16)0.f, (_Float16)0.f, (_Float16)0.f};
    if (ok) {
      const float* krow = kpb + ((size_t)(b * 196) + key) * 128 +
                          h * 32 + 8 * (l >> 4);
      f32x4 v0 = *(const f32x4*)krow;
      f32x4 v1 = *(const f32x4*)(krow + 4);
#pragma unroll
      for (int j = 0; j < 4; ++j) { bf[j] = (_Float16)v0[j]; bf[j + 4] = (_Float16)v1[j]; }
    }
    acc[nt] = mfma32(aq, bf, acc[nt]);
  }
#pragma unroll
  for (int r = 0; r < 4; ++r) {
    float mx = -3e38f;
#pragma unroll
    for (int nt = 0; nt < 13; ++nt) {
      bool ok = nt * 16 + (l & 15) < 196;
      float v = ok ? acc[nt][r] * SC : -3e38f;
      acc[nt][r] = v;
      mx = fmaxf(mx, v);
    }
    for (int m = 1; m < 16; m <<= 1) mx = fmaxf(mx, __shfl_xor(mx, m));
    float sum = 0.f;
#pragma unroll
    for (int nt = 0; nt < 13; ++nt) {
      bool ok = nt * 16 + (l & 15) < 196;
      float e = ok ? __expf(acc[nt][r] - mx) : 0.f;
      acc[nt][r] = e;
      sum += e;
    }
    for (int m = 1; m < 16; m <<= 1) sum += __shfl_xor(sum, m);
    float inv = 1.f / sum;
#pragma unroll
    for (int nt = 0; nt < 13; ++nt)
      sP[h][4 * (l >> 4) + r][nt * 16 + (l & 15)] = acc[nt][r] * inv;
  }
  __syncthreads();
  _Float16* pb = Ph + (size_t)(b * 784 + qt) * 13 * 256;
  for (int i = t; i < 832; i += 256) {
    int kt = i >> 6, ll = i & 63;
    int q = ll & 15, kb = kt * 16 + 4 * (ll >> 4);
    h16x4 v;
#pragma unroll
    for (int j = 0; j < 4; ++j) {
      int k = kb + j;
      float s = 0.25f * (sP[0][q][k] + sP[1][q][k] + sP[2][q][k] + sP[3][q][k]);
      v[j] = (_Float16)s;
    }
    *(h16x4*)(pb + (size_t)i * 4) = v;
  }
}

// ---------- attention PV: pure fragment streaming, no LDS ----------

__global__ __launch_bounds__(256) void k_attn2m(
    const _Float16* __restrict__ Ph, const _Float16* __restrict__ featB,
    float* __restrict__ out) {
  int t = threadIdx.x, l = t & 63, w = t >> 6;
  int b = blockIdx.x / 196, qt = blockIdx.x % 196;
  int q16 = qt * 4 + w;
  f32x4 z = {0.f, 0.f, 0.f, 0.f};
  f32x4 acc[24];
#pragma unroll
  for (int dt = 0; dt < 24; ++dt) acc[dt] = z;
  const h16x4* PB = (const h16x4*)Ph + ((size_t)(b * 784 + q16) * 13) * 64 + l;
  const h16x4* FB = (const h16x4*)featB + (size_t)b * 13 * 24 * 64 + l;
  for (int kt = 0; kt < 13; ++kt) {
    h16x4 bp = PB[kt * 64];
    const h16x4* fb = FB + kt * 24 * 64;
#pragma unroll
    for (int dt = 0; dt < 24; ++dt)
      acc[dt] = mfma16(fb[(size_t)dt * 64], bp, acc[dt]);
  }
  int qg = q16 * 16 + (l & 15);
#pragma unroll
  for (int dt = 0; dt < 24; ++dt)
#pragma unroll
    for (int r = 0; r < 4; ++r) {
      int d = dt * 16 + 4 * (l >> 4) + r;
      out[((size_t)(b * 384) + d) * NQ + qg] = acc[dt][r];
    }
}

}  // namespace

extern "C" void kernel_launch(void* const* d_in, const int* in_sizes, int n_in,
                              void* d_out, int out_size, void* d_ws,
                              size_t ws_size, hipStream_t stream) {
  (void)in_sizes; (void)n_in; (void)out_size; (void)ws_size;
  const float* image        = (const float*)d_in[0];
  const float* features     = (const float*)d_in[1];
  const float* rope_f       = (const float*)d_in[2];
  const float* img_conv_w   = (const float*)d_in[3];
  const float* img_proj_w   = (const float*)d_in[4];
  const float* qenc_w       = (const float*)d_in[5];
  const float* kenc_w       = (const float*)d_in[6];
  const float* kfeat_conv_w = (const float*)d_in[7];
  const float* kfeat_proj_w = (const float*)d_in[8];
  const float* sft_gamma_w  = (const float*)d_in[9];
  const float* sft_beta_w   = (const float*)d_in[10];
  const float* block_conv_w = (const float*)d_in[11];
  const float* rms_q_w      = (const float*)d_in[12];
  const float* rms_k_w      = (const float*)d_in[13];
  const float* q_proj_w     = (const float*)d_in[14];
  const float* q_proj_b     = (const float*)d_in[15];
  const float* k_proj_w     = (const float*)d_in[16];
  const float* k_proj_b     = (const float*)d_in[17];
  float* out = (float*)d_out;
  float* ws = (float*)d_ws;

  size_t off = 0;
  auto alloc = [&](size_t n) {
    size_t r = off;
    off += (n + 63) & ~(size_t)63;
    return r;
  };
  _Float16* WqB  = (_Float16*)(ws + alloc(8192));
  _Float16* WkB  = (_Float16*)(ws + alloc(8192));
  _Float16* QPB  = (_Float16*)(ws + alloc(8192));
  _Float16* W3B  = (_Float16*)(ws + alloc(73728));
  _Float16* KFB  = (_Float16*)(ws + alloc(24576));
  _Float16* KFPB = (_Float16*)(ws + alloc(24576));
  _Float16* GB   = (_Float16*)(ws + alloc(8192));
  _Float16* BBf  = (_Float16*)(ws + alloc(8192));
  _Float16* KPB  = (_Float16*)(ws + alloc(8192));
  float* cosT     = ws + alloc(14336);
  float* sinT     = ws + alloc(14336);
  _Float16* featB = (_Float16*)(ws + alloc(159744));
  float* imgpart  = ws + alloc(2304);
  float* img_murs = ws + alloc(64);
  float* qk_murs  = ws + alloc(128);
  float* murs2    = ws + alloc(64);
  float* kgn_murs = ws + alloc(64);
  float* kf_murs  = ws + alloc(64);
  float* G        = ws + alloc(65536);
  float* mvec     = ws + alloc(512);
  float* mpart    = ws + alloc(392 * 128);
  float* Qpart    = ws + alloc((size_t)BB * 784 * 16);
  float* kpp      = ws + alloc((size_t)BB * 784 * 128);
  float* y_kf     = ws + alloc(100352);
  float* skip_kf  = ws + alloc(100352);
  float* k_pool   = ws + alloc(100352);
  float* kpb      = ws + alloc(100352);
  // RA (25.7MB): Gpart -> q_pool
  float* RA = ws + alloc((size_t)BB * NQ * 128);
  // ENC (51.4MB): encF -> (qp, Ph)
  float* ENCp = ws + alloc((size_t)BB * 784 * 8192 / 2);
  float* Gpart  = RA;
  float* q_pool = RA;
  _Float16* encF = (_Float16*)ENCp;
  float* qp      = ENCp;                                      // after encF dead
  _Float16* Ph   = (_Float16*)(ENCp + (size_t)BB * NQ * 128); // after qp

  k_prep<<<2648, 256, 0, stream>>>(qenc_w, kenc_w, q_proj_w, rms_q_w,
                                   block_conv_w, kfeat_conv_w, kfeat_proj_w,
                                   sft_gamma_w, sft_beta_w, k_proj_w, rms_k_w,
                                   rope_f, features,
                                   WqB, WkB, QPB, W3B, KFB, KFPB, GB, BBf, KPB,
                                   cosT, sinT, featB);

  k_imgstat1<<<BB * 64, 256, 0, stream>>>(image, imgpart);
  k_imgstat2<<<BB, 128, 0, stream>>>(imgpart, img_conv_w, img_murs);

  k_kf<<<BB * 4, 256, 0, stream>>>(features, KFB, KFPB, y_kf, skip_kf);
  k_gnstats<<<32, 256, 0, stream>>>(y_kf, kf_murs, NKk, EPS_GN);

  k_gram<<<BB * 98, 256, 0, stream>>>(image, cosT, sinT, img_conv_w,
                                      img_proj_w, img_murs, encF, Gpart, mpart);
  k_gred<<<BB * 64, 256, 0, stream>>>(Gpart, mpart, G, mvec);
  k_gstats<<<64, 256, 0, stream>>>(G, mvec, qenc_w, kenc_w, qk_murs);

  k_passA2<<<BB * 784, 256, 0, stream>>>(encF, qk_murs, WqB, WkB,
                                         q_pool, kpp, Qpart);
  k_qstatfin<<<32, 256, 0, stream>>>(Qpart, murs2);
  k_kpred<<<392, 256, 0, stream>>>(kpp, k_pool);
  k_gnstats<<<32, 256, 0, stream>>>(k_pool, kgn_murs, NKk, EPS_GN);

  k_ksft<<<BB * 4, 256, 0, stream>>>(y_kf, skip_kf, kf_murs, kgn_murs,
                                     GB, BBf, KPB, k_pool, k_proj_b, kpb);

  k_conv3f<<<BB * 196, 256, 0, stream>>>(q_pool, murs2, W3B, QPB, q_proj_b, qp);

  k_attn1m<<<BB * 784, 256, 0, stream>>>(qp, kpb, Ph);
  k_attn2m<<<BB * 196, 256, 0, stream>>>(Ph, featB, out);
}

// Round 16
// 369.460 us; speedup vs baseline: 1.2837x; 1.0559x over previous
//
#include <hip/hip_runtime.h>
#include <cstdint>
#include <cstddef>

#define DEV __device__ __forceinline__

namespace {

constexpr int BB   = 4;
constexpr int HWP  = 50176;   // 224*224
constexpr int NQ   = 12544;   // 112*112
constexpr int NKk  = 196;     // 14*14
constexpr int VD   = 384;
constexpr float EPS_GN  = 1e-5f;
constexpr float EPS_RMS = 1.1920929e-7f;

typedef __attribute__((ext_vector_type(4))) float f32x4;
typedef __attribute__((ext_vector_type(4))) _Float16 h16x4;
typedef __attribute__((ext_vector_type(8))) _Float16 h16x8;

// silu via HW rcp (<=1 ulp) instead of IEEE division: saves ~8 VALU inst/use
DEV float silu_f(float z) {
  return z * __builtin_amdgcn_rcpf(1.f + __expf(-z));
}
DEV int rfl(int v) { return __builtin_amdgcn_readfirstlane(v); }

DEV f32x4 mfma16(h16x4 a, h16x4 b, f32x4 c) {
  return __builtin_amdgcn_mfma_f32_16x16x16f16(a, b, c, 0, 0, 0);
}
DEV f32x4 mfma32(h16x8 a, h16x8 b, f32x4 c) {
  return __builtin_amdgcn_mfma_f32_16x16x32_f16(a, b, c, 0, 0, 0);
}

// ---------- fused weight prep (one launch) ----------
DEV void pack16_one(int id, const float* W, const float* rowscale,
                    _Float16* dst) {
  int j = id & 3, l = (id >> 2) & 63, tile = id >> 8;
  int ct = tile & 7, kt = tile >> 3;
  int ci = kt * 16 + 4 * (l >> 4) + j;
  int co = ct * 16 + (l & 15);
  float v = W[(size_t)co * 128 + ci];
  if (rowscale) v *= rowscale[ci];
  dst[id] = (_Float16)v;
}
// K=32 pack for 128x128 weight, channel map matching paired K=16 enc frags
DEV void pack32_one(int id, const float* W, _Float16* dst) {
  int j = id & 7, l = (id >> 3) & 63, ct = (id >> 9) & 7, kt2 = id >> 12;
  int u = l >> 4;
  int ci = kt2 * 32 + ((j < 4) ? (4 * u + j) : (16 + 4 * u + (j - 4)));
  int co = ct * 16 + (l & 15);
  dst[id] = (_Float16)W[(size_t)co * 128 + ci];
}
// pack 128x384 weight into frag order, K=384 (24 kt)
DEV void pack384_one(int id, const float* W, _Float16* dst) {
  int j = id & 3, l = (id >> 2) & 63, rest = id >> 8;
  int ct = rest & 7, kt = rest >> 3;          // kt 0..23
  int ci = kt * 16 + 4 * (l >> 4) + j;
  int co = ct * 16 + (l & 15);
  dst[id] = (_Float16)W[(size_t)co * 384 + ci];
}

__global__ __launch_bounds__(256) void k_prep(
    const float* __restrict__ qenc_w, const float* __restrict__ kenc_w,
    const float* __restrict__ q_proj_w, const float* __restrict__ rms_q_w,
    const float* __restrict__ block_conv_w,
    const float* __restrict__ kfeat_conv_w, const float* __restrict__ kfeat_proj_w,
    const float* __restrict__ sft_gamma_w, const float* __restrict__ sft_beta_w,
    const float* __restrict__ k_proj_w, const float* __restrict__ rms_k_w,
    const float* __restrict__ ropef, const float* __restrict__ feat,
    _Float16* __restrict__ WqB, _Float16* __restrict__ WkB,
    _Float16* __restrict__ QPB, _Float16* __restrict__ W3B,
    _Float16* __restrict__ KFB, _Float16* __restrict__ KFPB,
    _Float16* __restrict__ GB, _Float16* __restrict__ BBf,
    _Float16* __restrict__ KPB,
    float* __restrict__ cosT, float* __restrict__ sinT,
    _Float16* __restrict__ featB) {
  int idx = blockIdx.x * 256 + threadIdx.x;
  if (idx < 16384) {
    pack32_one(idx, qenc_w, WqB);                 // K=32 pack
  } else if (idx < 32768) {
    pack32_one(idx - 16384, kenc_w, WkB);         // K=32 pack
  } else if (idx < 49152) {
    pack16_one(idx - 32768, q_proj_w, rms_q_w, QPB);
  } else if (idx < 196608) {
    // K=32 frag order for conv: frag id = (tap*4+kt2)*8+ct, lane l, elem j
    int id = idx - 49152;
    int j = id & 7, l = (id >> 3) & 63, ct = (id >> 9) & 7;
    int kt2 = (id >> 12) & 3, tap = id >> 14;
    int ci = kt2 * 32 + 8 * (l >> 4) + j;
    int co = ct * 16 + (l & 15);
    W3B[id] = (_Float16)block_conv_w[((size_t)co * 128 + ci) * 9 + tap];
  } else if (idx < 245760) {
    pack384_one(idx - 196608, kfeat_conv_w, KFB);
  } else if (idx < 294912) {
    pack384_one(idx - 245760, kfeat_proj_w, KFPB);
  } else if (idx < 311296) {
    pack16_one(idx - 294912, sft_gamma_w, nullptr, GB);
  } else if (idx < 327680) {
    pack16_one(idx - 311296, sft_beta_w, nullptr, BBf);
  } else if (idx < 344064) {
    pack16_one(idx - 327680, k_proj_w, rms_k_w, KPB);
  } else if (idx < 358400) {
    int id = idx - 344064;            // pos*64 + d
    int pos = id >> 6, d = id & 63;
    float a = (pos + 0.5f) * (1.f / 224.f) * ropef[d];
    float s, c;
    __sincosf(a, &s, &c);
    cosT[id] = c;
    sinT[id] = s;
  } else if (idx < 677888) {
    int id = idx - 358400;            // (((b*13+kt)*24+dt)*64+l)*4+j
    int j = id & 3, l = (id >> 2) & 63;
    int rest = id >> 8;
    int dt = rest % 24;
    int kt = (rest / 24) % 13;
    int b = rest / (24 * 13);
    int key = kt * 16 + 4 * (l >> 4) + j;
    int d = dt * 16 + (l & 15);
    float v = (key < 196) ? feat[((size_t)(b * 384) + d) * 196 + key] : 0.f;
    featB[id] = (_Float16)v;
  }
}

// ---------- image GN stats via 3x3 Gram ----------

__global__ __launch_bounds__(256) void k_imgstat1(
    const float* __restrict__ img, float* __restrict__ part) {
  __shared__ float lds[4][9];
  int b = blockIdx.x >> 6, blk = blockIdx.x & 63;
  int t = threadIdx.x;
  float a[9];
#pragma unroll
  for (int j = 0; j < 9; ++j) a[j] = 0.f;
  const float* ib = img + (size_t)b * 3 * HWP;
  for (int pix = blk * 784 + t; pix < blk * 784 + 784; pix += 256) {
    float x0 = ib[pix], x1 = ib[HWP + pix], x2 = ib[2 * HWP + pix];
    a[0] += x0; a[1] += x1; a[2] += x2;
    a[3] += x0 * x0; a[4] += x0 * x1; a[5] += x0 * x2;
    a[6] += x1 * x1; a[7] += x1 * x2; a[8] += x2 * x2;
  }
#pragma unroll
  for (int j = 0; j < 9; ++j)
    for (int m = 1; m < 64; m <<= 1) a[j] += __shfl_xor(a[j], m);
  if ((t & 63) == 0)
    for (int j = 0; j < 9; ++j) lds[t >> 6][j] = a[j];
  __syncthreads();
  if (t < 9)
    part[(size_t)blockIdx.x * 9 + t] =
        lds[0][t] + lds[1][t] + lds[2][t] + lds[3][t];
}

__global__ __launch_bounds__(128) void k_imgstat2(
    const float* __restrict__ part, const float* __restrict__ wimg,
    float* __restrict__ img_murs) {
  __shared__ float MG[9];
  int b = blockIdx.x, t = threadIdx.x;
  if (t < 9) {
    float s = 0.f;
    for (int i = 0; i < 64; ++i) s += part[(size_t)(b * 64 + i) * 9 + t];
    MG[t] = s;
  }
  __syncthreads();
  int c = t;
  float w0 = wimg[c * 3], w1 = wimg[c * 3 + 1], w2 = wimg[c * 3 + 2];
  float s1 = w0 * MG[0] + w1 * MG[1] + w2 * MG[2];
  float s2 = w0 * w0 * MG[3] + w1 * w1 * MG[6] + w2 * w2 * MG[8] +
             2.f * (w0 * w1 * MG[4] + w0 * w2 * MG[5] + w1 * w2 * MG[7]);
  for (int m = 1; m < 16; m <<= 1) {
    s1 += __shfl_xor(s1, m);
    s2 += __shfl_xor(s2, m);
  }
  if ((c & 15) == 0) {
    int g = c >> 4;
    float invN = 1.f / (16.f * HWP);
    float mu = s1 * invN;
    float var = s2 * invN - mu * mu;
    img_murs[b * 16 + g] = mu;
    img_murs[b * 16 + 8 + g] = rsqrtf(var + EPS_GN);
  }
}

// ---------- enc producer + Gram + enc_frag materialization ----------
// encF is written as paired K=32 fragments: h16x8 index (kt2*4+mt)*64+l,
// elems 0-3 from K=16 frag kt=2kt2, elems 4-7 from kt=2kt2+1.

__global__ __launch_bounds__(256) void k_gram(
    const float* __restrict__ img, const float* __restrict__ cosT,
    const float* __restrict__ sinT,
    const float* __restrict__ wimg, const float* __restrict__ wimgp,
    const float* __restrict__ img_murs,
    _Float16* __restrict__ encF,
    float* __restrict__ Gpart, float* __restrict__ mpart) {
  __shared__ __align__(16) _Float16 fragP[2080 * 4];   // [kt*4+mt][lane(65 pad)][j]
  __shared__ __align__(16) _Float16 fragC[8192];       // [pk][ct][lane][j]
  __shared__ float sWc[384], sWp[384], sMu[8], sRs[8];
  int t = threadIdx.x, l = t & 63, w = t >> 6;
  int b = blockIdx.x / 98, blk = blockIdx.x % 98;
  for (int i = t; i < 384; i += 256) { sWc[i] = wimg[i]; sWp[i] = wimgp[i]; }
  if (t < 8) { sMu[t] = img_murs[b * 16 + t]; sRs[t] = img_murs[b * 16 + 8 + t]; }
  f32x4 acc[2][8];
  f32x4 macc[2];
  f32x4 z = {0.f, 0.f, 0.f, 0.f};
#pragma unroll
  for (int e = 0; e < 2; ++e) {
    macc[e] = z;
#pragma unroll
    for (int nt = 0; nt < 8; ++nt) acc[e][nt] = z;
  }
  h16x4 hone = {(_Float16)1.f, (_Float16)1.f, (_Float16)1.f, (_Float16)1.f};
  int mt = l >> 4;
  int laneCbase = 16 * ((l & 15) >> 2);
  int jC = (l & 15) & 3;
  for (int s = 0; s < 8; ++s) {
    int sub = blk * 8 + s;
    int tile = sub >> 2, st = sub & 3;
    int py = (tile / 14) * 16 + ((st >> 1) << 3) + (l >> 3);
    int px = (tile % 14) * 16 + ((st & 1) << 3) + (l & 7);
    __syncthreads();
    {
      const float* ip = img + (size_t)b * 3 * HWP + py * 224 + px;
      float x0 = ip[0], x1 = ip[HWP], x2 = ip[2 * HWP];
      const float* cy = cosT + py * 64 + w * 16;
      const float* sy = sinT + py * 64 + w * 16;
      const float* cx = cosT + px * 64 + w * 16;
      const float* sx = sinT + px * 64 + w * 16;
#pragma unroll
      for (int jj = 0; jj < 4; ++jj) {
        f32x4 cyv = *(const f32x4*)(cy + jj * 4);
        f32x4 syv = *(const f32x4*)(sy + jj * 4);
        f32x4 cxv = *(const f32x4*)(cx + jj * 4);
        f32x4 sxv = *(const f32x4*)(sx + jj * 4);
        h16x4 lo4, hi4;
#pragma unroll
        for (int u = 0; u < 4; ++u) {
          int d = w * 16 + jj * 4 + u;
          int c2 = d + 64;
          float y1 = sWc[d * 3] * x0 + sWc[d * 3 + 1] * x1 + sWc[d * 3 + 2] * x2;
          float s1 = sWp[d * 3] * x0 + sWp[d * 3 + 1] * x1 + sWp[d * 3 + 2] * x2;
          float y2 = sWc[c2 * 3] * x0 + sWc[c2 * 3 + 1] * x1 + sWc[c2 * 3 + 2] * x2;
          float s2 = sWp[c2 * 3] * x0 + sWp[c2 * 3 + 1] * x1 + sWp[c2 * 3 + 2] * x2;
          int g1 = d >> 4, g2 = g1 + 4;
          float t1 = silu_f((y1 - sMu[g1]) * sRs[g1]) + s1;
          float t2 = silu_f((y2 - sMu[g2]) * sRs[g2]) + s2;
          lo4[u] = (_Float16)(t1 * cyv[u] - t2 * syv[u]);
          hi4[u] = (_Float16)(t2 * cxv[u] + t1 * sxv[u]);
        }
        int lane = (l & 15) + 16 * jj;
        *(h16x4*)&fragP[((w * 4 + mt) * 65 + lane) * 4]       = lo4;
        *(h16x4*)&fragP[(((w + 4) * 4 + mt) * 65 + lane) * 4] = hi4;
#pragma unroll
        for (int u = 0; u < 4; ++u) {
          int laneC = jj * 4 + u + laneCbase;
          fragC[((mt * 8 + w) * 64 + laneC) * 4 + jC]     = lo4[u];
          fragC[((mt * 8 + w + 4) * 64 + laneC) * 4 + jC] = hi4[u];
        }
      }
    }
    __syncthreads();
    // stream fragP -> encF as paired K=32 fragments (coalesced 16B stores)
    _Float16* ef = encF + ((size_t)(b * 784) + sub) * 8192;
    for (int i = t; i < 1024; i += 256) {
      int kt2 = i >> 8, m2 = (i >> 6) & 3, ln = i & 63;
      h16x4 lo = *(const h16x4*)&fragP[(((2 * kt2) * 4 + m2) * 65 + ln) * 4];
      h16x4 hi = *(const h16x4*)&fragP[(((2 * kt2 + 1) * 4 + m2) * 65 + ln) * 4];
      h16x8 v;
#pragma unroll
      for (int j = 0; j < 4; ++j) { v[j] = lo[j]; v[j + 4] = hi[j]; }
      *(h16x8*)(ef + (size_t)i * 8) = v;
    }
#pragma unroll
    for (int pk = 0; pk < 4; ++pk) {
      h16x4 a0 = *(const h16x4*)&fragC[((pk * 8 + 2 * w) * 64 + l) * 4];
      h16x4 a1 = *(const h16x4*)&fragC[((pk * 8 + 2 * w + 1) * 64 + l) * 4];
      macc[0] = mfma16(a0, hone, macc[0]);
      macc[1] = mfma16(a1, hone, macc[1]);
#pragma unroll
      for (int nt = 0; nt < 8; ++nt) {
        h16x4 bv = *(const h16x4*)&fragC[((pk * 8 + nt) * 64 + l) * 4];
        acc[0][nt] = mfma16(a0, bv, acc[0][nt]);
        acc[1][nt] = mfma16(a1, bv, acc[1][nt]);
      }
    }
  }
  float* gp = Gpart + (size_t)(b * 98 + blk) * 16384;
#pragma unroll
  for (int e = 0; e < 2; ++e)
#pragma unroll
    for (int nt = 0; nt < 8; ++nt)
#pragma unroll
      for (int r = 0; r < 4; ++r) {
        int row = (2 * w + e) * 16 + 4 * (l >> 4) + r;
        int col = nt * 16 + (l & 15);
        gp[row * 128 + col] = acc[e][nt][r];
      }
  if ((l & 15) == 0) {
    float* mp = mpart + (size_t)(b * 98 + blk) * 128;
#pragma unroll
    for (int e = 0; e < 2; ++e)
#pragma unroll
      for (int r = 0; r < 4; ++r)
        mp[(2 * w + e) * 16 + 4 * (l >> 4) + r] = macc[e][r];
  }
}

__global__ void k_gred(const float* __restrict__ Gpart,
                       const float* __restrict__ mpart,
                       float* __restrict__ G, float* __restrict__ mvec) {
  int b = blockIdx.x >> 6, chunk = blockIdx.x & 63;
  int idx = chunk * 256 + threadIdx.x;
  float s = 0.f;
  for (int i = 0; i < 98; ++i) s += Gpart[(size_t)(b * 98 + i) * 16384 + idx];
  G[(size_t)b * 16384 + idx] = s;
  if (idx < 128) {
    float sm = 0.f;
    for (int i = 0; i < 98; ++i) sm += mpart[(size_t)(b * 98 + i) * 128 + idx];
    mvec[b * 128 + idx] = sm;
  }
}

__global__ __launch_bounds__(256) void k_gstats(
    const float* __restrict__ G, const float* __restrict__ mvec,
    const float* __restrict__ qw, const float* __restrict__ kw,
    float* __restrict__ qk_murs) {
  __shared__ float red1[4], red2[4];
  int bi = blockIdx.x;               // conv*32 + b*8 + g
  int conv = bi >> 5, b = (bi >> 3) & 3, g = bi & 7;
  const float* W = conv ? kw : qw;
  int t = threadIdx.x;
  int c = g * 16 + (t >> 4);
  int i0 = (t & 15) * 8;
  const float* wc = W + (size_t)c * 128;
  const float* Gb = G + (size_t)b * 16384;
  const float* mb = mvec + b * 128;
  float s1 = 0.f, s2 = 0.f;
  for (int i = i0; i < i0 + 8; ++i) {
    float gi = 0.f;
    for (int j = 0; j < 128; ++j) gi += Gb[i * 128 + j] * wc[j];
    s2 += wc[i] * gi;
    s1 += wc[i] * mb[i];
  }
  for (int m = 1; m < 64; m <<= 1) { s1 += __shfl_xor(s1, m); s2 += __shfl_xor(s2, m); }
  if ((t & 63) == 0) { red1[t >> 6] = s1; red2[t >> 6] = s2; }
  __syncthreads();
  if (t == 0) {
    float S1 = red1[0] + red1[1] + red1[2] + red1[3];
    float S2 = red2[0] + red2[1] + red2[2] + red2[3];
    float invN = 1.f / 802816.f;
    float mu = S1 * invN;
    float var = S2 * invN - mu * mu;
    qk_murs[bi * 2] = mu;
    qk_murs[bi * 2 + 1] = rsqrtf(var + EPS_GN);
  }
}

// ---------- pass Q: q enc_block from encF (K=32 MFMA), barrier-free ----------

__global__ __launch_bounds__(256) void k_passQ(
    const _Float16* __restrict__ encF, const float* __restrict__ qk_murs,
    const _Float16* __restrict__ WqB,
    float* __restrict__ q_pool, float* __restrict__ Qpart) {
  int t = threadIdx.x, l = t & 63;
  int wu = rfl(t >> 6);
  int bi = blockIdx.x;
  int b = bi / 784, sub = bi % 784;
  int tile = sub >> 2, st = sub & 3;
  int by = (tile / 14) * 16, bx = (tile % 14) * 16;
  float qmu[2], qrs[2];
#pragma unroll
  for (int cc = 0; cc < 2; ++cc) {
    int g = 2 * wu + cc;
    qmu[cc] = qk_murs[(b * 8 + g) * 2];
    qrs[cc] = qk_murs[(b * 8 + g) * 2 + 1];
  }
  const h16x8* EF = (const h16x8*)encF + ((size_t)(b * 784) + sub) * 1024;
  const h16x8* WQ = (const h16x8*)WqB;
  f32x4 z = {0.f, 0.f, 0.f, 0.f};
  f32x4 accQ[4][2];
  h16x8 sf8[4];
#pragma unroll
  for (int mt = 0; mt < 4; ++mt)
#pragma unroll
    for (int cc = 0; cc < 2; ++cc) accQ[mt][cc] = z;
  for (int kt2 = 0; kt2 < 4; ++kt2) {
    h16x8 a[4];
#pragma unroll
    for (int mt = 0; mt < 4; ++mt) a[mt] = EF[(kt2 * 4 + mt) * 64 + l];
    if (kt2 == wu) {
#pragma unroll
      for (int mt = 0; mt < 4; ++mt) sf8[mt] = a[mt];
    }
    int fi = (kt2 * 8 + 2 * wu) * 64 + l;
    h16x8 bq0 = WQ[fi];
    h16x8 bq1 = WQ[fi + 64];
#pragma unroll
    for (int mt = 0; mt < 4; ++mt) {
      accQ[mt][0] = mfma32(bq0, a[mt], accQ[mt][0]);
      accQ[mt][1] = mfma32(bq1, a[mt], accQ[mt][1]);
    }
  }
  int q = l & 15;
  bool act = (q & 9) == 0;
  float qs1[2] = {0.f, 0.f}, qs2[2] = {0.f, 0.f};
#pragma unroll
  for (int cc = 0; cc < 2; ++cc) {
    int g = 2 * wu + cc;
#pragma unroll
    for (int mt = 0; mt < 4; ++mt) {
      f32x4 pv;
#pragma unroll
      for (int r = 0; r < 4; ++r) {
        float skip = (float)sf8[mt][cc * 4 + r];
        pv[r] = silu_f((accQ[mt][cc][r] - qmu[cc]) * qrs[cc]) + skip;
      }
#pragma unroll
      for (int r = 0; r < 4; ++r) {
        float v = pv[r] + __shfl_xor(pv[r], 1);
        v += __shfl_xor(v, 8);
        pv[r] = v * 0.25f;
      }
      if (act) {
        int p = mt * 16 + q;
        int py = by + (st >> 1) * 8 + (p >> 3);
        int px = bx + (st & 1) * 8 + (p & 7);
        size_t base = ((size_t)(b * NQ) + (py >> 1) * 112 + (px >> 1)) * 128 +
                      g * 16 + 4 * (l >> 4);
        *(f32x4*)(q_pool + base) = pv;
        qs1[cc] += pv[0] + pv[1] + pv[2] + pv[3];
        qs2[cc] += pv[0] * pv[0] + pv[1] * pv[1] + pv[2] * pv[2] + pv[3] * pv[3];
      }
    }
  }
#pragma unroll
  for (int cc = 0; cc < 2; ++cc) {
    float a1 = qs1[cc], a2 = qs2[cc];
    for (int m = 1; m < 64; m <<= 1) {
      a1 += __shfl_xor(a1, m);
      a2 += __shfl_xor(a2, m);
    }
    if (l == 0) {
      Qpart[(size_t)bi * 16 + (2 * wu + cc) * 2] = a1;
      Qpart[(size_t)bi * 16 + (2 * wu + cc) * 2 + 1] = a2;
    }
  }
}

// ---------- pass K: k enc_block from encF (K=32 MFMA), barrier-free ----------

__global__ __launch_bounds__(256) void k_passK(
    const _Float16* __restrict__ encF, const float* __restrict__ qk_murs,
    const _Float16* __restrict__ WkB, float* __restrict__ kpp) {
  int t = threadIdx.x, l = t & 63;
  int wu = rfl(t >> 6);
  int bi = blockIdx.x;
  int b = bi / 784, sub = bi % 784;
  float kmu[2], krs[2];
#pragma unroll
  for (int cc = 0; cc < 2; ++cc) {
    int g = 2 * wu + cc;
    kmu[cc] = qk_murs[(32 + b * 8 + g) * 2];
    krs[cc] = qk_murs[(32 + b * 8 + g) * 2 + 1];
  }
  const h16x8* EF = (const h16x8*)encF + ((size_t)(b * 784) + sub) * 1024;
  const h16x8* WK = (const h16x8*)WkB;
  f32x4 z = {0.f, 0.f, 0.f, 0.f};
  f32x4 accK[4][2];
  h16x8 sf8[4];
#pragma unroll
  for (int mt = 0; mt < 4; ++mt)
#pragma unroll
    for (int cc = 0; cc < 2; ++cc) accK[mt][cc] = z;
  for (int kt2 = 0; kt2 < 4; ++kt2) {
    h16x8 a[4];
#pragma unroll
    for (int mt = 0; mt < 4; ++mt) a[mt] = EF[(kt2 * 4 + mt) * 64 + l];
    if (kt2 == wu) {
#pragma unroll
      for (int mt = 0; mt < 4; ++mt) sf8[mt] = a[mt];
    }
    int fi = (kt2 * 8 + 2 * wu) * 64 + l;
    h16x8 bk0 = WK[fi];
    h16x8 bk1 = WK[fi + 64];
#pragma unroll
    for (int mt = 0; mt < 4; ++mt) {
      accK[mt][0] = mfma32(bk0, a[mt], accK[mt][0]);
      accK[mt][1] = mfma32(bk1, a[mt], accK[mt][1]);
    }
  }
  int q = l & 15;
  float kacc[2][4];
#pragma unroll
  for (int cc = 0; cc < 2; ++cc)
#pragma unroll
    for (int r = 0; r < 4; ++r) kacc[cc][r] = 0.f;
#pragma unroll
  for (int cc = 0; cc < 2; ++cc) {
#pragma unroll
    for (int mt = 0; mt < 4; ++mt) {
#pragma unroll
      for (int r = 0; r < 4; ++r) {
        float skip = (float)sf8[mt][cc * 4 + r];
        kacc[cc][r] += silu_f((accK[mt][cc][r] - kmu[cc]) * krs[cc]) + skip;
      }
    }
  }
#pragma unroll
  for (int cc = 0; cc < 2; ++cc) {
#pragma unroll
    for (int r = 0; r < 4; ++r) {
      float v = kacc[cc][r];
      v += __shfl_xor(v, 1);
      v += __shfl_xor(v, 2);
      v += __shfl_xor(v, 4);
      v += __shfl_xor(v, 8);
      kacc[cc][r] = v;
    }
    if (q == 0) {
      f32x4 kv = {kacc[cc][0], kacc[cc][1], kacc[cc][2], kacc[cc][3]};
      *(f32x4*)(kpp + (size_t)bi * 128 + (2 * wu + cc) * 16 + 4 * (l >> 4)) = kv;
    }
  }
}

__global__ __launch_bounds__(256) void k_kpred(
    const float* __restrict__ kpp, float* __restrict__ k_pool) {
  int idx = blockIdx.x * 256 + threadIdx.x;
  if (idx >= BB * 128 * NKk) return;
  int b = idx / (128 * NKk);
  int rem = idx % (128 * NKk);
  int c = rem / NKk, tile = rem % NKk;
  const float* base = kpp + ((size_t)(b * 196 + tile) * 4) * 128 + c;
  float s = base[0] + base[128] + base[256] + base[384];
  k_pool[idx] = s * (1.f / 256.f);
}

__global__ __launch_bounds__(256) void k_qstatfin(
    const float* __restrict__ Qpart, float* __restrict__ murs2) {
  __shared__ float l1[4], l2[4];
  int b = blockIdx.x >> 3, g = blockIdx.x & 7, t = threadIdx.x;
  float s1 = 0.f, s2 = 0.f;
  for (int i = t; i < 784; i += 256) {
    s1 += Qpart[((size_t)(b * 784) + i) * 16 + g * 2];
    s2 += Qpart[((size_t)(b * 784) + i) * 16 + g * 2 + 1];
  }
  for (int m = 1; m < 64; m <<= 1) { s1 += __shfl_xor(s1, m); s2 += __shfl_xor(s2, m); }
  if ((t & 63) == 0) { l1[t >> 6] = s1; l2[t >> 6] = s2; }
  __syncthreads();
  if (t == 0) {
    float a = l1[0] + l1[1] + l1[2] + l1[3];
    float bq = l2[0] + l2[1] + l2[2] + l2[3];
    float invN = 1.f / (16.f * (float)NQ);
    float mu = a * invN;
    float var = bq * invN - mu * mu;
    murs2[blockIdx.x * 2] = mu;
    murs2[blockIdx.x * 2 + 1] = rsqrtf(var + EPS_GN);
  }
}

// ---------- GN stats (channel-major src[b][c][P]) ----------

__global__ __launch_bounds__(256) void k_gnstats(
    const float* __restrict__ src, float* __restrict__ murs, int P, float eps) {
  __shared__ float l1[4], l2[4];
  int b = blockIdx.x >> 3, g = blockIdx.x & 7, t = threadIdx.x;
  const float* base = src + ((size_t)(b * 128) + g * 16) * P;
  float s1 = 0.f, s2 = 0.f;
  for (int i = t; i < 16 * P; i += 256) {
    float v = base[i];
    s1 += v; s2 += v * v;
  }
  for (int m = 1; m < 64; m <<= 1) { s1 += __shfl_xor(s1, m); s2 += __shfl_xor(s2, m); }
  if ((t & 63) == 0) { l1[t >> 6] = s1; l2[t >> 6] = s2; }
  __syncthreads();
  if (t == 0) {
    float invN = 1.f / (16.f * (float)P);
    float a = l1[0] + l1[1] + l1[2] + l1[3];
    float bq = l2[0] + l2[1] + l2[2] + l2[3];
    float mu = a * invN;
    float var = bq * invN - mu * mu;
    murs[blockIdx.x * 2] = mu;
    murs[blockIdx.x * 2 + 1] = rsqrtf(var + eps);
  }
}

// ---------- kf branch: fused L2-norm + 384->128 conv+proj (MFMA) ----------

__global__ __launch_bounds__(256) void k_kf(
    const float* __restrict__ feat,
    const _Float16* __restrict__ KFB, const _Float16* __restrict__ KFPB,
    float* __restrict__ y_kf, float* __restrict__ skip_kf) {
  __shared__ __align__(16) _Float16 fnF[24 * 4 * 64 * 4];  // 48KB, A-frags
  __shared__ float ssqL[4][64];
  __shared__ float rsqL[64];
  int t = threadIdx.x, l = t & 63, w = t >> 6;
  int b = blockIdx.x >> 2, tile = blockIdx.x & 3;
  int p0 = tile * 49;
  const float* fb = feat + (size_t)b * VD * NKk;
  {
    float s = 0.f;
    if (l < 49) {
#pragma unroll 4
      for (int k = w; k < VD; k += 4) {
        float v = fb[(size_t)k * NKk + p0 + l];
        s += v * v;
      }
    }
    ssqL[w][l] = s;
  }
  __syncthreads();
  if (t < 64) {
    float s = ssqL[0][t] + ssqL[1][t] + ssqL[2][t] + ssqL[3][t];
    rsqL[t] = rsqrtf(fmaxf(s, 1e-24f));
  }
  __syncthreads();
  for (int i = t; i < VD * 64; i += 256) {
    int k = i >> 6, p = i & 63;
    float v = 0.f;
    if (p < 49) v = fb[(size_t)k * NKk + p0 + p] * rsqL[p];
    int kt = k >> 4, kr = k & 15, u = kr >> 2, j = kr & 3, mt = p >> 4;
    fnF[(((kt * 4 + mt) * 64) + (p & 15) + 16 * u) * 4 + j] = (_Float16)v;
  }
  __syncthreads();
  f32x4 z = {0.f, 0.f, 0.f, 0.f};
  f32x4 accY[4][2], accS[4][2];
#pragma unroll
  for (int mt = 0; mt < 4; ++mt)
#pragma unroll
    for (int cc = 0; cc < 2; ++cc) { accY[mt][cc] = z; accS[mt][cc] = z; }
  for (int kt = 0; kt < 24; ++kt) {
    h16x4 a[4];
#pragma unroll
    for (int mt = 0; mt < 4; ++mt)
      a[mt] = *(const h16x4*)&fnF[((kt * 4 + mt) * 64 + l) * 4];
    int fi = (kt * 8 + 2 * w) * 64 + l;
    h16x4 by0 = *(const h16x4*)(KFB + (size_t)fi * 4);
    h16x4 by1 = *(const h16x4*)(KFB + (size_t)(fi + 64) * 4);
    h16x4 bs0 = *(const h16x4*)(KFPB + (size_t)fi * 4);
    h16x4 bs1 = *(const h16x4*)(KFPB + (size_t)(fi + 64) * 4);
#pragma unroll
    for (int mt = 0; mt < 4; ++mt) {
      accY[mt][0] = mfma16(a[mt], by0, accY[mt][0]);
      accY[mt][1] = mfma16(a[mt], by1, accY[mt][1]);
      accS[mt][0] = mfma16(a[mt], bs0, accS[mt][0]);
      accS[mt][1] = mfma16(a[mt], bs1, accS[mt][1]);
    }
  }
#pragma unroll
  for (int cc = 0; cc < 2; ++cc) {
    int co = (2 * w + cc) * 16 + (l & 15);
#pragma unroll
    for (int mt = 0; mt < 4; ++mt)
#pragma unroll
      for (int r = 0; r < 4; ++r) {
        int pix = mt * 16 + 4 * (l >> 4) + r;
        if (pix < 49) {
          size_t off = ((size_t)(b * 128) + co) * NKk + p0 + pix;
          y_kf[off] = accY[mt][cc][r];
          skip_kf[off] = accS[mt][cc][r];
        }
      }
  }
}

// ---------- merged SFT + RMSNorm + k-proj (MFMA) ----------

__global__ __launch_bounds__(256) void k_ksft(
    const float* __restrict__ y_kf, const float* __restrict__ skip_kf,
    const float* __restrict__ kf_murs, const float* __restrict__ kgn_murs,
    const _Float16* __restrict__ GB, const _Float16* __restrict__ BBf,
    const _Float16* __restrict__ KPB,
    const float* __restrict__ k_pool, const float* __restrict__ k_proj_b,
    float* __restrict__ kpb) {
  __shared__ __align__(16) _Float16 kfF[8 * 4 * 64 * 4];  // 16KB A-frags
  __shared__ float msL[4][64];
  __shared__ float sMu[8], sRs[8], sGmu[8], sGrs[8];
  int t = threadIdx.x, l = t & 63, w = t >> 6;
  int b = blockIdx.x >> 2, tile = blockIdx.x & 3;
  int p0 = tile * 49;
  if (t < 8) {
    sMu[t] = kf_murs[(b * 8 + t) * 2];
    sRs[t] = kf_murs[(b * 8 + t) * 2 + 1];
    sGmu[t] = kgn_murs[(b * 8 + t) * 2];
    sGrs[t] = kgn_murs[(b * 8 + t) * 2 + 1];
  }
  __syncthreads();
  for (int i = t; i < 128 * 64; i += 256) {
    int c = i >> 6, p = i & 63;
    float v = 0.f;
    if (p < 49) {
      size_t off = ((size_t)(b * 128) + c) * NKk + p0 + p;
      int g = c >> 4;
      v = silu_f((y_kf[off] - sMu[g]) * sRs[g]) + skip_kf[off];
    }
    int kt = c >> 4, kr = c & 15, u = kr >> 2, j = kr & 3, mt = p >> 4;
    kfF[(((kt * 4 + mt) * 64) + (p & 15) + 16 * u) * 4 + j] = (_Float16)v;
  }
  __syncthreads();
  f32x4 z = {0.f, 0.f, 0.f, 0.f};
  f32x4 accG[4][2], accB[4][2];
#pragma unroll
  for (int mt = 0; mt < 4; ++mt)
#pragma unroll
    for (int cc = 0; cc < 2; ++cc) { accG[mt][cc] = z; accB[mt][cc] = z; }
  for (int kt = 0; kt < 8; ++kt) {
    h16x4 a[4];
#pragma unroll
    for (int mt = 0; mt < 4; ++mt)
      a[mt] = *(const h16x4*)&kfF[((kt * 4 + mt) * 64 + l) * 4];
    int fi = (kt * 8 + 2 * w) * 64 + l;
    h16x4 bg0 = *(const h16x4*)(GB + (size_t)fi * 4);
    h16x4 bg1 = *(const h16x4*)(GB + (size_t)(fi + 64) * 4);
    h16x4 bb0 = *(const h16x4*)(BBf + (size_t)fi * 4);
    h16x4 bb1 = *(const h16x4*)(BBf + (size_t)(fi + 64) * 4);
#pragma unroll
    for (int mt = 0; mt < 4; ++mt) {
      accG[mt][0] = mfma16(a[mt], bg0, accG[mt][0]);
      accG[mt][1] = mfma16(a[mt], bg1, accG[mt][1]);
      accB[mt][0] = mfma16(a[mt], bb0, accB[mt][0]);
      accB[mt][1] = mfma16(a[mt], bb1, accB[mt][1]);
    }
  }
  float kfin[4][2][4];
#pragma unroll
  for (int cc = 0; cc < 2; ++cc) {
    int g = 2 * w + cc;
    int co = g * 16 + (l & 15);
    float gmu = sGmu[g], grs = sGrs[g];
#pragma unroll
    for (int mt = 0; mt < 4; ++mt)
#pragma unroll
      for (int r = 0; r < 4; ++r) {
        int pix = mt * 16 + 4 * (l >> 4) + r;
        float v = 0.f;
        if (pix < 49) {
          float kn = (k_pool[((size_t)(b * 128) + co) * NKk + p0 + pix] - gmu) * grs;
          v = fmaf(accG[mt][cc][r], kn, accB[mt][cc][r]);
        }
        kfin[mt][cc][r] = v;
      }
  }
#pragma unroll
  for (int mt = 0; mt < 4; ++mt)
#pragma unroll
    for (int r = 0; r < 4; ++r) {
      float s2 = kfin[mt][0][r] * kfin[mt][0][r] + kfin[mt][1][r] * kfin[mt][1][r];
      for (int m = 1; m < 16; m <<= 1) s2 += __shfl_xor(s2, m);
      if ((l & 15) == 0) msL[w][mt * 16 + 4 * (l >> 4) + r] = s2;
    }
  __syncthreads();
#pragma unroll
  for (int cc = 0; cc < 2; ++cc) {
    int ktn = 2 * w + cc;
    int u = (l & 15) >> 2, j = (l & 15) & 3;
#pragma unroll
    for (int mt = 0; mt < 4; ++mt)
#pragma unroll
      for (int r = 0; r < 4; ++r) {
        int lane = (4 * (l >> 4) + r) + 16 * u;
        kfF[((ktn * 4 + mt) * 64 + lane) * 4 + j] = (_Float16)kfin[mt][cc][r];
      }
  }
  __syncthreads();
  f32x4 accP[4][2];
#pragma unroll
  for (int mt = 0; mt < 4; ++mt)
#pragma unroll
    for (int cc = 0; cc < 2; ++cc) accP[mt][cc] = z;
  for (int kt = 0; kt < 8; ++kt) {
    h16x4 a[4];
#pragma unroll
    for (int mt = 0; mt < 4; ++mt)
      a[mt] = *(const h16x4*)&kfF[((kt * 4 + mt) * 64 + l) * 4];
    int fi = (kt * 8 + 2 * w) * 64 + l;
    h16x4 b0 = *(const h16x4*)(KPB + (size_t)fi * 4);
    h16x4 b1 = *(const h16x4*)(KPB + (size_t)(fi + 64) * 4);
#pragma unroll
    for (int mt = 0; mt < 4; ++mt) {
      accP[mt][0] = mfma16(a[mt], b0, accP[mt][0]);
      accP[mt][1] = mfma16(a[mt], b1, accP[mt][1]);
    }
  }
#pragma unroll
  for (int mt = 0; mt < 4; ++mt)
#pragma unroll
    for (int r = 0; r < 4; ++r) {
      int pix = mt * 16 + 4 * (l >> 4) + r;
      if (pix >= 49) continue;
      float ms = msL[0][pix] + msL[1][pix] + msL[2][pix] + msL[3][pix];
      float rr = rsqrtf(ms * (1.f / 128.f) + EPS_RMS);
#pragma unroll
      for (int cc = 0; cc < 2; ++cc) {
        int co = (2 * w + cc) * 16 + (l & 15);
        kpb[((size_t)(b * 196) + p0 + pix) * 128 + co] =
            accP[mt][cc][r] * rr + k_proj_b[co];
      }
    }
}

// ---------- fused 3x3 conv + RMSNorm + q-proj (K=32 MFMA conv, LDS input,
// SW-pipelined weight stream) ----------

__global__ __launch_bounds__(256) void k_conv3f(
    const float* __restrict__ q_pool, const float* __restrict__ murs2,
    const _Float16* __restrict__ W3B, const _Float16* __restrict__ QPB,
    const float* __restrict__ bias, float* __restrict__ qp) {
  __shared__ __align__(16) _Float16 tileL[100 * 136];  // 27.2 KB
  __shared__ float sMu[8], sRs[8];
  int t = threadIdx.x, l = t & 63, w = t >> 6;
  int b = blockIdx.x / 196, reg = blockIdx.x % 196;
  int y0 = (reg / 14) * 8, x0 = (reg % 14) * 8;
  if (t < 8) { sMu[t] = murs2[(b * 8 + t) * 2]; sRs[t] = murs2[(b * 8 + t) * 2 + 1]; }
  __syncthreads();
  for (int i = t; i < 3200; i += 256) {
    int rowp = i >> 5, c4 = i & 31;
    int gy = y0 - 1 + rowp / 10, gx = x0 - 1 + rowp % 10;
    h16x4 hv = {(_Float16)0.f, (_Float16)0.f, (_Float16)0.f, (_Float16)0.f};
    if (gy >= 0 && gy < 112 && gx >= 0 && gx < 112) {
      f32x4 v = *(const f32x4*)(q_pool + ((size_t)(b * NQ) + gy * 112 + gx) * 128 +
                                c4 * 4);
      int g = c4 >> 2;
      float mu = sMu[g], rs = sRs[g];
#pragma unroll
      for (int j = 0; j < 4; ++j) hv[j] = (_Float16)((v[j] - mu) * rs);
    }
    *(h16x4*)&tileL[rowp * 136 + c4 * 4] = hv;
  }
  __syncthreads();
  f32x4 z = {0.f, 0.f, 0.f, 0.f};
  f32x4 acc[8];
#pragma unroll
  for (int ct = 0; ct < 8; ++ct) acc[ct] = z;
  int lm = l & 15;
  int mrow = lm >> 3, mcol = lm & 7;
  const h16x8* W3l = (const h16x8*)W3B + l;
  h16x8 wbuf[3][8];
#pragma unroll
  for (int ct = 0; ct < 8; ++ct) wbuf[0][ct] = W3l[ct * 64];
#pragma unroll
  for (int ct = 0; ct < 8; ++ct) wbuf[1][ct] = W3l[(8 + ct) * 64];
#pragma unroll
  for (int s = 0; s < 36; ++s) {
    if (s + 2 < 36) {
#pragma unroll
      for (int ct = 0; ct < 8; ++ct)
        wbuf[(s + 2) % 3][ct] = W3l[((s + 2) * 8 + ct) * 64];
    }
    int tap = s >> 2, kt2 = s & 3;
    int prow = (2 * w + mrow + tap / 3) * 10 + (mcol + tap % 3);
    h16x8 bf = *(const h16x8*)&tileL[prow * 136 + kt2 * 32 + 8 * (l >> 4)];
#pragma unroll
    for (int ct = 0; ct < 8; ++ct)
      acc[ct] = mfma32(wbuf[s % 3][ct], bf, acc[ct]);
  }
  float sq = 0.f;
#pragma unroll
  for (int ct = 0; ct < 8; ++ct)
#pragma unroll
    for (int r = 0; r < 4; ++r) sq += acc[ct][r] * acc[ct][r];
  sq += __shfl_xor(sq, 16);
  sq += __shfl_xor(sq, 32);
  float rr = rsqrtf(sq * (1.f / 128.f) + EPS_RMS);
  int chof = 4 * (l >> 4);
  h16x4 pb[8];
#pragma unroll
  for (int kt = 0; kt < 8; ++kt)
#pragma unroll
    for (int j = 0; j < 4; ++j) pb[kt][j] = (_Float16)acc[kt][j];
  f32x4 accP[8];
#pragma unroll
  for (int ct = 0; ct < 8; ++ct) accP[ct] = z;
  const h16x4* QP = (const h16x4*)QPB + l;
#pragma unroll
  for (int kt = 0; kt < 8; ++kt) {
#pragma unroll
    for (int ct = 0; ct < 8; ++ct)
      accP[ct] = mfma16(QP[(kt * 8 + ct) * 64], pb[kt], accP[ct]);
  }
  int py = y0 + 2 * w + mrow, px = x0 + mcol;
  size_t pbase = ((size_t)(b * NQ) + py * 112 + px) * 128;
#pragma unroll
  for (int ct = 0; ct < 8; ++ct) {
    f32x4 o;
#pragma unroll
    for (int r = 0; r < 4; ++r)
      o[r] = accP[ct][r] * rr + bias[ct * 16 + chof + r];
    *(f32x4*)(qp + pbase + ct * 16 + chof) = o;
  }
}

// ---------- attention: QK^T (K=32) + softmax + head-mean -> packed fp16 P ----------

__global__ __launch_bounds__(256) void k_attn1m(
    const float* __restrict__ qp, const float* __restrict__ kpb,
    _Float16* __restrict__ Ph) {
  __shared__ float sP[4][16][212];
  int t = threadIdx.x, l = t & 63, h = t >> 6;
  int b = blockIdx.x / 784, qt = blockIdx.x % 784;
  int q0 = qt * 16;
  constexpr float SC = 0.17677669529663687f;  // 1/sqrt(32)
  h16x8 aq;
  {
    const float* qrow = qp + ((size_t)(b * NQ) + q0 + (l & 15)) * 128 +
                        h * 32 + 8 * (l >> 4);
    f32x4 v0 = *(const f32x4*)qrow;
    f32x4 v1 = *(const f32x4*)(qrow + 4);
#pragma unroll
    for (int j = 0; j < 4; ++j) { aq[j] = (_Float16)v0[j]; aq[j + 4] = (_Float16)v1[j]; }
  }
  f32x4 z = {0.f, 0.f, 0.f, 0.f};
  f32x4 acc[13];
#pragma unroll
  for (int nt = 0; nt < 13; ++nt) acc[nt] = z;
#pragma unroll
  for (int nt = 0; nt < 13; ++nt) {
    int key = nt * 16 + (l & 15);
    bool ok = key < 196;
    h16x8 bf = {(_Float16)0.f, (_Float16)0.f, (_Float16)0.f, (_Float16)0.f,
                (_Float16)0.f, (_Float16)0.f, (_Float16)0.f, (_Float16)0.f};
    if (ok) {
      const float* krow = kpb + ((size_t)(b * 196) + key) * 128 +
                          h * 32 + 8 * (l >> 4);
      f32x4 v0 = *(const f32x4*)krow;
      f32x4 v1 = *(const f32x4*)(krow + 4);
#pragma unroll
      for (int j = 0; j < 4; ++j) { bf[j] = (_Float16)v0[j]; bf[j + 4] = (_Float16)v1[j]; }
    }
    acc[nt] = mfma32(aq, bf, acc[nt]);
  }
#pragma unroll
  for (int r = 0; r < 4; ++r) {
    float mx = -3e38f;
#pragma unroll
    for (int nt = 0; nt < 13; ++nt) {
      bool ok = nt * 16 + (l & 15) < 196;
      float v = ok ? acc[nt][r] * SC : -3e38f;
      acc[nt][r] = v;
      mx = fmaxf(mx, v);
    }
    for (int m = 1; m < 16; m <<= 1) mx = fmaxf(mx, __shfl_xor(mx, m));
    float sum = 0.f;
#pragma unroll
    for (int nt = 0; nt < 13; ++nt) {
      bool ok = nt * 16 + (l & 15) < 196;
      float e = ok ? __expf(acc[nt][r] - mx) : 0.f;
      acc[nt][r] = e;
      sum += e;
    }
    for (int m = 1; m < 16; m <<= 1) sum += __shfl_xor(sum, m);
    float inv = 1.f / sum;
#pragma unroll
    for (int nt = 0; nt < 13; ++nt)
      sP[h][4 * (l >> 4) + r][nt * 16 + (l & 15)] = acc[nt][r] * inv;
  }
  __syncthreads();
  _Float16* pb = Ph + (size_t)(b * 784 + qt) * 13 * 256;
  for (int i = t; i < 832; i += 256) {
    int kt = i >> 6, ll = i & 63;
    int q = ll & 15, kb = kt * 16 + 4 * (ll >> 4);
    h16x4 v;
#pragma unroll
    for (int j = 0; j < 4; ++j) {
      int k = kb + j;
      float s = 0.25f * (sP[0][q][k] + sP[1][q][k] + sP[2][q][k] + sP[3][q][k]);
      v[j] = (_Float16)s;
    }
    *(h16x4*)(pb + (size_t)i * 4) = v;
  }
}

// ---------- attention PV: pure fragment streaming, no LDS ----------

__global__ __launch_bounds__(256) void k_attn2m(
    const _Float16* __restrict__ Ph, const _Float16* __restrict__ featB,
    float* __restrict__ out) {
  int t = threadIdx.x, l = t & 63, w = t >> 6;
  int b = blockIdx.x / 196, qt = blockIdx.x % 196;
  int q16 = qt * 4 + w;
  f32x4 z = {0.f, 0.f, 0.f, 0.f};
  f32x4 acc[24];
#pragma unroll
  for (int dt = 0; dt < 24; ++dt) acc[dt] = z;
  const h16x4* PB = (const h16x4*)Ph + ((size_t)(b * 784 + q16) * 13) * 64 + l;
  const h16x4* FB = (const h16x4*)featB + (size_t)b * 13 * 24 * 64 + l;
  for (int kt = 0; kt < 13; ++kt) {
    h16x4 bp = PB[kt * 64];
    const h16x4* fb = FB + kt * 24 * 64;
#pragma unroll
    for (int dt = 0; dt < 24; ++dt)
      acc[dt] = mfma16(fb[(size_t)dt * 64], bp, acc[dt]);
  }
  int qg = q16 * 16 + (l & 15);
#pragma unroll
  for (int dt = 0; dt < 24; ++dt)
#pragma unroll
    for (int r = 0; r < 4; ++r) {
      int d = dt * 16 + 4 * (l >> 4) + r;
      out[((size_t)(b * 384) + d) * NQ + qg] = acc[dt][r];
    }
}

}  // namespace

extern "C" void kernel_launch(void* const* d_in, const int* in_sizes, int n_in,
                              void* d_out, int out_size, void* d_ws,
                              size_t ws_size, hipStream_t stream) {
  (void)in_sizes; (void)n_in; (void)out_size; (void)ws_size;
  const float* image        = (const float*)d_in[0];
  const float* features     = (const float*)d_in[1];
  const float* rope_f       = (const float*)d_in[2];
  const float* img_conv_w   = (const float*)d_in[3];
  const float* img_proj_w   = (const float*)d_in[4];
  const float* qenc_w       = (const float*)d_in[5];
  const float* kenc_w       = (const float*)d_in[6];
  const float* kfeat_conv_w = (const float*)d_in[7];
  const float* kfeat_proj_w = (const float*)d_in[8];
  const float* sft_gamma_w  = (const float*)d_in[9];
  const float* sft_beta_w   = (const float*)d_in[10];
  const float* block_conv_w = (const float*)d_in[11];
  const float* rms_q_w      = (const float*)d_in[12];
  const float* rms_k_w      = (const float*)d_in[13];
  const float* q_proj_w     = (const float*)d_in[14];
  const float* q_proj_b     = (const float*)d_in[15];
  const float* k_proj_w     = (const float*)d_in[16];
  const float* k_proj_b     = (const float*)d_in[17];
  float* out = (float*)d_out;
  float* ws = (float*)d_ws;

  size_t off = 0;
  auto alloc = [&](size_t n) {
    size_t r = off;
    off += (n + 63) & ~(size_t)63;
    return r;
  };
  _Float16* WqB  = (_Float16*)(ws + alloc(8192));
  _Float16* WkB  = (_Float16*)(ws + alloc(8192));
  _Float16* QPB  = (_Float16*)(ws + alloc(8192));
  _Float16* W3B  = (_Float16*)(ws + alloc(73728));
  _Float16* KFB  = (_Float16*)(ws + alloc(24576));
  _Float16* KFPB = (_Float16*)(ws + alloc(24576));
  _Float16* GB   = (_Float16*)(ws + alloc(8192));
  _Float16* BBf  = (_Float16*)(ws + alloc(8192));
  _Float16* KPB  = (_Float16*)(ws + alloc(8192));
  float* cosT     = ws + alloc(14336);
  float* sinT     = ws + alloc(14336);
  _Float16* featB = (_Float16*)(ws + alloc(159744));
  float* imgpart  = ws + alloc(2304);
  float* img_murs = ws + alloc(64);
  float* qk_murs  = ws + alloc(128);
  float* murs2    = ws + alloc(64);
  float* kgn_murs = ws + alloc(64);
  float* kf_murs  = ws + alloc(64);
  float* G        = ws + alloc(65536);
  float* mvec     = ws + alloc(512);
  float* mpart    = ws + alloc(392 * 128);
  float* Qpart    = ws + alloc((size_t)BB * 784 * 16);
  float* kpp      = ws + alloc((size_t)BB * 784 * 128);
  float* y_kf     = ws + alloc(100352);
  float* skip_kf  = ws + alloc(100352);
  float* k_pool   = ws + alloc(100352);
  float* kpb      = ws + alloc(100352);
  // RA (25.7MB): Gpart -> q_pool
  float* RA = ws + alloc((size_t)BB * NQ * 128);
  // ENC (51.4MB): encF -> (qp, Ph)
  float* ENCp = ws + alloc((size_t)BB * 784 * 8192 / 2);
  float* Gpart  = RA;
  float* q_pool = RA;
  _Float16* encF = (_Float16*)ENCp;
  float* qp      = ENCp;                                      // after encF dead
  _Float16* Ph   = (_Float16*)(ENCp + (size_t)BB * NQ * 128); // after qp

  k_prep<<<2648, 256, 0, stream>>>(qenc_w, kenc_w, q_proj_w, rms_q_w,
                                   block_conv_w, kfeat_conv_w, kfeat_proj_w,
                                   sft_gamma_w, sft_beta_w, k_proj_w, rms_k_w,
                                   rope_f, features,
                                   WqB, WkB, QPB, W3B, KFB, KFPB, GB, BBf, KPB,
                                   cosT, sinT, featB);

  k_imgstat1<<<BB * 64, 256, 0, stream>>>(image, imgpart);
  k_imgstat2<<<BB, 128, 0, stream>>>(imgpart, img_conv_w, img_murs);

  k_kf<<<BB * 4, 256, 0, stream>>>(features, KFB, KFPB, y_kf, skip_kf);
  k_gnstats<<<32, 256, 0, stream>>>(y_kf, kf_murs, NKk, EPS_GN);

  k_gram<<<BB * 98, 256, 0, stream>>>(image, cosT, sinT, img_conv_w,
                                      img_proj_w, img_murs, encF, Gpart, mpart);
  k_gred<<<BB * 64, 256, 0, stream>>>(Gpart, mpart, G, mvec);
  k_gstats<<<64, 256, 0, stream>>>(G, mvec, qenc_w, kenc_w, qk_murs);

  // q/k enc_blocks split into two barrier-free kernels (higher occupancy)
  k_passK<<<BB * 784, 256, 0, stream>>>(encF, qk_murs, WkB, kpp);
  k_passQ<<<BB * 784, 256, 0, stream>>>(encF, qk_murs, WqB, q_pool, Qpart);
  k_qstatfin<<<32, 256, 0, stream>>>(Qpart, murs2);
  k_kpred<<<392, 256, 0, stream>>>(kpp, k_pool);
  k_gnstats<<<32, 256, 0, stream>>>(k_pool, kgn_murs, NKk, EPS_GN);

  k_ksft<<<BB * 4, 256, 0, stream>>>(y_kf, skip_kf, kf_murs, kgn_murs,
                                     GB, BBf, KPB, k_pool, k_proj_b, kpb);

  k_conv3f<<<BB * 196, 256, 0, stream>>>(q_pool, murs2, W3B, QPB, q_proj_b, qp);

  k_attn1m<<<BB * 784, 256, 0, stream>>>(qp, kpb, Ph);
  k_attn2m<<<BB * 196, 256, 0, stream>>>(Ph, featB, out);
}

// Round 17
// 360.264 us; speedup vs baseline: 1.3165x; 1.0255x over previous
//
#include <hip/hip_runtime.h>
#include <cstdint>
#include <cstddef>

#define DEV __device__ __forceinline__

namespace {

constexpr int BB   = 4;
constexpr int HWP  = 50176;   // 224*224
constexpr int NQ   = 12544;   // 112*112
constexpr int NKk  = 196;     // 14*14
constexpr int VD   = 384;
constexpr float EPS_GN  = 1e-5f;
constexpr float EPS_RMS = 1.1920929e-7f;

typedef __attribute__((ext_vector_type(4))) float f32x4;
typedef __attribute__((ext_vector_type(4))) _Float16 h16x4;
typedef __attribute__((ext_vector_type(8))) _Float16 h16x8;

// silu via HW rcp (<=1 ulp) instead of IEEE division
DEV float silu_f(float z) {
  return z * __builtin_amdgcn_rcpf(1.f + __expf(-z));
}
DEV int rfl(int v) { return __builtin_amdgcn_readfirstlane(v); }

DEV f32x4 mfma16(h16x4 a, h16x4 b, f32x4 c) {
  return __builtin_amdgcn_mfma_f32_16x16x16f16(a, b, c, 0, 0, 0);
}
DEV f32x4 mfma32(h16x8 a, h16x8 b, f32x4 c) {
  return __builtin_amdgcn_mfma_f32_16x16x32_f16(a, b, c, 0, 0, 0);
}

// ---------- fused weight prep (one launch) ----------
DEV void pack16_one(int id, const float* W, const float* rowscale,
                    _Float16* dst) {
  int j = id & 3, l = (id >> 2) & 63, tile = id >> 8;
  int ct = tile & 7, kt = tile >> 3;
  int ci = kt * 16 + 4 * (l >> 4) + j;
  int co = ct * 16 + (l & 15);
  float v = W[(size_t)co * 128 + ci];
  if (rowscale) v *= rowscale[ci];
  dst[id] = (_Float16)v;
}
// K=32 pack for 128x128 weight, channel map matching paired K=16 enc frags
DEV void pack32_one(int id, const float* W, _Float16* dst) {
  int j = id & 7, l = (id >> 3) & 63, ct = (id >> 9) & 7, kt2 = id >> 12;
  int u = l >> 4;
  int ci = kt2 * 32 + ((j < 4) ? (4 * u + j) : (16 + 4 * u + (j - 4)));
  int co = ct * 16 + (l & 15);
  dst[id] = (_Float16)W[(size_t)co * 128 + ci];
}
// pack 128x384 weight into frag order, K=384 (24 kt)
DEV void pack384_one(int id, const float* W, _Float16* dst) {
  int j = id & 3, l = (id >> 2) & 63, rest = id >> 8;
  int ct = rest & 7, kt = rest >> 3;          // kt 0..23
  int ci = kt * 16 + 4 * (l >> 4) + j;
  int co = ct * 16 + (l & 15);
  dst[id] = (_Float16)W[(size_t)co * 384 + ci];
}

__global__ __launch_bounds__(256) void k_prep(
    const float* __restrict__ qenc_w, const float* __restrict__ kenc_w,
    const float* __restrict__ q_proj_w, const float* __restrict__ rms_q_w,
    const float* __restrict__ block_conv_w,
    const float* __restrict__ kfeat_conv_w, const float* __restrict__ kfeat_proj_w,
    const float* __restrict__ sft_gamma_w, const float* __restrict__ sft_beta_w,
    const float* __restrict__ k_proj_w, const float* __restrict__ rms_k_w,
    const float* __restrict__ ropef, const float* __restrict__ feat,
    _Float16* __restrict__ WqB, _Float16* __restrict__ WkB,
    _Float16* __restrict__ QPB, _Float16* __restrict__ W3B,
    _Float16* __restrict__ KFB, _Float16* __restrict__ KFPB,
    _Float16* __restrict__ GB, _Float16* __restrict__ BBf,
    _Float16* __restrict__ KPB,
    float* __restrict__ cosT, float* __restrict__ sinT,
    _Float16* __restrict__ featB) {
  int idx = blockIdx.x * 256 + threadIdx.x;
  if (idx < 16384) {
    pack32_one(idx, qenc_w, WqB);                 // K=32 pack
  } else if (idx < 32768) {
    pack32_one(idx - 16384, kenc_w, WkB);         // K=32 pack
  } else if (idx < 49152) {
    pack16_one(idx - 32768, q_proj_w, rms_q_w, QPB);
  } else if (idx < 196608) {
    // K=32 frag order for conv: frag id = (tap*4+kt2)*8+ct, lane l, elem j
    int id = idx - 49152;
    int j = id & 7, l = (id >> 3) & 63, ct = (id >> 9) & 7;
    int kt2 = (id >> 12) & 3, tap = id >> 14;
    int ci = kt2 * 32 + 8 * (l >> 4) + j;
    int co = ct * 16 + (l & 15);
    W3B[id] = (_Float16)block_conv_w[((size_t)co * 128 + ci) * 9 + tap];
  } else if (idx < 245760) {
    pack384_one(idx - 196608, kfeat_conv_w, KFB);
  } else if (idx < 294912) {
    pack384_one(idx - 245760, kfeat_proj_w, KFPB);
  } else if (idx < 311296) {
    pack16_one(idx - 294912, sft_gamma_w, nullptr, GB);
  } else if (idx < 327680) {
    pack16_one(idx - 311296, sft_beta_w, nullptr, BBf);
  } else if (idx < 344064) {
    pack16_one(idx - 327680, k_proj_w, rms_k_w, KPB);
  } else if (idx < 358400) {
    int id = idx - 344064;            // pos*64 + d
    int pos = id >> 6, d = id & 63;
    float a = (pos + 0.5f) * (1.f / 224.f) * ropef[d];
    float s, c;
    __sincosf(a, &s, &c);
    cosT[id] = c;
    sinT[id] = s;
  } else if (idx < 677888) {
    int id = idx - 358400;            // (((b*13+kt)*24+dt)*64+l)*4+j
    int j = id & 3, l = (id >> 2) & 63;
    int rest = id >> 8;
    int dt = rest % 24;
    int kt = (rest / 24) % 13;
    int b = rest / (24 * 13);
    int key = kt * 16 + 4 * (l >> 4) + j;
    int d = dt * 16 + (l & 15);
    float v = (key < 196) ? feat[((size_t)(b * 384) + d) * 196 + key] : 0.f;
    featB[id] = (_Float16)v;
  }
}

// ---------- image GN stats via 3x3 Gram ----------

__global__ __launch_bounds__(256) void k_imgstat1(
    const float* __restrict__ img, float* __restrict__ part) {
  __shared__ float lds[4][9];
  int b = blockIdx.x >> 6, blk = blockIdx.x & 63;
  int t = threadIdx.x;
  float a[9];
#pragma unroll
  for (int j = 0; j < 9; ++j) a[j] = 0.f;
  const float* ib = img + (size_t)b * 3 * HWP;
  for (int pix = blk * 784 + t; pix < blk * 784 + 784; pix += 256) {
    float x0 = ib[pix], x1 = ib[HWP + pix], x2 = ib[2 * HWP + pix];
    a[0] += x0; a[1] += x1; a[2] += x2;
    a[3] += x0 * x0; a[4] += x0 * x1; a[5] += x0 * x2;
    a[6] += x1 * x1; a[7] += x1 * x2; a[8] += x2 * x2;
  }
#pragma unroll
  for (int j = 0; j < 9; ++j)
    for (int m = 1; m < 64; m <<= 1) a[j] += __shfl_xor(a[j], m);
  if ((t & 63) == 0)
    for (int j = 0; j < 9; ++j) lds[t >> 6][j] = a[j];
  __syncthreads();
  if (t < 9)
    part[(size_t)blockIdx.x * 9 + t] =
        lds[0][t] + lds[1][t] + lds[2][t] + lds[3][t];
}

__global__ __launch_bounds__(128) void k_imgstat2(
    const float* __restrict__ part, const float* __restrict__ wimg,
    float* __restrict__ img_murs) {
  __shared__ float MG[9];
  int b = blockIdx.x, t = threadIdx.x;
  if (t < 9) {
    float s = 0.f;
    for (int i = 0; i < 64; ++i) s += part[(size_t)(b * 64 + i) * 9 + t];
    MG[t] = s;
  }
  __syncthreads();
  int c = t;
  float w0 = wimg[c * 3], w1 = wimg[c * 3 + 1], w2 = wimg[c * 3 + 2];
  float s1 = w0 * MG[0] + w1 * MG[1] + w2 * MG[2];
  float s2 = w0 * w0 * MG[3] + w1 * w1 * MG[6] + w2 * w2 * MG[8] +
             2.f * (w0 * w1 * MG[4] + w0 * w2 * MG[5] + w1 * w2 * MG[7]);
  for (int m = 1; m < 16; m <<= 1) {
    s1 += __shfl_xor(s1, m);
    s2 += __shfl_xor(s2, m);
  }
  if ((c & 15) == 0) {
    int g = c >> 4;
    float invN = 1.f / (16.f * HWP);
    float mu = s1 * invN;
    float var = s2 * invN - mu * mu;
    img_murs[b * 16 + g] = mu;
    img_murs[b * 16 + 8 + g] = rsqrtf(var + EPS_GN);
  }
}

// ---------- enc producer + Gram + enc_frag materialization ----------
// encF written as paired K=32 fragments (h16x8).
// fragC (channel-major for Gram) uses 65-lane padded rows + XOR lane swizzle
// phi(x) = x ^ (4*(x>>4)) on BOTH write and read to kill bank conflicts.

__global__ __launch_bounds__(256) void k_gram(
    const float* __restrict__ img, const float* __restrict__ cosT,
    const float* __restrict__ sinT,
    const float* __restrict__ wimg, const float* __restrict__ wimgp,
    const float* __restrict__ img_murs,
    _Float16* __restrict__ encF,
    float* __restrict__ Gpart, float* __restrict__ mpart) {
  __shared__ __align__(16) _Float16 fragP[2080 * 4];   // [kt*4+mt][lane(65)][j]
  __shared__ __align__(16) _Float16 fragC[32 * 65 * 4];// [frag][lane(65,phi)][j]
  __shared__ float sWc[384], sWp[384], sMu[8], sRs[8];
  int t = threadIdx.x, l = t & 63, w = t >> 6;
  int b = blockIdx.x / 98, blk = blockIdx.x % 98;
  for (int i = t; i < 384; i += 256) { sWc[i] = wimg[i]; sWp[i] = wimgp[i]; }
  if (t < 8) { sMu[t] = img_murs[b * 16 + t]; sRs[t] = img_murs[b * 16 + 8 + t]; }
  f32x4 acc[2][8];
  f32x4 macc[2];
  f32x4 z = {0.f, 0.f, 0.f, 0.f};
#pragma unroll
  for (int e = 0; e < 2; ++e) {
    macc[e] = z;
#pragma unroll
    for (int nt = 0; nt < 8; ++nt) acc[e][nt] = z;
  }
  h16x8 hone8 = {(_Float16)1.f, (_Float16)1.f, (_Float16)1.f, (_Float16)1.f,
                 (_Float16)1.f, (_Float16)1.f, (_Float16)1.f, (_Float16)1.f};
  int mt = l >> 4;
  int qq = (l & 15) >> 2;           // pixel quarter within 16
  int jC = (l & 15) & 3;
  int phiL = l ^ (4 * (l >> 4));    // swizzled read lane
  for (int s = 0; s < 8; ++s) {
    int sub = blk * 8 + s;
    int tile = sub >> 2, st = sub & 3;
    int py = (tile / 14) * 16 + ((st >> 1) << 3) + (l >> 3);
    int px = (tile % 14) * 16 + ((st & 1) << 3) + (l & 7);
    __syncthreads();
    {
      const float* ip = img + (size_t)b * 3 * HWP + py * 224 + px;
      float x0 = ip[0], x1 = ip[HWP], x2 = ip[2 * HWP];
      const float* cy = cosT + py * 64 + w * 16;
      const float* sy = sinT + py * 64 + w * 16;
      const float* cx = cosT + px * 64 + w * 16;
      const float* sx = sinT + px * 64 + w * 16;
#pragma unroll
      for (int jj = 0; jj < 4; ++jj) {
        f32x4 cyv = *(const f32x4*)(cy + jj * 4);
        f32x4 syv = *(const f32x4*)(sy + jj * 4);
        f32x4 cxv = *(const f32x4*)(cx + jj * 4);
        f32x4 sxv = *(const f32x4*)(sx + jj * 4);
        h16x4 lo4, hi4;
#pragma unroll
        for (int u = 0; u < 4; ++u) {
          int d = w * 16 + jj * 4 + u;
          int c2 = d + 64;
          float y1 = sWc[d * 3] * x0 + sWc[d * 3 + 1] * x1 + sWc[d * 3 + 2] * x2;
          float s1 = sWp[d * 3] * x0 + sWp[d * 3 + 1] * x1 + sWp[d * 3 + 2] * x2;
          float y2 = sWc[c2 * 3] * x0 + sWc[c2 * 3 + 1] * x1 + sWc[c2 * 3 + 2] * x2;
          float s2 = sWp[c2 * 3] * x0 + sWp[c2 * 3 + 1] * x1 + sWp[c2 * 3 + 2] * x2;
          int g1 = d >> 4, g2 = g1 + 4;
          float t1 = silu_f((y1 - sMu[g1]) * sRs[g1]) + s1;
          float t2 = silu_f((y2 - sMu[g2]) * sRs[g2]) + s2;
          lo4[u] = (_Float16)(t1 * cyv[u] - t2 * syv[u]);
          hi4[u] = (_Float16)(t2 * cxv[u] + t1 * sxv[u]);
        }
        int lane = (l & 15) + 16 * jj;
        *(h16x4*)&fragP[((w * 4 + mt) * 65 + lane) * 4]       = lo4;
        *(h16x4*)&fragP[(((w + 4) * 4 + mt) * 65 + lane) * 4] = hi4;
#pragma unroll
        for (int u = 0; u < 4; ++u) {
          int laneC = jj * 4 + u + 16 * qq;
          int pl = laneC ^ (4 * qq);            // phi(laneC)
          fragC[((mt * 8 + w) * 65 + pl) * 4 + jC]     = lo4[u];
          fragC[((mt * 8 + w + 4) * 65 + pl) * 4 + jC] = hi4[u];
        }
      }
    }
    __syncthreads();
    // stream fragP -> encF as paired K=32 fragments (coalesced 16B stores)
    _Float16* ef = encF + ((size_t)(b * 784) + sub) * 8192;
    for (int i = t; i < 1024; i += 256) {
      int kt2 = i >> 8, m2 = (i >> 6) & 3, ln = i & 63;
      h16x4 lo = *(const h16x4*)&fragP[(((2 * kt2) * 4 + m2) * 65 + ln) * 4];
      h16x4 hi = *(const h16x4*)&fragP[(((2 * kt2 + 1) * 4 + m2) * 65 + ln) * 4];
      h16x8 v;
#pragma unroll
      for (int j = 0; j < 4; ++j) { v[j] = lo[j]; v[j + 4] = hi[j]; }
      *(h16x8*)(ef + (size_t)i * 8) = v;
    }
    // Gram MFMA (K=32: paired pk frags; A/B share the k-map so pi cancels)
#pragma unroll
    for (int pk2 = 0; pk2 < 2; ++pk2) {
      int f0 = (2 * pk2) * 8, f1 = (2 * pk2 + 1) * 8;
      h16x8 a0, a1;
      {
        h16x4 lo = *(const h16x4*)&fragC[((f0 + 2 * w) * 65 + phiL) * 4];
        h16x4 hi = *(const h16x4*)&fragC[((f1 + 2 * w) * 65 + phiL) * 4];
#pragma unroll
        for (int j = 0; j < 4; ++j) { a0[j] = lo[j]; a0[j + 4] = hi[j]; }
      }
      {
        h16x4 lo = *(const h16x4*)&fragC[((f0 + 2 * w + 1) * 65 + phiL) * 4];
        h16x4 hi = *(const h16x4*)&fragC[((f1 + 2 * w + 1) * 65 + phiL) * 4];
#pragma unroll
        for (int j = 0; j < 4; ++j) { a1[j] = lo[j]; a1[j + 4] = hi[j]; }
      }
      macc[0] = mfma32(a0, hone8, macc[0]);
      macc[1] = mfma32(a1, hone8, macc[1]);
#pragma unroll
      for (int nt = 0; nt < 8; ++nt) {
        h16x4 lo = *(const h16x4*)&fragC[((f0 + nt) * 65 + phiL) * 4];
        h16x4 hi = *(const h16x4*)&fragC[((f1 + nt) * 65 + phiL) * 4];
        h16x8 bv;
#pragma unroll
        for (int j = 0; j < 4; ++j) { bv[j] = lo[j]; bv[j + 4] = hi[j]; }
        acc[0][nt] = mfma32(a0, bv, acc[0][nt]);
        acc[1][nt] = mfma32(a1, bv, acc[1][nt]);
      }
    }
  }
  float* gp = Gpart + (size_t)(b * 98 + blk) * 16384;
#pragma unroll
  for (int e = 0; e < 2; ++e)
#pragma unroll
    for (int nt = 0; nt < 8; ++nt)
#pragma unroll
      for (int r = 0; r < 4; ++r) {
        int row = (2 * w + e) * 16 + 4 * (l >> 4) + r;
        int col = nt * 16 + (l & 15);
        gp[row * 128 + col] = acc[e][nt][r];
      }
  if ((l & 15) == 0) {
    float* mp = mpart + (size_t)(b * 98 + blk) * 128;
#pragma unroll
    for (int e = 0; e < 2; ++e)
#pragma unroll
      for (int r = 0; r < 4; ++r)
        mp[(2 * w + e) * 16 + 4 * (l >> 4) + r] = macc[e][r];
  }
}

__global__ void k_gred(const float* __restrict__ Gpart,
                       const float* __restrict__ mpart,
                       float* __restrict__ G, float* __restrict__ mvec) {
  int b = blockIdx.x >> 6, chunk = blockIdx.x & 63;
  int idx = chunk * 256 + threadIdx.x;
  float s = 0.f;
  for (int i = 0; i < 98; ++i) s += Gpart[(size_t)(b * 98 + i) * 16384 + idx];
  G[(size_t)b * 16384 + idx] = s;
  if (idx < 128) {
    float sm = 0.f;
    for (int i = 0; i < 98; ++i) sm += mpart[(size_t)(b * 98 + i) * 128 + idx];
    mvec[b * 128 + idx] = sm;
  }
}

__global__ __launch_bounds__(256) void k_gstats(
    const float* __restrict__ G, const float* __restrict__ mvec,
    const float* __restrict__ qw, const float* __restrict__ kw,
    float* __restrict__ qk_murs) {
  __shared__ float red1[4], red2[4];
  int bi = blockIdx.x;               // conv*32 + b*8 + g
  int conv = bi >> 5, b = (bi >> 3) & 3, g = bi & 7;
  const float* W = conv ? kw : qw;
  int t = threadIdx.x;
  int c = g * 16 + (t >> 4);
  int i0 = (t & 15) * 8;
  const float* wc = W + (size_t)c * 128;
  const float* Gb = G + (size_t)b * 16384;
  const float* mb = mvec + b * 128;
  float s1 = 0.f, s2 = 0.f;
  for (int i = i0; i < i0 + 8; ++i) {
    float gi = 0.f;
    for (int j = 0; j < 128; ++j) gi += Gb[i * 128 + j] * wc[j];
    s2 += wc[i] * gi;
    s1 += wc[i] * mb[i];
  }
  for (int m = 1; m < 64; m <<= 1) { s1 += __shfl_xor(s1, m); s2 += __shfl_xor(s2, m); }
  if ((t & 63) == 0) { red1[t >> 6] = s1; red2[t >> 6] = s2; }
  __syncthreads();
  if (t == 0) {
    float S1 = red1[0] + red1[1] + red1[2] + red1[3];
    float S2 = red2[0] + red2[1] + red2[2] + red2[3];
    float invN = 1.f / 802816.f;
    float mu = S1 * invN;
    float var = S2 * invN - mu * mu;
    qk_murs[bi * 2] = mu;
    qk_murs[bi * 2 + 1] = rsqrtf(var + EPS_GN);
  }
}

// ---------- pass Q: q enc_block from encF (K=32 MFMA), barrier-free ----------

__global__ __launch_bounds__(256) void k_passQ(
    const _Float16* __restrict__ encF, const float* __restrict__ qk_murs,
    const _Float16* __restrict__ WqB,
    float* __restrict__ q_pool, float* __restrict__ Qpart) {
  int t = threadIdx.x, l = t & 63;
  int wu = rfl(t >> 6);
  int bi = blockIdx.x;
  int b = bi / 784, sub = bi % 784;
  int tile = sub >> 2, st = sub & 3;
  int by = (tile / 14) * 16, bx = (tile % 14) * 16;
  float qmu[2], qrs[2];
#pragma unroll
  for (int cc = 0; cc < 2; ++cc) {
    int g = 2 * wu + cc;
    qmu[cc] = qk_murs[(b * 8 + g) * 2];
    qrs[cc] = qk_murs[(b * 8 + g) * 2 + 1];
  }
  const h16x8* EF = (const h16x8*)encF + ((size_t)(b * 784) + sub) * 1024;
  const h16x8* WQ = (const h16x8*)WqB;
  f32x4 z = {0.f, 0.f, 0.f, 0.f};
  f32x4 accQ[4][2];
  h16x8 sf8[4];
#pragma unroll
  for (int mt = 0; mt < 4; ++mt)
#pragma unroll
    for (int cc = 0; cc < 2; ++cc) accQ[mt][cc] = z;
  for (int kt2 = 0; kt2 < 4; ++kt2) {
    h16x8 a[4];
#pragma unroll
    for (int mt = 0; mt < 4; ++mt) a[mt] = EF[(kt2 * 4 + mt) * 64 + l];
    if (kt2 == wu) {
#pragma unroll
      for (int mt = 0; mt < 4; ++mt) sf8[mt] = a[mt];
    }
    int fi = (kt2 * 8 + 2 * wu) * 64 + l;
    h16x8 bq0 = WQ[fi];
    h16x8 bq1 = WQ[fi + 64];
#pragma unroll
    for (int mt = 0; mt < 4; ++mt) {
      accQ[mt][0] = mfma32(bq0, a[mt], accQ[mt][0]);
      accQ[mt][1] = mfma32(bq1, a[mt], accQ[mt][1]);
    }
  }
  int q = l & 15;
  bool act = (q & 9) == 0;
  float qs1[2] = {0.f, 0.f}, qs2[2] = {0.f, 0.f};
#pragma unroll
  for (int cc = 0; cc < 2; ++cc) {
    int g = 2 * wu + cc;
#pragma unroll
    for (int mt = 0; mt < 4; ++mt) {
      f32x4 pv;
#pragma unroll
      for (int r = 0; r < 4; ++r) {
        float skip = (float)sf8[mt][cc * 4 + r];
        pv[r] = silu_f((accQ[mt][cc][r] - qmu[cc]) * qrs[cc]) + skip;
      }
#pragma unroll
      for (int r = 0; r < 4; ++r) {
        float v = pv[r] + __shfl_xor(pv[r], 1);
        v += __shfl_xor(v, 8);
        pv[r] = v * 0.25f;
      }
      if (act) {
        int p = mt * 16 + q;
        int py = by + (st >> 1) * 8 + (p >> 3);
        int px = bx + (st & 1) * 8 + (p & 7);
        size_t base = ((size_t)(b * NQ) + (py >> 1) * 112 + (px >> 1)) * 128 +
                      g * 16 + 4 * (l >> 4);
        *(f32x4*)(q_pool + base) = pv;
        qs1[cc] += pv[0] + pv[1] + pv[2] + pv[3];
        qs2[cc] += pv[0] * pv[0] + pv[1] * pv[1] + pv[2] * pv[2] + pv[3] * pv[3];
      }
    }
  }
#pragma unroll
  for (int cc = 0; cc < 2; ++cc) {
    float a1 = qs1[cc], a2 = qs2[cc];
    for (int m = 1; m < 64; m <<= 1) {
      a1 += __shfl_xor(a1, m);
      a2 += __shfl_xor(a2, m);
    }
    if (l == 0) {
      Qpart[(size_t)bi * 16 + (2 * wu + cc) * 2] = a1;
      Qpart[(size_t)bi * 16 + (2 * wu + cc) * 2 + 1] = a2;
    }
  }
}

// ---------- pass K: k enc_block from encF (K=32 MFMA), barrier-free ----------

__global__ __launch_bounds__(256) void k_passK(
    const _Float16* __restrict__ encF, const float* __restrict__ qk_murs,
    const _Float16* __restrict__ WkB, float* __restrict__ kpp) {
  int t = threadIdx.x, l = t & 63;
  int wu = rfl(t >> 6);
  int bi = blockIdx.x;
  int b = bi / 784, sub = bi % 784;
  float kmu[2], krs[2];
#pragma unroll
  for (int cc = 0; cc < 2; ++cc) {
    int g = 2 * wu + cc;
    kmu[cc] = qk_murs[(32 + b * 8 + g) * 2];
    krs[cc] = qk_murs[(32 + b * 8 + g) * 2 + 1];
  }
  const h16x8* EF = (const h16x8*)encF + ((size_t)(b * 784) + sub) * 1024;
  const h16x8* WK = (const h16x8*)WkB;
  f32x4 z = {0.f, 0.f, 0.f, 0.f};
  f32x4 accK[4][2];
  h16x8 sf8[4];
#pragma unroll
  for (int mt = 0; mt < 4; ++mt)
#pragma unroll
    for (int cc = 0; cc < 2; ++cc) accK[mt][cc] = z;
  for (int kt2 = 0; kt2 < 4; ++kt2) {
    h16x8 a[4];
#pragma unroll
    for (int mt = 0; mt < 4; ++mt) a[mt] = EF[(kt2 * 4 + mt) * 64 + l];
    if (kt2 == wu) {
#pragma unroll
      for (int mt = 0; mt < 4; ++mt) sf8[mt] = a[mt];
    }
    int fi = (kt2 * 8 + 2 * wu) * 64 + l;
    h16x8 bk0 = WK[fi];
    h16x8 bk1 = WK[fi + 64];
#pragma unroll
    for (int mt = 0; mt < 4; ++mt) {
      accK[mt][0] = mfma32(bk0, a[mt], accK[mt][0]);
      accK[mt][1] = mfma32(bk1, a[mt], accK[mt][1]);
    }
  }
  int q = l & 15;
  float kacc[2][4];
#pragma unroll
  for (int cc = 0; cc < 2; ++cc)
#pragma unroll
    for (int r = 0; r < 4; ++r) kacc[cc][r] = 0.f;
#pragma unroll
  for (int cc = 0; cc < 2; ++cc) {
#pragma unroll
    for (int mt = 0; mt < 4; ++mt) {
#pragma unroll
      for (int r = 0; r < 4; ++r) {
        float skip = (float)sf8[mt][cc * 4 + r];
        kacc[cc][r] += silu_f((accK[mt][cc][r] - kmu[cc]) * krs[cc]) + skip;
      }
    }
  }
#pragma unroll
  for (int cc = 0; cc < 2; ++cc) {
#pragma unroll
    for (int r = 0; r < 4; ++r) {
      float v = kacc[cc][r];
      v += __shfl_xor(v, 1);
      v += __shfl_xor(v, 2);
      v += __shfl_xor(v, 4);
      v += __shfl_xor(v, 8);
      kacc[cc][r] = v;
    }
    if (q == 0) {
      f32x4 kv = {kacc[cc][0], kacc[cc][1], kacc[cc][2], kacc[cc][3]};
      *(f32x4*)(kpp + (size_t)bi * 128 + (2 * wu + cc) * 16 + 4 * (l >> 4)) = kv;
    }
  }
}

__global__ __launch_bounds__(256) void k_kpred(
    const float* __restrict__ kpp, float* __restrict__ k_pool) {
  int idx = blockIdx.x * 256 + threadIdx.x;
  if (idx >= BB * 128 * NKk) return;
  int b = idx / (128 * NKk);
  int rem = idx % (128 * NKk);
  int c = rem / NKk, tile = rem % NKk;
  const float* base = kpp + ((size_t)(b * 196 + tile) * 4) * 128 + c;
  float s = base[0] + base[128] + base[256] + base[384];
  k_pool[idx] = s * (1.f / 256.f);
}

__global__ __launch_bounds__(256) void k_qstatfin(
    const float* __restrict__ Qpart, float* __restrict__ murs2) {
  __shared__ float l1[4], l2[4];
  int b = blockIdx.x >> 3, g = blockIdx.x & 7, t = threadIdx.x;
  float s1 = 0.f, s2 = 0.f;
  for (int i = t; i < 784; i += 256) {
    s1 += Qpart[((size_t)(b * 784) + i) * 16 + g * 2];
    s2 += Qpart[((size_t)(b * 784) + i) * 16 + g * 2 + 1];
  }
  for (int m = 1; m < 64; m <<= 1) { s1 += __shfl_xor(s1, m); s2 += __shfl_xor(s2, m); }
  if ((t & 63) == 0) { l1[t >> 6] = s1; l2[t >> 6] = s2; }
  __syncthreads();
  if (t == 0) {
    float a = l1[0] + l1[1] + l1[2] + l1[3];
    float bq = l2[0] + l2[1] + l2[2] + l2[3];
    float invN = 1.f / (16.f * (float)NQ);
    float mu = a * invN;
    float var = bq * invN - mu * mu;
    murs2[blockIdx.x * 2] = mu;
    murs2[blockIdx.x * 2 + 1] = rsqrtf(var + EPS_GN);
  }
}

// ---------- GN stats (channel-major src[b][c][P]) ----------

__global__ __launch_bounds__(256) void k_gnstats(
    const float* __restrict__ src, float* __restrict__ murs, int P, float eps) {
  __shared__ float l1[4], l2[4];
  int b = blockIdx.x >> 3, g = blockIdx.x & 7, t = threadIdx.x;
  const float* base = src + ((size_t)(b * 128) + g * 16) * P;
  float s1 = 0.f, s2 = 0.f;
  for (int i = t; i < 16 * P; i += 256) {
    float v = base[i];
    s1 += v; s2 += v * v;
  }
  for (int m = 1; m < 64; m <<= 1) { s1 += __shfl_xor(s1, m); s2 += __shfl_xor(s2, m); }
  if ((t & 63) == 0) { l1[t >> 6] = s1; l2[t >> 6] = s2; }
  __syncthreads();
  if (t == 0) {
    float invN = 1.f / (16.f * (float)P);
    float a = l1[0] + l1[1] + l1[2] + l1[3];
    float bq = l2[0] + l2[1] + l2[2] + l2[3];
    float mu = a * invN;
    float var = bq * invN - mu * mu;
    murs[blockIdx.x * 2] = mu;
    murs[blockIdx.x * 2 + 1] = rsqrtf(var + eps);
  }
}

// ---------- kf branch: fused L2-norm + 384->128 conv+proj (MFMA) ----------

__global__ __launch_bounds__(256) void k_kf(
    const float* __restrict__ feat,
    const _Float16* __restrict__ KFB, const _Float16* __restrict__ KFPB,
    float* __restrict__ y_kf, float* __restrict__ skip_kf) {
  __shared__ __align__(16) _Float16 fnF[24 * 4 * 64 * 4];  // 48KB, A-frags
  __shared__ float ssqL[4][64];
  __shared__ float rsqL[64];
  int t = threadIdx.x, l = t & 63, w = t >> 6;
  int b = blockIdx.x >> 2, tile = blockIdx.x & 3;
  int p0 = tile * 49;
  const float* fb = feat + (size_t)b * VD * NKk;
  {
    float s = 0.f;
    if (l < 49) {
#pragma unroll 4
      for (int k = w; k < VD; k += 4) {
        float v = fb[(size_t)k * NKk + p0 + l];
        s += v * v;
      }
    }
    ssqL[w][l] = s;
  }
  __syncthreads();
  if (t < 64) {
    float s = ssqL[0][t] + ssqL[1][t] + ssqL[2][t] + ssqL[3][t];
    rsqL[t] = rsqrtf(fmaxf(s, 1e-24f));
  }
  __syncthreads();
  for (int i = t; i < VD * 64; i += 256) {
    int k = i >> 6, p = i & 63;
    float v = 0.f;
    if (p < 49) v = fb[(size_t)k * NKk + p0 + p] * rsqL[p];
    int kt = k >> 4, kr = k & 15, u = kr >> 2, j = kr & 3, mt = p >> 4;
    fnF[(((kt * 4 + mt) * 64) + (p & 15) + 16 * u) * 4 + j] = (_Float16)v;
  }
  __syncthreads();
  f32x4 z = {0.f, 0.f, 0.f, 0.f};
  f32x4 accY[4][2], accS[4][2];
#pragma unroll
  for (int mt = 0; mt < 4; ++mt)
#pragma unroll
    for (int cc = 0; cc < 2; ++cc) { accY[mt][cc] = z; accS[mt][cc] = z; }
  for (int kt = 0; kt < 24; ++kt) {
    h16x4 a[4];
#pragma unroll
    for (int mt = 0; mt < 4; ++mt)
      a[mt] = *(const h16x4*)&fnF[((kt * 4 + mt) * 64 + l) * 4];
    int fi = (kt * 8 + 2 * w) * 64 + l;
    h16x4 by0 = *(const h16x4*)(KFB + (size_t)fi * 4);
    h16x4 by1 = *(const h16x4*)(KFB + (size_t)(fi + 64) * 4);
    h16x4 bs0 = *(const h16x4*)(KFPB + (size_t)fi * 4);
    h16x4 bs1 = *(const h16x4*)(KFPB + (size_t)(fi + 64) * 4);
#pragma unroll
    for (int mt = 0; mt < 4; ++mt) {
      accY[mt][0] = mfma16(a[mt], by0, accY[mt][0]);
      accY[mt][1] = mfma16(a[mt], by1, accY[mt][1]);
      accS[mt][0] = mfma16(a[mt], bs0, accS[mt][0]);
      accS[mt][1] = mfma16(a[mt], bs1, accS[mt][1]);
    }
  }
#pragma unroll
  for (int cc = 0; cc < 2; ++cc) {
    int co = (2 * w + cc) * 16 + (l & 15);
#pragma unroll
    for (int mt = 0; mt < 4; ++mt)
#pragma unroll
      for (int r = 0; r < 4; ++r) {
        int pix = mt * 16 + 4 * (l >> 4) + r;
        if (pix < 49) {
          size_t off = ((size_t)(b * 128) + co) * NKk + p0 + pix;
          y_kf[off] = accY[mt][cc][r];
          skip_kf[off] = accS[mt][cc][r];
        }
      }
  }
}

// ---------- merged SFT + RMSNorm + k-proj (MFMA) ----------

__global__ __launch_bounds__(256) void k_ksft(
    const float* __restrict__ y_kf, const float* __restrict__ skip_kf,
    const float* __restrict__ kf_murs, const float* __restrict__ kgn_murs,
    const _Float16* __restrict__ GB, const _Float16* __restrict__ BBf,
    const _Float16* __restrict__ KPB,
    const float* __restrict__ k_pool, const float* __restrict__ k_proj_b,
    float* __restrict__ kpb) {
  __shared__ __align__(16) _Float16 kfF[8 * 4 * 64 * 4];  // 16KB A-frags
  __shared__ float msL[4][64];
  __shared__ float sMu[8], sRs[8], sGmu[8], sGrs[8];
  int t = threadIdx.x, l = t & 63, w = t >> 6;
  int b = blockIdx.x >> 2, tile = blockIdx.x & 3;
  int p0 = tile * 49;
  if (t < 8) {
    sMu[t] = kf_murs[(b * 8 + t) * 2];
    sRs[t] = kf_murs[(b * 8 + t) * 2 + 1];
    sGmu[t] = kgn_murs[(b * 8 + t) * 2];
    sGrs[t] = kgn_murs[(b * 8 + t) * 2 + 1];
  }
  __syncthreads();
  for (int i = t; i < 128 * 64; i += 256) {
    int c = i >> 6, p = i & 63;
    float v = 0.f;
    if (p < 49) {
      size_t off = ((size_t)(b * 128) + c) * NKk + p0 + p;
      int g = c >> 4;
      v = silu_f((y_kf[off] - sMu[g]) * sRs[g]) + skip_kf[off];
    }
    int kt = c >> 4, kr = c & 15, u = kr >> 2, j = kr & 3, mt = p >> 4;
    kfF[(((kt * 4 + mt) * 64) + (p & 15) + 16 * u) * 4 + j] = (_Float16)v;
  }
  __syncthreads();
  f32x4 z = {0.f, 0.f, 0.f, 0.f};
  f32x4 accG[4][2], accB[4][2];
#pragma unroll
  for (int mt = 0; mt < 4; ++mt)
#pragma unroll
    for (int cc = 0; cc < 2; ++cc) { accG[mt][cc] = z; accB[mt][cc] = z; }
  for (int kt = 0; kt < 8; ++kt) {
    h16x4 a[4];
#pragma unroll
    for (int mt = 0; mt < 4; ++mt)
      a[mt] = *(const h16x4*)&kfF[((kt * 4 + mt) * 64 + l) * 4];
    int fi = (kt * 8 + 2 * w) * 64 + l;
    h16x4 bg0 = *(const h16x4*)(GB + (size_t)fi * 4);
    h16x4 bg1 = *(const h16x4*)(GB + (size_t)(fi + 64) * 4);
    h16x4 bb0 = *(const h16x4*)(BBf + (size_t)fi * 4);
    h16x4 bb1 = *(const h16x4*)(BBf + (size_t)(fi + 64) * 4);
#pragma unroll
    for (int mt = 0; mt < 4; ++mt) {
      accG[mt][0] = mfma16(a[mt], bg0, accG[mt][0]);
      accG[mt][1] = mfma16(a[mt], bg1, accG[mt][1]);
      accB[mt][0] = mfma16(a[mt], bb0, accB[mt][0]);
      accB[mt][1] = mfma16(a[mt], bb1, accB[mt][1]);
    }
  }
  float kfin[4][2][4];
#pragma unroll
  for (int cc = 0; cc < 2; ++cc) {
    int g = 2 * w + cc;
    int co = g * 16 + (l & 15);
    float gmu = sGmu[g], grs = sGrs[g];
#pragma unroll
    for (int mt = 0; mt < 4; ++mt)
#pragma unroll
      for (int r = 0; r < 4; ++r) {
        int pix = mt * 16 + 4 * (l >> 4) + r;
        float v = 0.f;
        if (pix < 49) {
          float kn = (k_pool[((size_t)(b * 128) + co) * NKk + p0 + pix] - gmu) * grs;
          v = fmaf(accG[mt][cc][r], kn, accB[mt][cc][r]);
        }
        kfin[mt][cc][r] = v;
      }
  }
#pragma unroll
  for (int mt = 0; mt < 4; ++mt)
#pragma unroll
    for (int r = 0; r < 4; ++r) {
      float s2 = kfin[mt][0][r] * kfin[mt][0][r] + kfin[mt][1][r] * kfin[mt][1][r];
      for (int m = 1; m < 16; m <<= 1) s2 += __shfl_xor(s2, m);
      if ((l & 15) == 0) msL[w][mt * 16 + 4 * (l >> 4) + r] = s2;
    }
  __syncthreads();
#pragma unroll
  for (int cc = 0; cc < 2; ++cc) {
    int ktn = 2 * w + cc;
    int u = (l & 15) >> 2, j = (l & 15) & 3;
#pragma unroll
    for (int mt = 0; mt < 4; ++mt)
#pragma unroll
      for (int r = 0; r < 4; ++r) {
        int lane = (4 * (l >> 4) + r) + 16 * u;
        kfF[((ktn * 4 + mt) * 64 + lane) * 4 + j] = (_Float16)kfin[mt][cc][r];
      }
  }
  __syncthreads();
  f32x4 accP[4][2];
#pragma unroll
  for (int mt = 0; mt < 4; ++mt)
#pragma unroll
    for (int cc = 0; cc < 2; ++cc) accP[mt][cc] = z;
  for (int kt = 0; kt < 8; ++kt) {
    h16x4 a[4];
#pragma unroll
    for (int mt = 0; mt < 4; ++mt)
      a[mt] = *(const h16x4*)&kfF[((kt * 4 + mt) * 64 + l) * 4];
    int fi = (kt * 8 + 2 * w) * 64 + l;
    h16x4 b0 = *(const h16x4*)(KPB + (size_t)fi * 4);
    h16x4 b1 = *(const h16x4*)(KPB + (size_t)(fi + 64) * 4);
#pragma unroll
    for (int mt = 0; mt < 4; ++mt) {
      accP[mt][0] = mfma16(a[mt], b0, accP[mt][0]);
      accP[mt][1] = mfma16(a[mt], b1, accP[mt][1]);
    }
  }
#pragma unroll
  for (int mt = 0; mt < 4; ++mt)
#pragma unroll
    for (int r = 0; r < 4; ++r) {
      int pix = mt * 16 + 4 * (l >> 4) + r;
      if (pix >= 49) continue;
      float ms = msL[0][pix] + msL[1][pix] + msL[2][pix] + msL[3][pix];
      float rr = rsqrtf(ms * (1.f / 128.f) + EPS_RMS);
#pragma unroll
      for (int cc = 0; cc < 2; ++cc) {
        int co = (2 * w + cc) * 16 + (l & 15);
        kpb[((size_t)(b * 196) + p0 + pix) * 128 + co] =
            accP[mt][cc][r] * rr + k_proj_b[co];
      }
    }
}

// ---------- fused 3x3 conv + RMSNorm + q-proj (K=32 MFMA conv, LDS input,
// SW-pipelined weight stream) ----------

__global__ __launch_bounds__(256) void k_conv3f(
    const float* __restrict__ q_pool, const float* __restrict__ murs2,
    const _Float16* __restrict__ W3B, const _Float16* __restrict__ QPB,
    const float* __restrict__ bias, float* __restrict__ qp) {
  __shared__ __align__(16) _Float16 tileL[100 * 136];  // 27.2 KB
  __shared__ float sMu[8], sRs[8];
  int t = threadIdx.x, l = t & 63, w = t >> 6;
  int b = blockIdx.x / 196, reg = blockIdx.x % 196;
  int y0 = (reg / 14) * 8, x0 = (reg % 14) * 8;
  if (t < 8) { sMu[t] = murs2[(b * 8 + t) * 2]; sRs[t] = murs2[(b * 8 + t) * 2 + 1]; }
  __syncthreads();
  for (int i = t; i < 3200; i += 256) {
    int rowp = i >> 5, c4 = i & 31;
    int gy = y0 - 1 + rowp / 10, gx = x0 - 1 + rowp % 10;
    h16x4 hv = {(_Float16)0.f, (_Float16)0.f, (_Float16)0.f, (_Float16)0.f};
    if (gy >= 0 && gy < 112 && gx >= 0 && gx < 112) {
      f32x4 v = *(const f32x4*)(q_pool + ((size_t)(b * NQ) + gy * 112 + gx) * 128 +
                                c4 * 4);
      int g = c4 >> 2;
      float mu = sMu[g], rs = sRs[g];
#pragma unroll
      for (int j = 0; j < 4; ++j) hv[j] = (_Float16)((v[j] - mu) * rs);
    }
    *(h16x4*)&tileL[rowp * 136 + c4 * 4] = hv;
  }
  __syncthreads();
  f32x4 z = {0.f, 0.f, 0.f, 0.f};
  f32x4 acc[8];
#pragma unroll
  for (int ct = 0; ct < 8; ++ct) acc[ct] = z;
  int lm = l & 15;
  int mrow = lm >> 3, mcol = lm & 7;
  const h16x8* W3l = (const h16x8*)W3B + l;
  h16x8 wbuf[3][8];
#pragma unroll
  for (int ct = 0; ct < 8; ++ct) wbuf[0][ct] = W3l[ct * 64];
#pragma unroll
  for (int ct = 0; ct < 8; ++ct) wbuf[1][ct] = W3l[(8 + ct) * 64];
#pragma unroll
  for (int s = 0; s < 36; ++s) {
    if (s + 2 < 36) {
#pragma unroll
      for (int ct = 0; ct < 8; ++ct)
        wbuf[(s + 2) % 3][ct] = W3l[((s + 2) * 8 + ct) * 64];
    }
    int tap = s >> 2, kt2 = s & 3;
    int prow = (2 * w + mrow + tap / 3) * 10 + (mcol + tap % 3);
    h16x8 bf = *(const h16x8*)&tileL[prow * 136 + kt2 * 32 + 8 * (l >> 4)];
#pragma unroll
    for (int ct = 0; ct < 8; ++ct)
      acc[ct] = mfma32(wbuf[s % 3][ct], bf, acc[ct]);
  }
  float sq = 0.f;
#pragma unroll
  for (int ct = 0; ct < 8; ++ct)
#pragma unroll
    for (int r = 0; r < 4; ++r) sq += acc[ct][r] * acc[ct][r];
  sq += __shfl_xor(sq, 16);
  sq += __shfl_xor(sq, 32);
  float rr = rsqrtf(sq * (1.f / 128.f) + EPS_RMS);
  int chof = 4 * (l >> 4);
  h16x4 pb[8];
#pragma unroll
  for (int kt = 0; kt < 8; ++kt)
#pragma unroll
    for (int j = 0; j < 4; ++j) pb[kt][j] = (_Float16)acc[kt][j];
  f32x4 accP[8];
#pragma unroll
  for (int ct = 0; ct < 8; ++ct) accP[ct] = z;
  const h16x4* QP = (const h16x4*)QPB + l;
#pragma unroll
  for (int kt = 0; kt < 8; ++kt) {
#pragma unroll
    for (int ct = 0; ct < 8; ++ct)
      accP[ct] = mfma16(QP[(kt * 8 + ct) * 64], pb[kt], accP[ct]);
  }
  int py = y0 + 2 * w + mrow, px = x0 + mcol;
  size_t pbase = ((size_t)(b * NQ) + py * 112 + px) * 128;
#pragma unroll
  for (int ct = 0; ct < 8; ++ct) {
    f32x4 o;
#pragma unroll
    for (int r = 0; r < 4; ++r)
      o[r] = accP[ct][r] * rr + bias[ct * 16 + chof + r];
    *(f32x4*)(qp + pbase + ct * 16 + chof) = o;
  }
}

// ---------- attention: QK^T (K=32) + softmax + head-mean -> packed fp16 P ----------

__global__ __launch_bounds__(256) void k_attn1m(
    const float* __restrict__ qp, const float* __restrict__ kpb,
    _Float16* __restrict__ Ph) {
  __shared__ float sP[4][16][212];
  int t = threadIdx.x, l = t & 63, h = t >> 6;
  int b = blockIdx.x / 784, qt = blockIdx.x % 784;
  int q0 = qt * 16;
  constexpr float SC = 0.17677669529663687f;  // 1/sqrt(32)
  h16x8 aq;
  {
    const float* qrow = qp + ((size_t)(b * NQ) + q0 + (l & 15)) * 128 +
                        h * 32 + 8 * (l >> 4);
    f32x4 v0 = *(const f32x4*)qrow;
    f32x4 v1 = *(const f32x4*)(qrow + 4);
#pragma unroll
    for (int j = 0; j < 4; ++j) { aq[j] = (_Float16)v0[j]; aq[j + 4] = (_Float16)v1[j]; }
  }
  f32x4 z = {0.f, 0.f, 0.f, 0.f};
  f32x4 acc[13];
#pragma unroll
  for (int nt = 0; nt < 13; ++nt) acc[nt] = z;
#pragma unroll
  for (int nt = 0; nt < 13; ++nt) {
    int key = nt * 16 + (l & 15);
    bool ok = key < 196;
    h16x8 bf = {(_Float16)0.f, (_Float16)0.f, (_Float16)0.f, (_Float16)0.f,
                (_Float16)0.f, (_Float16)0.f, (_Float16)0.f, (_Float16)0.f};
    if (ok) {
      const float* krow = kpb + ((size_t)(b * 196) + key) * 128 +
                          h * 32 + 8 * (l >> 4);
      f32x4 v0 = *(const f32x4*)krow;
      f32x4 v1 = *(const f32x4*)(krow + 4);
#pragma unroll
      for (int j = 0; j < 4; ++j) { bf[j] = (_Float16)v0[j]; bf[j + 4] = (_Float16)v1[j]; }
    }
    acc[nt] = mfma32(aq, bf, acc[nt]);
  }
#pragma unroll
  for (int r = 0; r < 4; ++r) {
    float mx = -3e38f;
#pragma unroll
    for (int nt = 0; nt < 13; ++nt) {
      bool ok = nt * 16 + (l & 15) < 196;
      float v = ok ? acc[nt][r] * SC : -3e38f;
      acc[nt][r] = v;
      mx = fmaxf(mx, v);
    }
    for (int m = 1; m < 16; m <<= 1) mx = fmaxf(mx, __shfl_xor(mx, m));
    float sum = 0.f;
#pragma unroll
    for (int nt = 0; nt < 13; ++nt) {
      bool ok = nt * 16 + (l & 15) < 196;
      float e = ok ? __expf(acc[nt][r] - mx) : 0.f;
      acc[nt][r] = e;
      sum += e;
    }
    for (int m = 1; m < 16; m <<= 1) sum += __shfl_xor(sum, m);
    float inv = 1.f / sum;
#pragma unroll
    for (int nt = 0; nt < 13; ++nt)
      sP[h][4 * (l >> 4) + r][nt * 16 + (l & 15)] = acc[nt][r] * inv;
  }
  __syncthreads();
  _Float16* pb = Ph + (size_t)(b * 784 + qt) * 13 * 256;
  for (int i = t; i < 832; i += 256) {
    int kt = i >> 6, ll = i & 63;
    int q = ll & 15, kb = kt * 16 + 4 * (ll >> 4);
    h16x4 v;
#pragma unroll
    for (int j = 0; j < 4; ++j) {
      int k = kb + j;
      float s = 0.25f * (sP[0][q][k] + sP[1][q][k] + sP[2][q][k] + sP[3][q][k]);
      v[j] = (_Float16)s;
    }
    *(h16x4*)(pb + (size_t)i * 4) = v;
  }
}

// ---------- attention PV: pure fragment streaming, no LDS ----------

__global__ __launch_bounds__(256) void k_attn2m(
    const _Float16* __restrict__ Ph, const _Float16* __restrict__ featB,
    float* __restrict__ out) {
  int t = threadIdx.x, l = t & 63, w = t >> 6;
  int b = blockIdx.x / 196, qt = blockIdx.x % 196;
  int q16 = qt * 4 + w;
  f32x4 z = {0.f, 0.f, 0.f, 0.f};
  f32x4 acc[24];
#pragma unroll
  for (int dt = 0; dt < 24; ++dt) acc[dt] = z;
  const h16x4* PB = (const h16x4*)Ph + ((size_t)(b * 784 + q16) * 13) * 64 + l;
  const h16x4* FB = (const h16x4*)featB + (size_t)b * 13 * 24 * 64 + l;
  for (int kt = 0; kt < 13; ++kt) {
    h16x4 bp = PB[kt * 64];
    const h16x4* fb = FB + kt * 24 * 64;
#pragma unroll
    for (int dt = 0; dt < 24; ++dt)
      acc[dt] = mfma16(fb[(size_t)dt * 64], bp, acc[dt]);
  }
  int qg = q16 * 16 + (l & 15);
#pragma unroll
  for (int dt = 0; dt < 24; ++dt)
#pragma unroll
    for (int r = 0; r < 4; ++r) {
      int d = dt * 16 + 4 * (l >> 4) + r;
      out[((size_t)(b * 384) + d) * NQ + qg] = acc[dt][r];
    }
}

}  // namespace

extern "C" void kernel_launch(void* const* d_in, const int* in_sizes, int n_in,
                              void* d_out, int out_size, void* d_ws,
                              size_t ws_size, hipStream_t stream) {
  (void)in_sizes; (void)n_in; (void)out_size; (void)ws_size;
  const float* image        = (const float*)d_in[0];
  const float* features     = (const float*)d_in[1];
  const float* rope_f       = (const float*)d_in[2];
  const float* img_conv_w   = (const float*)d_in[3];
  const float* img_proj_w   = (const float*)d_in[4];
  const float* qenc_w       = (const float*)d_in[5];
  const float* kenc_w       = (const float*)d_in[6];
  const float* kfeat_conv_w = (const float*)d_in[7];
  const float* kfeat_proj_w = (const float*)d_in[8];
  const float* sft_gamma_w  = (const float*)d_in[9];
  const float* sft_beta_w   = (const float*)d_in[10];
  const float* block_conv_w = (const float*)d_in[11];
  const float* rms_q_w      = (const float*)d_in[12];
  const float* rms_k_w      = (const float*)d_in[13];
  const float* q_proj_w     = (const float*)d_in[14];
  const float* q_proj_b     = (const float*)d_in[15];
  const float* k_proj_w     = (const float*)d_in[16];
  const float* k_proj_b     = (const float*)d_in[17];
  float* out = (float*)d_out;
  float* ws = (float*)d_ws;

  size_t off = 0;
  auto alloc = [&](size_t n) {
    size_t r = off;
    off += (n + 63) & ~(size_t)63;
    return r;
  };
  _Float16* WqB  = (_Float16*)(ws + alloc(8192));
  _Float16* WkB  = (_Float16*)(ws + alloc(8192));
  _Float16* QPB  = (_Float16*)(ws + alloc(8192));
  _Float16* W3B  = (_Float16*)(ws + alloc(73728));
  _Float16* KFB  = (_Float16*)(ws + alloc(24576));
  _Float16* KFPB = (_Float16*)(ws + alloc(24576));
  _Float16* GB   = (_Float16*)(ws + alloc(8192));
  _Float16* BBf  = (_Float16*)(ws + alloc(8192));
  _Float16* KPB  = (_Float16*)(ws + alloc(8192));
  float* cosT     = ws + alloc(14336);
  float* sinT     = ws + alloc(14336);
  _Float16* featB = (_Float16*)(ws + alloc(159744));
  float* imgpart  = ws + alloc(2304);
  float* img_murs = ws + alloc(64);
  float* qk_murs  = ws + alloc(128);
  float* murs2    = ws + alloc(64);
  float* kgn_murs = ws + alloc(64);
  float* kf_murs  = ws + alloc(64);
  float* G        = ws + alloc(65536);
  float* mvec     = ws + alloc(512);
  float* mpart    = ws + alloc(392 * 128);
  float* Qpart    = ws + alloc((size_t)BB * 784 * 16);
  float* kpp      = ws + alloc((size_t)BB * 784 * 128);
  float* y_kf     = ws + alloc(100352);
  float* skip_kf  = ws + alloc(100352);
  float* k_pool   = ws + alloc(100352);
  float* kpb      = ws + alloc(100352);
  // RA (25.7MB): Gpart -> q_pool
  float* RA = ws + alloc((size_t)BB * NQ * 128);
  // ENC (51.4MB): encF -> (qp, Ph)
  float* ENCp = ws + alloc((size_t)BB * 784 * 8192 / 2);
  float* Gpart  = RA;
  float* q_pool = RA;
  _Float16* encF = (_Float16*)ENCp;
  float* qp      = ENCp;                                      // after encF dead
  _Float16* Ph   = (_Float16*)(ENCp + (size_t)BB * NQ * 128); // after qp

  k_prep<<<2648, 256, 0, stream>>>(qenc_w, kenc_w, q_proj_w, rms_q_w,
                                   block_conv_w, kfeat_conv_w, kfeat_proj_w,
                                   sft_gamma_w, sft_beta_w, k_proj_w, rms_k_w,
                                   rope_f, features,
                                   WqB, WkB, QPB, W3B, KFB, KFPB, GB, BBf, KPB,
                                   cosT, sinT, featB);

  k_imgstat1<<<BB * 64, 256, 0, stream>>>(image, imgpart);
  k_imgstat2<<<BB, 128, 0, stream>>>(imgpart, img_conv_w, img_murs);

  k_kf<<<BB * 4, 256, 0, stream>>>(features, KFB, KFPB, y_kf, skip_kf);
  k_gnstats<<<32, 256, 0, stream>>>(y_kf, kf_murs, NKk, EPS_GN);

  k_gram<<<BB * 98, 256, 0, stream>>>(image, cosT, sinT, img_conv_w,
                                      img_proj_w, img_murs, encF, Gpart, mpart);
  k_gred<<<BB * 64, 256, 0, stream>>>(Gpart, mpart, G, mvec);
  k_gstats<<<64, 256, 0, stream>>>(G, mvec, qenc_w, kenc_w, qk_murs);

  // q/k enc_blocks split into two barrier-free kernels (higher occupancy)
  k_passK<<<BB * 784, 256, 0, stream>>>(encF, qk_murs, WkB, kpp);
  k_passQ<<<BB * 784, 256, 0, stream>>>(encF, qk_murs, WqB, q_pool, Qpart);
  k_qstatfin<<<32, 256, 0, stream>>>(Qpart, murs2);
  k_kpred<<<392, 256, 0, stream>>>(kpp, k_pool);
  k_gnstats<<<32, 256, 0, stream>>>(k_pool, kgn_murs, NKk, EPS_GN);

  k_ksft<<<BB * 4, 256, 0, stream>>>(y_kf, skip_kf, kf_murs, kgn_murs,
                                     GB, BBf, KPB, k_pool, k_proj_b, kpb);

  k_conv3f<<<BB * 196, 256, 0, stream>>>(q_pool, murs2, W3B, QPB, q_proj_b, qp);

  k_attn1m<<<BB * 784, 256, 0, stream>>>(qp, kpb, Ph);
  k_attn2m<<<BB * 196, 256, 0, stream>>>(Ph, featB, out);
}